// Round 10
// baseline (260.008 us; speedup 1.0000x reference)
//
#include <hip/hip_runtime.h>
#include <cstdint>

typedef unsigned short u16;
typedef unsigned int   u32;
typedef __attribute__((ext_vector_type(8))) short bf16x8;
typedef __attribute__((ext_vector_type(4))) float f32x4;

#define DEVFN static __device__ __forceinline__

constexpr int B  = 4096;
constexpr int SQ = 41;

DEVFN float bf2f(u16 v) { return __uint_as_float(((u32)v) << 16); }
DEVFN u16 f2bf(float f) {
  u32 u = __float_as_uint(f);
  u += 0x7fffu + ((u >> 16) & 1u);
  return (u16)(u >> 16);
}
DEVFN u32 pack2(float a, float b) { return (u32)f2bf(a) | ((u32)f2bf(b) << 16); }

DEVFN void gload16(const void* g, void* l) {
  __builtin_amdgcn_global_load_lds(
      (const __attribute__((address_space(1))) unsigned int*)g,
      (__attribute__((address_space(3))) unsigned int*)l, 16, 0, 0);
}

// ---------------- K-1: pack weights into swizzled bf16 global images --------
__global__ void k_pack(const float* __restrict__ cw, const float* __restrict__ cpw,
                       const float* __restrict__ rW, const float* __restrict__ rb,
                       u16* __restrict__ wpk, u16* __restrict__ cpk,
                       u16* __restrict__ rwp, u16* __restrict__ zp) {
  int i = blockIdx.x * 256 + threadIdx.x;
  if (i < 12288) {                    // conv1 weights [t][o][c^swz], c padded 64
    int tt = i >> 12, rem = i & 4095, o = rem >> 6, c = rem & 63;
    float v = (c < 41) ? cw[(o * 41 + c) * 3 + tt] : 0.f;
    wpk[(tt * 64 + o) * 64 + (c ^ ((o & 7) << 3))] = f2bf(v);
  } else if (i < 18432) {             // caps weights [t][o][cg^swz]
    int k = i - 12288;
    int tt = k >> 11, rem = k & 2047, o = rem >> 5, c = rem & 31;
    cpk[(tt * 64 + o) * 32 + (c ^ ((o & 3) << 3))] = f2bf(cpw[(o * 32 + c) * 3 + tt]);
  } else if (i < 34816) {             // routing weights [j*64+o][l] * (1+rb)
    int k = i - 18432;
    rwp[k] = f2bf(rW[k] * (1.f + rb[k >> 7]));
  } else if (i < 38912) {             // 8 KB zero page for gemm7 A-padding
    zp[i - 34816] = 0;
  }
}

// ---------------- K0: combo indices [B][41], symbols 0..3, pad=4 -------------
__global__ void k_combo(const int* __restrict__ x, int* __restrict__ combo) {
  int i = blockIdx.x * 256 + threadIdx.x;
  if (i >= B * SQ) return;
  int b = i / SQ, s = i - b * SQ;
  const int* xb = x + b * SQ;
  int d0 = (s > 0) ? xb[s - 1] : 4;
  int d1 = xb[s];
  int d2 = (s < SQ - 1) ? xb[s + 1] : 4;
  combo[i] = d0 * 25 + d1 * 5 + d2;
}

// ---------------- K1a: G[s][w][sym][o] = sum_f emb[sym][f]*W3[s][w*128+f][o] -
__global__ void k_gmat(const float* __restrict__ emb, const float* __restrict__ W3,
                       float* __restrict__ G) {
  int s = blockIdx.x / 3, ww = blockIdx.x % 3;
  int o = threadIdx.x;
  const float* Ws = W3 + ((size_t)s * 384 + ww * 128) * 128;
  float a0 = 0.f, a1 = 0.f, a2 = 0.f, a3 = 0.f;
  for (int f = 0; f < 128; ++f) {
    float wg = Ws[(size_t)f * 128 + o];
    a0 = fmaf(emb[f], wg, a0);
    a1 = fmaf(emb[128 + f], wg, a1);
    a2 = fmaf(emb[256 + f], wg, a2);
    a3 = fmaf(emb[384 + f], wg, a3);
  }
  float* Gp = G + ((size_t)(s * 3 + ww) * 5) * 128 + o;
  Gp[0] = a0; Gp[128] = a1; Gp[256] = a2; Gp[384] = a3; Gp[512] = 0.f;
}

// ---------------- K1b: t1T[s][o][v] = relu(b3 + G0+G1+G2)  (transposed) -----
__global__ void k_t1(const float* __restrict__ G, const float* __restrict__ b3,
                     float* __restrict__ t1T) {
  int i = blockIdx.x * 256 + threadIdx.x;
  if (i >= SQ * 128 * 125) return;
  int v = i % 125, so = i / 125;
  int s = so >> 7, o = so & 127;
  int d0 = v / 25, r = v % 25;
  int d1 = r / 5, d2 = r % 5;
  float acc = b3[so]
      + G[((size_t)(s * 3 + 0) * 5 + d0) * 128 + o]
      + G[((size_t)(s * 3 + 1) * 5 + d1) * 128 + o]
      + G[((size_t)(s * 3 + 2) * 5 + d2) * 128 + o];
  t1T[i] = fmaxf(acc, 0.f);
}

// ---------------- K2: t2[s][w][v][o] (bf16) = sum_f t1[s+w-2][v][f]*W5[..] --
__global__ __launch_bounds__(128) void k_t2(const float* __restrict__ t1T,
                                            const float* __restrict__ W5,
                                            u16* __restrict__ t2) {
  int bx = blockIdx.x;
  int s = bx / 25; int r = bx % 25;
  int ww = r / 5;  int vt = (r % 5) * 25;
  int o = threadIdx.x;
  int t = s + ww - 2;
  u16* dst = t2 + ((size_t)(s * 5 + ww) * 125 + vt) * 128 + o;
  if (t < 0 || t >= SQ) {
    #pragma unroll
    for (int v = 0; v < 25; ++v) dst[(size_t)v * 128] = 0;
    return;
  }
  float acc[25];
  #pragma unroll
  for (int v = 0; v < 25; ++v) acc[v] = 0.f;
  const float* Ws = W5 + ((size_t)s * 640 + ww * 128) * 128;
  const float* tp = t1T + (size_t)t * 128 * 125 + vt;
  for (int f = 0; f < 128; ++f) {
    float wg = Ws[(size_t)f * 128 + o];
    #pragma unroll
    for (int v = 0; v < 25; ++v) acc[v] = fmaf(tp[f * 125 + v], wg, acc[v]);
  }
  #pragma unroll
  for (int v = 0; v < 25; ++v) dst[(size_t)v * 128] = f2bf(acc[v]);
}

// ---------------- K3: h2[b][s][o] = relu(b5 + sum_w t2[s][w][combo]) --------
__global__ __launch_bounds__(256) void k_h2(const u16* __restrict__ t2,
                                            const int* __restrict__ combo,
                                            const float* __restrict__ b5,
                                            u16* __restrict__ h2) {
  const int i = blockIdx.x * 256 + threadIdx.x;   // B*41*16 total
  const int o8 = (i & 15) * 8;
  const int rid = i >> 4;                          // s-major: s = rid>>12
  const int s = rid >> 12, b = rid & 4095;
  float acc[8];
  {
    float4 b0 = *reinterpret_cast<const float4*>(b5 + s * 128 + o8);
    float4 b1 = *reinterpret_cast<const float4*>(b5 + s * 128 + o8 + 4);
    acc[0] = b0.x; acc[1] = b0.y; acc[2] = b0.z; acc[3] = b0.w;
    acc[4] = b1.x; acc[5] = b1.y; acc[6] = b1.z; acc[7] = b1.w;
  }
  const int* cb = combo + b * SQ;
  #pragma unroll
  for (int ww = 0; ww < 5; ++ww) {
    const int t = s + ww - 2;
    if (0 <= t && t < SQ) {
      const int c = cb[t];
      uint4 raw = *reinterpret_cast<const uint4*>(
          t2 + ((size_t)(s * 5 + ww) * 125 + c) * 128 + o8);
      acc[0] += __uint_as_float(raw.x << 16);
      acc[1] += __uint_as_float(raw.x & 0xffff0000u);
      acc[2] += __uint_as_float(raw.y << 16);
      acc[3] += __uint_as_float(raw.y & 0xffff0000u);
      acc[4] += __uint_as_float(raw.z << 16);
      acc[5] += __uint_as_float(raw.z & 0xffff0000u);
      acc[6] += __uint_as_float(raw.w << 16);
      acc[7] += __uint_as_float(raw.w & 0xffff0000u);
    }
  }
  uint4 pk;
  pk.x = pack2(fmaxf(acc[0], 0.f), fmaxf(acc[1], 0.f));
  pk.y = pack2(fmaxf(acc[2], 0.f), fmaxf(acc[3], 0.f));
  pk.z = pack2(fmaxf(acc[4], 0.f), fmaxf(acc[5], 0.f));
  pk.w = pack2(fmaxf(acc[6], 0.f), fmaxf(acc[7], 0.f));
  *reinterpret_cast<uint4*>(h2 + ((size_t)b * SQ + s) * 128 + o8) = pk;
}

// ---------------- K4a: W7 [41][896][128] f32 -> w7t [41][128][896] bf16 -----
__global__ __launch_bounds__(256) void k_w7t(const float* __restrict__ W7,
                                             u16* __restrict__ w7t) {
  __shared__ float tile[64][65];
  const int s = blockIdx.z;
  const int k0 = blockIdx.x * 64;   // 896/64 = 14
  const int o0 = blockIdx.y * 64;   // 128/64 = 2
  const int t = threadIdx.x;
  #pragma unroll
  for (int i = 0; i < 16; ++i) {
    int idx = t + i * 256;
    int kl = idx >> 6, ol = idx & 63;
    tile[kl][ol] = W7[((size_t)s * 896 + k0 + kl) * 128 + o0 + ol];
  }
  __syncthreads();
  #pragma unroll
  for (int i = 0; i < 16; ++i) {
    int idx = t + i * 256;
    int ol = idx >> 6, kl = idx & 63;
    w7t[((size_t)s * 128 + o0 + ol) * 896 + k0 + kl] = f2bf(tile[kl][ol]);
  }
}

// ---------------- K4b: layer-3 GEMM, BK=32, 4-buf, 3-step-lookahead pipeline -
// 2D grid (s-major dispatch, restores R8 L2/L3 locality). Constant 4 loads per
// stage (zero page for out-of-band A) -> static vmcnt immediates 12/8/4/0.
// Swizzle: source granule g^(row&3); read granule qk^(row&3) (both-sides, #21).
__global__ __launch_bounds__(256) void k_gemm7_mfma(const u16* __restrict__ h2,
                                                    const u16* __restrict__ w7t,
                                                    const float* __restrict__ b7,
                                                    const u16* __restrict__ zp,
                                                    u16* __restrict__ h3) {
  __shared__ u16 As[4][4096];   // 4 bufs x 8 KB: [row 0..127][4 granules ^swz]
  __shared__ u16 Bs[4][4096];
  const int s  = blockIdx.y;
  const int b0 = blockIdx.x * 128;
  const int t  = threadIdx.x;
  const int lane = t & 63, w = t >> 6;
  const int wr = w >> 1, wc = w & 1;            // wave -> 64x64 quadrant
  const int lcol = lane & 15, qk = lane >> 4;   // qk: k-granule 0..3

  f32x4 acc[4][4];
  #pragma unroll
  for (int i = 0; i < 4; ++i)
    #pragma unroll
    for (int j = 0; j < 4; ++j) acc[i][j] = (f32x4){0.f, 0.f, 0.f, 0.f};

  const u16* wbase = w7t + (size_t)s * 128 * 896;

  // stage K-tile kt (32 wide) into buffer bi; always issues exactly 4 loads
  auto stage = [&](int kt, int bi) {
    const int ww = kt >> 2, tr = s + ww - 3;
    const int kf0 = (kt & 3) * 32;
    const bool val = (0 <= tr && tr < SQ);
    #pragma unroll
    for (int it = 0; it < 2; ++it) {
      const int L = it * 4096 + t * 16;          // dest byte offset
      const int r = L >> 6, g = (L >> 4) & 3;    // row, dest granule
      const u16* src = val
          ? h2 + ((size_t)(b0 + r) * SQ + tr) * 128 + kf0 + ((g ^ (r & 3)) << 3)
          : zp + (L >> 1);
      gload16(src, (char*)As[bi] + it * 4096 + w * 1024);
    }
    #pragma unroll
    for (int it = 0; it < 2; ++it) {
      const int L = it * 4096 + t * 16;
      const int o = L >> 6, g = (L >> 4) & 3;
      gload16(wbase + (size_t)o * 896 + kt * 32 + ((g ^ (o & 3)) << 3),
              (char*)Bs[bi] + it * 4096 + w * 1024);
    }
  };

  stage(0, 0); stage(1, 1); stage(2, 2);   // prologue: 3 tiles in flight

  for (int kt = 0; kt < 28; ++kt) {
    __builtin_amdgcn_sched_barrier(0);     // loop-boundary fence
    if (kt + 3 < 28) stage(kt + 3, (kt + 3) & 3);
    // wait only for tile-kt's 4 loads; newer tiles stay in flight
    if (kt < 25)       asm volatile("s_waitcnt vmcnt(12)" ::: "memory");
    else if (kt == 25) asm volatile("s_waitcnt vmcnt(8)" ::: "memory");
    else if (kt == 26) asm volatile("s_waitcnt vmcnt(4)" ::: "memory");
    else               asm volatile("s_waitcnt vmcnt(0)" ::: "memory");
    __builtin_amdgcn_s_barrier();          // buf[kt&3] ready for all waves
    __builtin_amdgcn_sched_barrier(0);     // pin LDS reads after the barrier
    const int bi = kt & 3;
    bf16x8 av[4], bv[4];
    #pragma unroll
    for (int m = 0; m < 4; ++m) {
      const int zr = wr * 64 + m * 16 + lcol;
      av[m] = *reinterpret_cast<const bf16x8*>(&As[bi][zr * 32 + ((qk ^ (zr & 3)) << 3)]);
    }
    #pragma unroll
    for (int n = 0; n < 4; ++n) {
      const int br = wc * 64 + n * 16 + lcol;
      bv[n] = *reinterpret_cast<const bf16x8*>(&Bs[bi][br * 32 + ((qk ^ (br & 3)) << 3)]);
    }
    #pragma unroll
    for (int m = 0; m < 4; ++m)
      #pragma unroll
      for (int n = 0; n < 4; ++n)
        acc[m][n] = __builtin_amdgcn_mfma_f32_16x16x32_bf16(av[m], bv[n], acc[m][n], 0, 0, 0);
    __builtin_amdgcn_sched_barrier(0);     // pin reads before the barrier
    __builtin_amdgcn_s_barrier();          // all reads of buf[kt&3] done
  }

  const int rq = (lane >> 4) * 4;
  #pragma unroll
  for (int n = 0; n < 4; ++n) {
    const int o = wc * 64 + n * 16 + lcol;
    const float bias = b7[s * 128 + o];
    #pragma unroll
    for (int m = 0; m < 4; ++m) {
      #pragma unroll
      for (int rg = 0; rg < 4; ++rg) {
        const int row = b0 + wr * 64 + m * 16 + rq + rg;
        h3[((size_t)row * SQ + s) * 128 + o] = f2bf(fmaxf(acc[m][n][rg] + bias, 0.f));
      }
    }
  }
}

// ---------------- K5: conv1 via MFMA (weights pre-packed) -------------------
__global__ __launch_bounds__(256) void k_conv1(const u16* __restrict__ h3,
                                               const u16* __restrict__ wpk,
                                               const float* __restrict__ cb,
                                               u16* __restrict__ c1T,
                                               float2* __restrict__ part) {
  __shared__ u16 zs[6144];           // h3[b] staging 41*128=5248 (+pad)
  __shared__ u16 zt[130 * 64];       // transposed [l+1][c^swz]
  __shared__ u16 wl[3 * 64 * 64];    // weights [t][o][c^swz]
  __shared__ float2 red[4][64];
  const int b = blockIdx.x;
  const int t = threadIdx.x;
  const int lane = t & 63, wv = t >> 6;

  const u16* src = h3 + (size_t)b * (SQ * 128);
  #pragma unroll
  for (int it = 0; it < 3; ++it)
    gload16(src + ((size_t)it * 256 + t) * 8, (char*)zs + it * 4096 + wv * 1024);
  #pragma unroll
  for (int it = 0; it < 6; ++it)
    gload16(wpk + ((size_t)it * 256 + t) * 8, (char*)wl + it * 4096 + wv * 1024);

  if (t < 64) zt[t] = 0;
  else if (t < 128) zt[129 * 64 + t - 64] = 0;
  __syncthreads();

  {
    const int l = t & 127, jb = (t >> 7) * 32;
    const int sw = ((l + 1) & 7) << 3;
    u16* dst = zt + (l + 1) * 64;
    #pragma unroll
    for (int j = 0; j < 32; ++j) {
      int c = (jb + j + l) & 63;
      dst[c ^ sw] = (c < 41) ? zs[c * 128 + l] : (u16)0;
    }
  }
  __syncthreads();

  f32x4 acc[2][4];
  #pragma unroll
  for (int m = 0; m < 2; ++m)
    #pragma unroll
    for (int n = 0; n < 4; ++n) acc[m][n] = (f32x4){0.f, 0.f, 0.f, 0.f};
  const int r = lane & 15, kq = (lane >> 4) * 8;

  #pragma unroll
  for (int tt = 0; tt < 3; ++tt) {
    #pragma unroll
    for (int kk = 0; kk < 2; ++kk) {
      const int kof = kk * 32 + kq;
      bf16x8 av[2], bv[4];
      #pragma unroll
      for (int m = 0; m < 2; ++m) {
        const int zr = wv * 32 + m * 16 + r + tt;
        av[m] = *reinterpret_cast<const bf16x8*>(zt + zr * 64 + (kof ^ ((zr & 7) << 3)));
      }
      #pragma unroll
      for (int n = 0; n < 4; ++n) {
        const int o = n * 16 + r;
        bv[n] = *reinterpret_cast<const bf16x8*>(wl + (tt * 64 + o) * 64 + (kof ^ ((o & 7) << 3)));
      }
      #pragma unroll
      for (int m = 0; m < 2; ++m)
        #pragma unroll
        for (int n = 0; n < 4; ++n)
          acc[m][n] = __builtin_amdgcn_mfma_f32_16x16x32_bf16(av[m], bv[n], acc[m][n], 0, 0, 0);
    }
  }

  const int q = lane >> 4;
  u16* outb = c1T + (size_t)b * 8192;
  #pragma unroll
  for (int n = 0; n < 4; ++n) {
    const int o = n * 16 + r;
    const float bias = cb[o];
    float s1 = 0.f, s2 = 0.f;
    #pragma unroll
    for (int m = 0; m < 2; ++m) {
      #pragma unroll
      for (int rg = 0; rg < 4; ++rg) {
        float v = acc[m][n][rg] + bias;
        s1 += v; s2 += v * v;
        outb[(wv * 32 + m * 16 + q * 4 + rg) * 64 + o] = f2bf(v);
      }
    }
    s1 += __shfl_xor(s1, 16); s1 += __shfl_xor(s1, 32);
    s2 += __shfl_xor(s2, 16); s2 += __shfl_xor(s2, 32);
    if (lane < 16) red[wv][n * 16 + lane] = make_float2(s1, s2);
  }
  __syncthreads();
  if (t < 64) {
    float S = red[0][t].x + red[1][t].x + red[2][t].x + red[3][t].x;
    float Q = red[0][t].y + red[1][t].y + red[2][t].y + red[3][t].y;
    part[(size_t)t * B + b] = make_float2(S, Q);
  }
}

// ---------------- K6: finalize conv1 BN -> scale/shift per channel ----------
__global__ void k_bnfin(const float2* __restrict__ part, const float* __restrict__ g,
                        const float* __restrict__ bb, float* __restrict__ scale,
                        float* __restrict__ shift) {
  int o = blockIdx.x;
  float s = 0.f, q = 0.f;
  for (int i = threadIdx.x; i < B; i += 256) {
    float2 p = part[(size_t)o * B + i];
    s += p.x; q += p.y;
  }
  #pragma unroll
  for (int off = 32; off; off >>= 1) { s += __shfl_down(s, off); q += __shfl_down(q, off); }
  __shared__ float rs[4], rq[4];
  int wv = threadIdx.x >> 6, ln = threadIdx.x & 63;
  if (ln == 0) { rs[wv] = s; rq[wv] = q; }
  __syncthreads();
  if (threadIdx.x == 0) {
    float S = rs[0] + rs[1] + rs[2] + rs[3];
    float Q = rq[0] + rq[1] + rq[2] + rq[3];
    const float n = (float)B * 128.f;
    float mu = S / n, var = Q / n - mu * mu;
    float sc = g[o] * rsqrtf(var + 1e-5f);
    scale[o] = sc; shift[o] = bb[o] - mu * sc;
  }
}

// ---------------- K7: caps conv + squash + routing + pair/max + fc1 ---------
constexpr int NB = 8;
__global__ __launch_bounds__(256) void k_caps(const u16* __restrict__ c1T,
                                              const float* __restrict__ scale,
                                              const float* __restrict__ shift,
                                              const u16* __restrict__ cpk,
                                              const float* __restrict__ cpb,
                                              const u16* __restrict__ rwp,
                                              const float* __restrict__ f1,
                                              float* __restrict__ y1) {
  __shared__ u16 zt[130 * 64];
  __shared__ u16 wl[3 * 64 * 32];
  __shared__ float f1l[128 * 64];
  __shared__ float red[4][64];
  __shared__ float fl[64];
  __shared__ float sc_s[64], sh_s[64];
  __shared__ float red2[4][2];
  __shared__ float yl[2][128];
  __shared__ float pt[128];
  const int b0 = blockIdx.x * NB;
  const int t = threadIdx.x;
  const int lane = t & 63, wv = t >> 6;
  const int r = lane & 15, kq = (lane >> 4) * 8, q = lane >> 4;

  #pragma unroll
  for (int it = 0; it < 3; ++it)
    gload16(cpk + ((size_t)it * 256 + t) * 8, (char*)wl + it * 4096 + wv * 1024);
  #pragma unroll
  for (int it = 0; it < 8; ++it)
    gload16(f1 + ((size_t)it * 256 + t) * 4, (char*)f1l + it * 4096 + wv * 1024);
  if (t < 64) { sc_s[t] = scale[t]; sh_s[t] = shift[t]; }
  if (t < 64) zt[t] = 0;
  else if (t < 128) zt[129 * 64 + t - 64] = 0;

  uint4 raw[4], rawn[4];
  {
    const u16* src = c1T + (size_t)b0 * 8192;
    #pragma unroll
    for (int p = 0; p < 4; ++p)
      raw[p] = *reinterpret_cast<const uint4*>(src + ((size_t)t + p * 256) * 8);
  }

  for (int i = 0; i < NB; ++i) {
    const int b = b0 + i;
    __syncthreads();

    #pragma unroll
    for (int p = 0; p < 4; ++p) {
      int idx = t + p * 256;
      int l = idx >> 3, c0 = (idx & 7) * 8;
      float vv[8];
      vv[0] = __uint_as_float(raw[p].x << 16); vv[1] = __uint_as_float(raw[p].x & 0xffff0000u);
      vv[2] = __uint_as_float(raw[p].y << 16); vv[3] = __uint_as_float(raw[p].y & 0xffff0000u);
      vv[4] = __uint_as_float(raw[p].z << 16); vv[5] = __uint_as_float(raw[p].z & 0xffff0000u);
      vv[6] = __uint_as_float(raw[p].w << 16); vv[7] = __uint_as_float(raw[p].w & 0xffff0000u);
      float a0 = fmaxf(fmaf(vv[0], sc_s[c0 + 0], sh_s[c0 + 0]), 0.f);
      float a1 = fmaxf(fmaf(vv[1], sc_s[c0 + 1], sh_s[c0 + 1]), 0.f);
      float a2 = fmaxf(fmaf(vv[2], sc_s[c0 + 2], sh_s[c0 + 2]), 0.f);
      float a3 = fmaxf(fmaf(vv[3], sc_s[c0 + 3], sh_s[c0 + 3]), 0.f);
      float a4 = fmaxf(fmaf(vv[4], sc_s[c0 + 4], sh_s[c0 + 4]), 0.f);
      float a5 = fmaxf(fmaf(vv[5], sc_s[c0 + 5], sh_s[c0 + 5]), 0.f);
      float a6 = fmaxf(fmaf(vv[6], sc_s[c0 + 6], sh_s[c0 + 6]), 0.f);
      float a7 = fmaxf(fmaf(vv[7], sc_s[c0 + 7], sh_s[c0 + 7]), 0.f);
      uint4 pk;
      pk.x = pack2(a0, a1); pk.y = pack2(a2, a3);
      pk.z = pack2(a4, a5); pk.w = pack2(a6, a7);
      *reinterpret_cast<uint4*>(zt + (l + 1) * 64 + (c0 ^ (((l + 1) & 7) << 3))) = pk;
    }
    if (i + 1 < NB) {
      const u16* srcn = c1T + (size_t)(b + 1) * 8192;
      #pragma unroll
      for (int p = 0; p < 4; ++p)
        rawn[p] = *reinterpret_cast<const uint4*>(srcn + ((size_t)t + p * 256) * 8);
    }
    __syncthreads();

    f32x4 acc[2][4];
    #pragma unroll
    for (int m = 0; m < 2; ++m)
      #pragma unroll
      for (int n = 0; n < 4; ++n) acc[m][n] = (f32x4){0.f, 0.f, 0.f, 0.f};
    #pragma unroll
    for (int tt = 0; tt < 3; ++tt) {
      bf16x8 av[2][2], bv[4];
      #pragma unroll
      for (int m = 0; m < 2; ++m) {
        const int zr = wv * 32 + m * 16 + r + tt;
        const int sw = (zr & 7) << 3;
        av[m][0] = *reinterpret_cast<const bf16x8*>(zt + zr * 64 + (kq ^ sw));
        av[m][1] = *reinterpret_cast<const bf16x8*>(zt + zr * 64 + ((32 + kq) ^ sw));
      }
      #pragma unroll
      for (int n = 0; n < 4; ++n) {
        const int o = n * 16 + r;
        bv[n] = *reinterpret_cast<const bf16x8*>(wl + (tt * 64 + o) * 32 + (kq ^ ((o & 3) << 3)));
      }
      #pragma unroll
      for (int m = 0; m < 2; ++m)
        #pragma unroll
        for (int n = 0; n < 4; ++n)
          acc[m][n] = __builtin_amdgcn_mfma_f32_16x16x32_bf16(av[m][n >> 1], bv[n], acc[m][n], 0, 0, 0);
    }

    #pragma unroll
    for (int n = 0; n < 4; ++n) {
      const int o = n * 16 + r;
      const float bias = cpb[o];
      float s2 = 0.f;
      #pragma unroll
      for (int m = 0; m < 2; ++m) {
        #pragma unroll
        for (int rg = 0; rg < 4; ++rg) {
          float v = acc[m][n][rg] + bias;
          acc[m][n][rg] = v;
          s2 += v * v;
        }
      }
      s2 += __shfl_xor(s2, 16); s2 += __shfl_xor(s2, 32);
      if (lane < 16) red[wv][n * 16 + lane] = s2;
    }
    __syncthreads();
    if (t < 64) {
      float S = red[0][t] + red[1][t] + red[2][t] + red[3][t];
      float nn = sqrtf(S);
      fl[t] = (1.f - 1.f / (expf(nn) + 1e-21f)) / (nn + 1e-21f);
    }
    __syncthreads();

    float s0[2][4], s1[2][4];
    #pragma unroll
    for (int m = 0; m < 2; ++m)
      #pragma unroll
      for (int rg = 0; rg < 4; ++rg) { s0[m][rg] = 0.f; s1[m][rg] = 0.f; }
    #pragma unroll
    for (int n = 0; n < 4; ++n) {
      const int o = n * 16 + r;
      const float fact = fl[o];
      #pragma unroll
      for (int m = 0; m < 2; ++m) {
        const int l0 = wv * 32 + m * 16 + q * 4;
        uint2 rw0 = *reinterpret_cast<const uint2*>(rwp + (size_t)o * 128 + l0);
        uint2 rw1 = *reinterpret_cast<const uint2*>(rwp + (size_t)(64 + o) * 128 + l0);
        #pragma unroll
        for (int rg = 0; rg < 4; ++rg) {
          float v = acc[m][n][rg] * fact;
          u32 w0w = (rg < 2) ? rw0.x : rw0.y;
          u32 w1w = (rg < 2) ? rw1.x : rw1.y;
          float w0 = __uint_as_float((rg & 1) ? (w0w & 0xffff0000u) : (w0w << 16));
          float w1 = __uint_as_float((rg & 1) ? (w1w & 0xffff0000u) : (w1w << 16));
          s0[m][rg] = fmaf(v, w0, s0[m][rg]);
          s1[m][rg] = fmaf(v, w1, s1[m][rg]);
        }
      }
    }
    #pragma unroll
    for (int m = 0; m < 2; ++m)
      #pragma unroll
      for (int rg = 0; rg < 4; ++rg) {
        #pragma unroll
        for (int off = 1; off <= 8; off <<= 1) {
          s0[m][rg] += __shfl_xor(s0[m][rg], off);
          s1[m][rg] += __shfl_xor(s1[m][rg], off);
        }
      }
    float n0 = 0.f, n1 = 0.f;
    #pragma unroll
    for (int m = 0; m < 2; ++m)
      #pragma unroll
      for (int rg = 0; rg < 4; ++rg) {
        n0 = fmaf(s0[m][rg], s0[m][rg], n0);
        n1 = fmaf(s1[m][rg], s1[m][rg], n1);
      }
    n0 += __shfl_xor(n0, 16); n0 += __shfl_xor(n0, 32);
    n1 += __shfl_xor(n1, 16); n1 += __shfl_xor(n1, 32);
    if (lane == 0) { red2[wv][0] = n0; red2[wv][1] = n1; }
    __syncthreads();
    {
      float t0 = red2[0][0] + red2[1][0] + red2[2][0] + red2[3][0];
      float t1 = red2[0][1] + red2[1][1] + red2[2][1] + red2[3][1];
      float nn0 = sqrtf(t0), nn1 = sqrtf(t1);
      float fa0 = (1.f - 1.f / (expf(nn0) + 1e-21f)) / (nn0 + 1e-21f);
      float fa1 = (1.f - 1.f / (expf(nn1) + 1e-21f)) / (nn1 + 1e-21f);
      if (r == 0) {
        #pragma unroll
        for (int m = 0; m < 2; ++m)
          #pragma unroll
          for (int rg = 0; rg < 4; ++rg) {
            float v0 = s0[m][rg] * fa0, v1 = s1[m][rg] * fa1;
            float mx = fmaxf(v0, v1);
            int l = wv * 32 + m * 16 + q * 4 + rg;
            yl[0][l] = v0 + mx;
            yl[1][l] = v1 + mx;
          }
      }
    }
    __syncthreads();

    {
      const int h = t >> 7, idx = t & 127;
      const int jj = idx >> 6, qq = idx & 63;
      float a = 0.f;
      const float* yrow = &yl[jj][h * 64];
      const float* frow = f1l + (h * 64) * 64 + qq;
      #pragma unroll 8
      for (int tt = 0; tt < 64; ++tt)
        a = fmaf(yrow[tt], frow[tt * 64], a);
      if (h == 1) pt[idx] = a;
      __syncthreads();
      if (h == 0)
        y1[((size_t)b * 2 + jj) * 64 + qq] = a + pt[idx];
    }

    #pragma unroll
    for (int p = 0; p < 4; ++p) raw[p] = rawn[p];
  }
}

// ---------------- K9: BN stats stage 1 — partial sums over [B][2][per] ------
__global__ __launch_bounds__(256) void k_bnstat_part(const float* __restrict__ y,
                                                     float2* __restrict__ pp,
                                                     int perShift) {
  const int jj = blockIdx.y;
  const int per = 1 << perShift;
  const int n4 = (B << perShift) >> 2;
  const int p4shift = perShift - 2;
  const int p4mask = (per >> 2) - 1;
  float s = 0.f, q = 0.f;
  for (int i = blockIdx.x * 256 + threadIdx.x; i < n4; i += 64 * 256) {
    int bI = i >> p4shift, c4 = (i & p4mask) * 4;
    float4 v = *reinterpret_cast<const float4*>(
        y + (size_t)bI * (per * 2) + jj * per + c4);
    s += v.x + v.y + v.z + v.w;
    q += v.x * v.x + v.y * v.y + v.z * v.z + v.w * v.w;
  }
  #pragma unroll
  for (int off = 32; off; off >>= 1) { s += __shfl_down(s, off); q += __shfl_down(q, off); }
  __shared__ float rs[4], rq[4];
  int wv = threadIdx.x >> 6, ln = threadIdx.x & 63;
  if (ln == 0) { rs[wv] = s; rq[wv] = q; }
  __syncthreads();
  if (threadIdx.x == 0)
    pp[jj * 64 + blockIdx.x] =
        make_float2(rs[0] + rs[1] + rs[2] + rs[3], rq[0] + rq[1] + rq[2] + rq[3]);
}

// ---------------- K9b: BN stats stage 2 — 64 partials -> scale/shift --------
__global__ void k_bnstat_fin(const float2* __restrict__ pp, const float* __restrict__ g,
                             const float* __restrict__ bb, float* __restrict__ scale,
                             float* __restrict__ shift, int perShift) {
  const int jj = blockIdx.x;
  float2 p = pp[jj * 64 + threadIdx.x];
  float s = p.x, q = p.y;
  #pragma unroll
  for (int off = 32; off; off >>= 1) { s += __shfl_down(s, off); q += __shfl_down(q, off); }
  if (threadIdx.x == 0) {
    float fn = (float)(B << perShift);
    float mu = s / fn, var = q / fn - mu * mu;
    float sc = g[jj] * rsqrtf(var + 1e-5f);
    scale[jj] = sc; shift[jj] = bb[jj] - mu * sc;
  }
}

// ---------------- K10: bn1+relu+fc2 -----------------------------------------
__global__ void k_fc2(const float* __restrict__ y1, const float* __restrict__ sc1,
                      const float* __restrict__ sh1, const float* __restrict__ f2,
                      float* __restrict__ y2) {
  int t = threadIdx.x;
  int b = blockIdx.x * 4 + (t >> 6);
  int jj = (t >> 5) & 1, r = t & 31;
  float sc = sc1[jj], sh = sh1[jj];
  const float* yb = y1 + (size_t)b * 128 + jj * 64;
  float acc = 0.f;
  for (int q = 0; q < 64; ++q) {
    float v = fmaxf(fmaf(yb[q], sc, sh), 0.f);
    acc = fmaf(v, f2[q * 32 + r], acc);
  }
  y2[(size_t)b * 64 + jj * 32 + r] = acc;
}

// ---------------- K12: bn2+relu+fc3+sigmoid+max -----------------------------
__global__ void k_head(const float* __restrict__ y2, const float* __restrict__ sc2,
                       const float* __restrict__ sh2, const float* __restrict__ f3,
                       float* __restrict__ out) {
  int b = blockIdx.x * 256 + threadIdx.x;
  if (b >= B) return;
  const float* yb = y2 + (size_t)b * 64;
  float c0 = sc2[0], d0 = sh2[0], c1v = sc2[1], d1 = sh2[1];
  float a0 = 0.f, a1 = 0.f;
  for (int r = 0; r < 32; ++r) {
    float w = f3[r];
    a0 = fmaf(fmaxf(fmaf(yb[r], c0, d0), 0.f), w, a0);
    a1 = fmaf(fmaxf(fmaf(yb[32 + r], c1v, d1), 0.f), w, a1);
  }
  float s0 = 1.f / (1.f + expf(-a0));
  float s1 = 1.f / (1.f + expf(-a1));
  out[b] = fmaxf(s0, s1);
}

// ---------------- workspace layout ------------------------------------------
constexpr size_t SZ_H2    = (size_t)B * SQ * 128 * 2;   // 42,991,616 (bf16)
constexpr size_t SZ_C1    = (size_t)B * 64 * 128 * 2;   // 67,108,864 (bf16)
constexpr size_t OFF_H2   = 0;
constexpr size_t OFF_H3   = SZ_H2;
constexpr size_t R1       = 2 * SZ_H2;         // 85,983,232
constexpr size_t OFF_G    = R1;                                 // 314,880
constexpr size_t OFF_T1   = OFF_G + 314880;                     // 2,624,000
constexpr size_t OFF_T2   = OFF_T1 + 2624000;                   // 6,560,000 (bf16)
constexpr size_t OFF_CMB  = OFF_T2 + 6560000;                   //   671,744
constexpr size_t OFF_W7T  = OFF_CMB + 671744;  // 9,404,416 bf16; dead by K5
constexpr size_t OFF_ZP   = OFF_W7T + 9404416; // 8,192 zero page (live: pack->gemm7)
constexpr size_t OFF_C1   = R1;                // overlaps tables+w7t+zp (dead by K5)
constexpr size_t R2       = R1 + SZ_C1;        // 153,092,096
constexpr size_t OFF_PART = R2;                                 // 2,097,152
constexpr size_t OFF_Y1   = OFF_PART + 2097152;                 // 2,097,152
constexpr size_t OFF_Y2   = OFF_Y1 + 2097152;                   // 1,048,576
constexpr size_t OFF_SM   = OFF_Y2 + 1048576;                   //     1,024
constexpr size_t OFF_BNP  = OFF_SM + 1024;                      //     1,024
constexpr size_t OFF_WPK  = OFF_BNP + 1024;                     //    24,576
constexpr size_t OFF_CPK  = OFF_WPK + 24576;                    //    12,288
constexpr size_t OFF_RWP  = OFF_CPK + 12288;                    //    32,768

extern "C" void kernel_launch(void* const* d_in, const int* in_sizes, int n_in,
                              void* d_out, int out_size, void* d_ws, size_t ws_size,
                              hipStream_t stream) {
  const int*   x   = (const int*)d_in[0];
  const float* emb = (const float*)d_in[1];
  const float* W3  = (const float*)d_in[2];
  const float* b3  = (const float*)d_in[3];
  const float* W5  = (const float*)d_in[4];
  const float* b5  = (const float*)d_in[5];
  const float* W7  = (const float*)d_in[6];
  const float* b7  = (const float*)d_in[7];
  const float* c1w = (const float*)d_in[8];
  const float* c1b = (const float*)d_in[9];
  const float* bng = (const float*)d_in[10];
  const float* bnb = (const float*)d_in[11];
  const float* cpw = (const float*)d_in[12];
  const float* cpb = (const float*)d_in[13];
  const float* rW  = (const float*)d_in[14];
  const float* rb  = (const float*)d_in[15];
  const float* f1  = (const float*)d_in[16];
  const float* g1  = (const float*)d_in[17];
  const float* bb1 = (const float*)d_in[18];
  const float* f2  = (const float*)d_in[19];
  const float* g2  = (const float*)d_in[20];
  const float* bb2 = (const float*)d_in[21];
  const float* f3  = (const float*)d_in[22];

  char* wsb = (char*)d_ws;
  u16*    h2p   = (u16*)(wsb + OFF_H2);
  u16*    h3p   = (u16*)(wsb + OFF_H3);
  float*  Gp    = (float*)(wsb + OFF_G);
  float*  t1p   = (float*)(wsb + OFF_T1);
  u16*    t2p   = (u16*)(wsb + OFF_T2);
  int*    cmbp  = (int*)(wsb + OFF_CMB);
  u16*    w7tp  = (u16*)(wsb + OFF_W7T);
  u16*    zpp   = (u16*)(wsb + OFF_ZP);
  u16*    c1p   = (u16*)(wsb + OFF_C1);
  float2* partp = (float2*)(wsb + OFF_PART);
  float*  y1p   = (float*)(wsb + OFF_Y1);
  float*  y2p   = (float*)(wsb + OFF_Y2);
  float*  scp   = (float*)(wsb + OFF_SM);
  float*  shp   = scp + 64;
  float*  sc1p  = shp + 64;
  float*  sh1p  = sc1p + 2;
  float*  sc2p  = sh1p + 2;
  float*  sh2p  = sc2p + 2;
  float2* bnpp  = (float2*)(wsb + OFF_BNP);
  u16*    wpkp  = (u16*)(wsb + OFF_WPK);
  u16*    cpkp  = (u16*)(wsb + OFF_CPK);
  u16*    rwpp  = (u16*)(wsb + OFF_RWP);

  k_pack<<<152, 256, 0, stream>>>(c1w, cpw, rW, rb, wpkp, cpkp, rwpp, zpp);
  k_combo<<<(B * SQ + 255) / 256, 256, 0, stream>>>(x, cmbp);
  k_w7t<<<dim3(14, 2, SQ), 256, 0, stream>>>(W7, w7tp);
  k_gmat<<<SQ * 3, 128, 0, stream>>>(emb, W3, Gp);
  k_t1<<<(SQ * 128 * 125 + 255) / 256, 256, 0, stream>>>(Gp, b3, t1p);
  k_t2<<<SQ * 25, 128, 0, stream>>>(t1p, W5, t2p);
  k_h2<<<(B * SQ * 16) / 256, 256, 0, stream>>>(t2p, cmbp, b5, h2p);
  k_gemm7_mfma<<<dim3(32, SQ), 256, 0, stream>>>(h2p, w7tp, b7, zpp, h3p);
  k_conv1<<<B, 256, 0, stream>>>(h3p, wpkp, c1b, c1p, partp);
  k_bnfin<<<64, 256, 0, stream>>>(partp, bng, bnb, scp, shp);
  k_caps<<<B / NB, 256, 0, stream>>>(c1p, scp, shp, cpkp, cpb, rwpp, f1, y1p);
  k_bnstat_part<<<dim3(64, 2), 256, 0, stream>>>(y1p, bnpp, 6);
  k_bnstat_fin<<<2, 64, 0, stream>>>(bnpp, g1, bb1, sc1p, sh1p, 6);
  k_fc2<<<B / 4, 256, 0, stream>>>(y1p, sc1p, sh1p, f2, y2p);
  k_bnstat_part<<<dim3(64, 2), 256, 0, stream>>>(y2p, bnpp, 5);
  k_bnstat_fin<<<2, 64, 0, stream>>>(bnpp, g2, bb2, sc2p, sh2p, 5);
  k_head<<<B / 256, 256, 0, stream>>>(y2p, sc2p, sh2p, f3, (float*)d_out);
}

// Round 11
// 244.173 us; speedup vs baseline: 1.0648x; 1.0648x over previous
//
#include <hip/hip_runtime.h>
#include <cstdint>

typedef unsigned short u16;
typedef unsigned int   u32;
typedef __attribute__((ext_vector_type(8))) short bf16x8;
typedef __attribute__((ext_vector_type(4))) float f32x4;

#define DEVFN static __device__ __forceinline__

constexpr int B  = 4096;
constexpr int SQ = 41;

DEVFN float bf2f(u16 v) { return __uint_as_float(((u32)v) << 16); }
DEVFN u16 f2bf(float f) {
  u32 u = __float_as_uint(f);
  u += 0x7fffu + ((u >> 16) & 1u);
  return (u16)(u >> 16);
}
DEVFN u32 pack2(float a, float b) { return (u32)f2bf(a) | ((u32)f2bf(b) << 16); }

DEVFN void gload16(const void* g, void* l) {
  __builtin_amdgcn_global_load_lds(
      (const __attribute__((address_space(1))) unsigned int*)g,
      (__attribute__((address_space(3))) unsigned int*)l, 16, 0, 0);
}

// ---------------- K-1: pack weights into swizzled bf16 global images --------
__global__ void k_pack(const float* __restrict__ cw, const float* __restrict__ cpw,
                       const float* __restrict__ rW, const float* __restrict__ rb,
                       u16* __restrict__ wpk, u16* __restrict__ cpk,
                       u16* __restrict__ rwp) {
  int i = blockIdx.x * 256 + threadIdx.x;
  if (i < 12288) {                    // conv1 weights [t][o][c^swz], c padded 64
    int tt = i >> 12, rem = i & 4095, o = rem >> 6, c = rem & 63;
    float v = (c < 41) ? cw[(o * 41 + c) * 3 + tt] : 0.f;
    wpk[(tt * 64 + o) * 64 + (c ^ ((o & 7) << 3))] = f2bf(v);
  } else if (i < 18432) {             // caps weights [t][o][cg^swz]
    int k = i - 12288;
    int tt = k >> 11, rem = k & 2047, o = rem >> 5, c = rem & 31;
    cpk[(tt * 64 + o) * 32 + (c ^ ((o & 3) << 3))] = f2bf(cpw[(o * 32 + c) * 3 + tt]);
  } else if (i < 34816) {             // routing weights [j*64+o][l] * (1+rb)
    int k = i - 18432;
    rwp[k] = f2bf(rW[k] * (1.f + rb[k >> 7]));
  }
}

// ---------------- K0: combo indices [B][41], symbols 0..3, pad=4 -------------
__global__ void k_combo(const int* __restrict__ x, int* __restrict__ combo) {
  int i = blockIdx.x * 256 + threadIdx.x;
  if (i >= B * SQ) return;
  int b = i / SQ, s = i - b * SQ;
  const int* xb = x + b * SQ;
  int d0 = (s > 0) ? xb[s - 1] : 4;
  int d1 = xb[s];
  int d2 = (s < SQ - 1) ? xb[s + 1] : 4;
  combo[i] = d0 * 25 + d1 * 5 + d2;
}

// ---------------- K1a: G[s][w][sym][o] = sum_f emb[sym][f]*W3[s][w*128+f][o] -
__global__ void k_gmat(const float* __restrict__ emb, const float* __restrict__ W3,
                       float* __restrict__ G) {
  int s = blockIdx.x / 3, ww = blockIdx.x % 3;
  int o = threadIdx.x;
  const float* Ws = W3 + ((size_t)s * 384 + ww * 128) * 128;
  float a0 = 0.f, a1 = 0.f, a2 = 0.f, a3 = 0.f;
  for (int f = 0; f < 128; ++f) {
    float wg = Ws[(size_t)f * 128 + o];
    a0 = fmaf(emb[f], wg, a0);
    a1 = fmaf(emb[128 + f], wg, a1);
    a2 = fmaf(emb[256 + f], wg, a2);
    a3 = fmaf(emb[384 + f], wg, a3);
  }
  float* Gp = G + ((size_t)(s * 3 + ww) * 5) * 128 + o;
  Gp[0] = a0; Gp[128] = a1; Gp[256] = a2; Gp[384] = a3; Gp[512] = 0.f;
}

// ---------------- K1b: t1T[s][o][v] = relu(b3 + G0+G1+G2)  (transposed) -----
__global__ void k_t1(const float* __restrict__ G, const float* __restrict__ b3,
                     float* __restrict__ t1T) {
  int i = blockIdx.x * 256 + threadIdx.x;
  if (i >= SQ * 128 * 125) return;
  int v = i % 125, so = i / 125;
  int s = so >> 7, o = so & 127;
  int d0 = v / 25, r = v % 25;
  int d1 = r / 5, d2 = r % 5;
  float acc = b3[so]
      + G[((size_t)(s * 3 + 0) * 5 + d0) * 128 + o]
      + G[((size_t)(s * 3 + 1) * 5 + d1) * 128 + o]
      + G[((size_t)(s * 3 + 2) * 5 + d2) * 128 + o];
  t1T[i] = fmaxf(acc, 0.f);
}

// ---------------- K2: t2[s][w][v][o] (bf16) = sum_f t1[s+w-2][v][f]*W5[..] --
__global__ __launch_bounds__(128) void k_t2(const float* __restrict__ t1T,
                                            const float* __restrict__ W5,
                                            u16* __restrict__ t2) {
  int bx = blockIdx.x;
  int s = bx / 25; int r = bx % 25;
  int ww = r / 5;  int vt = (r % 5) * 25;
  int o = threadIdx.x;
  int t = s + ww - 2;
  u16* dst = t2 + ((size_t)(s * 5 + ww) * 125 + vt) * 128 + o;
  if (t < 0 || t >= SQ) {
    #pragma unroll
    for (int v = 0; v < 25; ++v) dst[(size_t)v * 128] = 0;
    return;
  }
  float acc[25];
  #pragma unroll
  for (int v = 0; v < 25; ++v) acc[v] = 0.f;
  const float* Ws = W5 + ((size_t)s * 640 + ww * 128) * 128;
  const float* tp = t1T + (size_t)t * 128 * 125 + vt;
  for (int f = 0; f < 128; ++f) {
    float wg = Ws[(size_t)f * 128 + o];
    #pragma unroll
    for (int v = 0; v < 25; ++v) acc[v] = fmaf(tp[f * 125 + v], wg, acc[v]);
  }
  #pragma unroll
  for (int v = 0; v < 25; ++v) dst[(size_t)v * 128] = f2bf(acc[v]);
}

// ---------------- K3: h2[b][s][o] = relu(b5 + sum_w t2[s][w][combo]) --------
__global__ __launch_bounds__(256) void k_h2(const u16* __restrict__ t2,
                                            const int* __restrict__ combo,
                                            const float* __restrict__ b5,
                                            u16* __restrict__ h2) {
  const int i = blockIdx.x * 256 + threadIdx.x;   // B*41*16 total
  const int o8 = (i & 15) * 8;
  const int rid = i >> 4;                          // s-major: s = rid>>12
  const int s = rid >> 12, b = rid & 4095;
  float acc[8];
  {
    float4 b0 = *reinterpret_cast<const float4*>(b5 + s * 128 + o8);
    float4 b1 = *reinterpret_cast<const float4*>(b5 + s * 128 + o8 + 4);
    acc[0] = b0.x; acc[1] = b0.y; acc[2] = b0.z; acc[3] = b0.w;
    acc[4] = b1.x; acc[5] = b1.y; acc[6] = b1.z; acc[7] = b1.w;
  }
  const int* cb = combo + b * SQ;
  #pragma unroll
  for (int ww = 0; ww < 5; ++ww) {
    const int t = s + ww - 2;
    if (0 <= t && t < SQ) {
      const int c = cb[t];
      uint4 raw = *reinterpret_cast<const uint4*>(
          t2 + ((size_t)(s * 5 + ww) * 125 + c) * 128 + o8);
      acc[0] += __uint_as_float(raw.x << 16);
      acc[1] += __uint_as_float(raw.x & 0xffff0000u);
      acc[2] += __uint_as_float(raw.y << 16);
      acc[3] += __uint_as_float(raw.y & 0xffff0000u);
      acc[4] += __uint_as_float(raw.z << 16);
      acc[5] += __uint_as_float(raw.z & 0xffff0000u);
      acc[6] += __uint_as_float(raw.w << 16);
      acc[7] += __uint_as_float(raw.w & 0xffff0000u);
    }
  }
  uint4 pk;
  pk.x = pack2(fmaxf(acc[0], 0.f), fmaxf(acc[1], 0.f));
  pk.y = pack2(fmaxf(acc[2], 0.f), fmaxf(acc[3], 0.f));
  pk.z = pack2(fmaxf(acc[4], 0.f), fmaxf(acc[5], 0.f));
  pk.w = pack2(fmaxf(acc[6], 0.f), fmaxf(acc[7], 0.f));
  *reinterpret_cast<uint4*>(h2 + ((size_t)b * SQ + s) * 128 + o8) = pk;
}

// ---------------- K4a: W7 [41][896][128] f32 -> w7t [41][128][896] bf16 -----
__global__ __launch_bounds__(256) void k_w7t(const float* __restrict__ W7,
                                             u16* __restrict__ w7t) {
  __shared__ float tile[64][65];
  const int s = blockIdx.z;
  const int k0 = blockIdx.x * 64;   // 896/64 = 14
  const int o0 = blockIdx.y * 64;   // 128/64 = 2
  const int t = threadIdx.x;
  #pragma unroll
  for (int i = 0; i < 16; ++i) {
    int idx = t + i * 256;
    int kl = idx >> 6, ol = idx & 63;
    tile[kl][ol] = W7[((size_t)s * 896 + k0 + kl) * 128 + o0 + ol];
  }
  __syncthreads();
  #pragma unroll
  for (int i = 0; i < 16; ++i) {
    int idx = t + i * 256;
    int ol = idx >> 6, kl = idx & 63;
    w7t[((size_t)s * 128 + o0 + ol) * 896 + k0 + kl] = f2bf(tile[kl][ol]);
  }
}

// ---------------- K4b: layer-3 GEMM, BK=64 dbuf + counted vmcnt pipeline ----
// R8-best structure (8-granule both-sides swizzle, s-major 2D grid => FETCH
// stays ~59 MB) + 2-phase double buffer: stage(t+1) issued BEFORE the counted
// s_waitcnt on stage(t)'s loads, so next-tile loads stay in flight across the
// barrier (T3-min + T4). No XCD swizzle (R9 showed it wrecks L2 locality here).
__global__ __launch_bounds__(256) void k_gemm7_mfma(const u16* __restrict__ h2,
                                                    const u16* __restrict__ w7t,
                                                    const float* __restrict__ b7,
                                                    u16* __restrict__ h3) {
  __shared__ u16 As[2][8192];   // [buf][row][k-granule^swz] 2x16 KB
  __shared__ u16 Bs[2][8192];   // [buf][o][k-granule^swz]   2x16 KB
  const int s  = blockIdx.y;
  const int b0 = blockIdx.x * 128;
  const int t  = threadIdx.x;
  const int lane = t & 63, w = t >> 6;
  const int wr = w >> 1, wc = w & 1;            // wave -> 64x64 quadrant
  const int lcol = lane & 15, qk = lane >> 4;   // qk: k-granule quarter 0..3

  f32x4 acc[4][4];
  #pragma unroll
  for (int i = 0; i < 4; ++i)
    #pragma unroll
    for (int j = 0; j < 4; ++j) acc[i][j] = (f32x4){0.f, 0.f, 0.f, 0.f};

  const u16* wbase = w7t + (size_t)s * 128 * 896;

  // stage tile `kt` (kt in [0,14)) into buffer bi; returns #vm loads issued
  auto stage = [&](int kt, int bi) -> int {
    const int k0 = kt * 64;
    const int ww = k0 >> 7, tr = s + ww - 3, kf0 = k0 & 127;
    int issued = 0;
    if (0 <= tr && tr < SQ) {
      #pragma unroll
      for (int it = 0; it < 4; ++it) {
        const int L = it * 4096 + t * 16;       // dest byte offset
        const int r = L >> 7;                   // tile row 0..127
        const int g = (L >> 4) & 7;             // dest 16B granule in row
        const int gs = g ^ (r & 7);             // pre-swizzled source granule
        gload16(h2 + ((size_t)(b0 + r) * SQ + tr) * 128 + kf0 + gs * 8,
                (char*)As[bi] + it * 4096 + w * 1024);
      }
      issued += 4;
    } else {
      #pragma unroll
      for (int it = 0; it < 4; ++it)
        *reinterpret_cast<uint4*>((char*)As[bi] + it * 4096 + t * 16) =
            make_uint4(0u, 0u, 0u, 0u);
    }
    #pragma unroll
    for (int it = 0; it < 4; ++it) {
      const int L = it * 4096 + t * 16;
      const int o = L >> 7;
      const int g = (L >> 4) & 7;
      const int gs = g ^ (o & 7);
      gload16(wbase + (size_t)o * 896 + k0 + gs * 8,
              (char*)Bs[bi] + it * 4096 + w * 1024);
    }
    return issued + 4;
  };

  stage(0, 0);   // prologue

  for (int kt = 0; kt < 14; ++kt) {
    const int cur = kt & 1;
    int ni = 0;
    if (kt < 13) ni = stage(kt + 1, cur ^ 1);
    // wait only for tile-kt's loads (the ni newer ones stay in flight);
    // lgkmcnt(0) drains zero-fill ds_writes.
    if (ni == 8)      asm volatile("s_waitcnt vmcnt(8) lgkmcnt(0)" ::: "memory");
    else if (ni == 4) asm volatile("s_waitcnt vmcnt(4) lgkmcnt(0)" ::: "memory");
    else              asm volatile("s_waitcnt vmcnt(0) lgkmcnt(0)" ::: "memory");
    __builtin_amdgcn_sched_barrier(0);
    __builtin_amdgcn_s_barrier();          // buf[cur] ready for all waves
    __builtin_amdgcn_sched_barrier(0);     // pin LDS reads after the barrier

    const u16* Ac = As[cur];
    const u16* Bc = Bs[cur];
    #pragma unroll
    for (int kk = 0; kk < 2; ++kk) {
      const int gk = kk * 4 + qk;          // logical k-granule 0..7
      bf16x8 av[4], bv[4];
      #pragma unroll
      for (int m = 0; m < 4; ++m) {
        const int zr = wr * 64 + m * 16 + lcol;
        av[m] = *reinterpret_cast<const bf16x8*>(Ac + zr * 64 + ((gk ^ (zr & 7)) << 3));
      }
      #pragma unroll
      for (int n = 0; n < 4; ++n) {
        const int br = wc * 64 + n * 16 + lcol;
        bv[n] = *reinterpret_cast<const bf16x8*>(Bc + br * 64 + ((gk ^ (br & 7)) << 3));
      }
      #pragma unroll
      for (int m = 0; m < 4; ++m)
        #pragma unroll
        for (int n = 0; n < 4; ++n)
          acc[m][n] = __builtin_amdgcn_mfma_f32_16x16x32_bf16(av[m], bv[n], acc[m][n], 0, 0, 0);
    }
    __builtin_amdgcn_sched_barrier(0);     // pin LDS reads before the barrier
    __builtin_amdgcn_s_barrier();          // all reads of buf[cur] done before
                                           // iter kt+1 stages into it
  }

  const int rq = (lane >> 4) * 4;
  #pragma unroll
  for (int n = 0; n < 4; ++n) {
    const int o = wc * 64 + n * 16 + lcol;
    const float bias = b7[s * 128 + o];
    #pragma unroll
    for (int m = 0; m < 4; ++m) {
      #pragma unroll
      for (int rg = 0; rg < 4; ++rg) {
        const int row = b0 + wr * 64 + m * 16 + rq + rg;
        h3[((size_t)row * SQ + s) * 128 + o] = f2bf(fmaxf(acc[m][n][rg] + bias, 0.f));
      }
    }
  }
}

// ---------------- K5: conv1 via MFMA (weights pre-packed) -------------------
__global__ __launch_bounds__(256) void k_conv1(const u16* __restrict__ h3,
                                               const u16* __restrict__ wpk,
                                               const float* __restrict__ cb,
                                               u16* __restrict__ c1T,
                                               float2* __restrict__ part) {
  __shared__ u16 zs[6144];           // h3[b] staging 41*128=5248 (+pad)
  __shared__ u16 zt[130 * 64];       // transposed [l+1][c^swz]
  __shared__ u16 wl[3 * 64 * 64];    // weights [t][o][c^swz]
  __shared__ float2 red[4][64];
  const int b = blockIdx.x;
  const int t = threadIdx.x;
  const int lane = t & 63, wv = t >> 6;

  const u16* src = h3 + (size_t)b * (SQ * 128);
  #pragma unroll
  for (int it = 0; it < 3; ++it)
    gload16(src + ((size_t)it * 256 + t) * 8, (char*)zs + it * 4096 + wv * 1024);
  #pragma unroll
  for (int it = 0; it < 6; ++it)
    gload16(wpk + ((size_t)it * 256 + t) * 8, (char*)wl + it * 4096 + wv * 1024);

  if (t < 64) zt[t] = 0;
  else if (t < 128) zt[129 * 64 + t - 64] = 0;
  __syncthreads();

  {
    const int l = t & 127, jb = (t >> 7) * 32;
    const int sw = ((l + 1) & 7) << 3;
    u16* dst = zt + (l + 1) * 64;
    #pragma unroll
    for (int j = 0; j < 32; ++j) {
      int c = (jb + j + l) & 63;
      dst[c ^ sw] = (c < 41) ? zs[c * 128 + l] : (u16)0;
    }
  }
  __syncthreads();

  f32x4 acc[2][4];
  #pragma unroll
  for (int m = 0; m < 2; ++m)
    #pragma unroll
    for (int n = 0; n < 4; ++n) acc[m][n] = (f32x4){0.f, 0.f, 0.f, 0.f};
  const int r = lane & 15, kq = (lane >> 4) * 8;

  #pragma unroll
  for (int tt = 0; tt < 3; ++tt) {
    #pragma unroll
    for (int kk = 0; kk < 2; ++kk) {
      const int kof = kk * 32 + kq;
      bf16x8 av[2], bv[4];
      #pragma unroll
      for (int m = 0; m < 2; ++m) {
        const int zr = wv * 32 + m * 16 + r + tt;
        av[m] = *reinterpret_cast<const bf16x8*>(zt + zr * 64 + (kof ^ ((zr & 7) << 3)));
      }
      #pragma unroll
      for (int n = 0; n < 4; ++n) {
        const int o = n * 16 + r;
        bv[n] = *reinterpret_cast<const bf16x8*>(wl + (tt * 64 + o) * 64 + (kof ^ ((o & 7) << 3)));
      }
      #pragma unroll
      for (int m = 0; m < 2; ++m)
        #pragma unroll
        for (int n = 0; n < 4; ++n)
          acc[m][n] = __builtin_amdgcn_mfma_f32_16x16x32_bf16(av[m], bv[n], acc[m][n], 0, 0, 0);
    }
  }

  const int q = lane >> 4;
  u16* outb = c1T + (size_t)b * 8192;
  #pragma unroll
  for (int n = 0; n < 4; ++n) {
    const int o = n * 16 + r;
    const float bias = cb[o];
    float s1 = 0.f, s2 = 0.f;
    #pragma unroll
    for (int m = 0; m < 2; ++m) {
      #pragma unroll
      for (int rg = 0; rg < 4; ++rg) {
        float v = acc[m][n][rg] + bias;
        s1 += v; s2 += v * v;
        outb[(wv * 32 + m * 16 + q * 4 + rg) * 64 + o] = f2bf(v);
      }
    }
    s1 += __shfl_xor(s1, 16); s1 += __shfl_xor(s1, 32);
    s2 += __shfl_xor(s2, 16); s2 += __shfl_xor(s2, 32);
    if (lane < 16) red[wv][n * 16 + lane] = make_float2(s1, s2);
  }
  __syncthreads();
  if (t < 64) {
    float S = red[0][t].x + red[1][t].x + red[2][t].x + red[3][t].x;
    float Q = red[0][t].y + red[1][t].y + red[2][t].y + red[3][t].y;
    part[(size_t)t * B + b] = make_float2(S, Q);
  }
}

// ---------------- K6: finalize conv1 BN -> scale/shift per channel ----------
__global__ void k_bnfin(const float2* __restrict__ part, const float* __restrict__ g,
                        const float* __restrict__ bb, float* __restrict__ scale,
                        float* __restrict__ shift) {
  int o = blockIdx.x;
  float s = 0.f, q = 0.f;
  for (int i = threadIdx.x; i < B; i += 256) {
    float2 p = part[(size_t)o * B + i];
    s += p.x; q += p.y;
  }
  #pragma unroll
  for (int off = 32; off; off >>= 1) { s += __shfl_down(s, off); q += __shfl_down(q, off); }
  __shared__ float rs[4], rq[4];
  int wv = threadIdx.x >> 6, ln = threadIdx.x & 63;
  if (ln == 0) { rs[wv] = s; rq[wv] = q; }
  __syncthreads();
  if (threadIdx.x == 0) {
    float S = rs[0] + rs[1] + rs[2] + rs[3];
    float Q = rq[0] + rq[1] + rq[2] + rq[3];
    const float n = (float)B * 128.f;
    float mu = S / n, var = Q / n - mu * mu;
    float sc = g[o] * rsqrtf(var + 1e-5f);
    scale[o] = sc; shift[o] = bb[o] - mu * sc;
  }
}

// ---------------- K7: caps conv + squash + routing + pair/max + fc1 ---------
constexpr int NB = 8;
__global__ __launch_bounds__(256) void k_caps(const u16* __restrict__ c1T,
                                              const float* __restrict__ scale,
                                              const float* __restrict__ shift,
                                              const u16* __restrict__ cpk,
                                              const float* __restrict__ cpb,
                                              const u16* __restrict__ rwp,
                                              const float* __restrict__ f1,
                                              float* __restrict__ y1) {
  __shared__ u16 zt[130 * 64];
  __shared__ u16 wl[3 * 64 * 32];
  __shared__ float f1l[128 * 64];
  __shared__ float red[4][64];
  __shared__ float fl[64];
  __shared__ float sc_s[64], sh_s[64];
  __shared__ float red2[4][2];
  __shared__ float yl[2][128];
  __shared__ float pt[128];
  const int b0 = blockIdx.x * NB;
  const int t = threadIdx.x;
  const int lane = t & 63, wv = t >> 6;
  const int r = lane & 15, kq = (lane >> 4) * 8, q = lane >> 4;

  #pragma unroll
  for (int it = 0; it < 3; ++it)
    gload16(cpk + ((size_t)it * 256 + t) * 8, (char*)wl + it * 4096 + wv * 1024);
  #pragma unroll
  for (int it = 0; it < 8; ++it)
    gload16(f1 + ((size_t)it * 256 + t) * 4, (char*)f1l + it * 4096 + wv * 1024);
  if (t < 64) { sc_s[t] = scale[t]; sh_s[t] = shift[t]; }
  if (t < 64) zt[t] = 0;
  else if (t < 128) zt[129 * 64 + t - 64] = 0;

  uint4 raw[4], rawn[4];
  {
    const u16* src = c1T + (size_t)b0 * 8192;
    #pragma unroll
    for (int p = 0; p < 4; ++p)
      raw[p] = *reinterpret_cast<const uint4*>(src + ((size_t)t + p * 256) * 8);
  }

  for (int i = 0; i < NB; ++i) {
    const int b = b0 + i;
    __syncthreads();

    #pragma unroll
    for (int p = 0; p < 4; ++p) {
      int idx = t + p * 256;
      int l = idx >> 3, c0 = (idx & 7) * 8;
      float vv[8];
      vv[0] = __uint_as_float(raw[p].x << 16); vv[1] = __uint_as_float(raw[p].x & 0xffff0000u);
      vv[2] = __uint_as_float(raw[p].y << 16); vv[3] = __uint_as_float(raw[p].y & 0xffff0000u);
      vv[4] = __uint_as_float(raw[p].z << 16); vv[5] = __uint_as_float(raw[p].z & 0xffff0000u);
      vv[6] = __uint_as_float(raw[p].w << 16); vv[7] = __uint_as_float(raw[p].w & 0xffff0000u);
      float a0 = fmaxf(fmaf(vv[0], sc_s[c0 + 0], sh_s[c0 + 0]), 0.f);
      float a1 = fmaxf(fmaf(vv[1], sc_s[c0 + 1], sh_s[c0 + 1]), 0.f);
      float a2 = fmaxf(fmaf(vv[2], sc_s[c0 + 2], sh_s[c0 + 2]), 0.f);
      float a3 = fmaxf(fmaf(vv[3], sc_s[c0 + 3], sh_s[c0 + 3]), 0.f);
      float a4 = fmaxf(fmaf(vv[4], sc_s[c0 + 4], sh_s[c0 + 4]), 0.f);
      float a5 = fmaxf(fmaf(vv[5], sc_s[c0 + 5], sh_s[c0 + 5]), 0.f);
      float a6 = fmaxf(fmaf(vv[6], sc_s[c0 + 6], sh_s[c0 + 6]), 0.f);
      float a7 = fmaxf(fmaf(vv[7], sc_s[c0 + 7], sh_s[c0 + 7]), 0.f);
      uint4 pk;
      pk.x = pack2(a0, a1); pk.y = pack2(a2, a3);
      pk.z = pack2(a4, a5); pk.w = pack2(a6, a7);
      *reinterpret_cast<uint4*>(zt + (l + 1) * 64 + (c0 ^ (((l + 1) & 7) << 3))) = pk;
    }
    if (i + 1 < NB) {
      const u16* srcn = c1T + (size_t)(b + 1) * 8192;
      #pragma unroll
      for (int p = 0; p < 4; ++p)
        rawn[p] = *reinterpret_cast<const uint4*>(srcn + ((size_t)t + p * 256) * 8);
    }
    __syncthreads();

    f32x4 acc[2][4];
    #pragma unroll
    for (int m = 0; m < 2; ++m)
      #pragma unroll
      for (int n = 0; n < 4; ++n) acc[m][n] = (f32x4){0.f, 0.f, 0.f, 0.f};
    #pragma unroll
    for (int tt = 0; tt < 3; ++tt) {
      bf16x8 av[2][2], bv[4];
      #pragma unroll
      for (int m = 0; m < 2; ++m) {
        const int zr = wv * 32 + m * 16 + r + tt;
        const int sw = (zr & 7) << 3;
        av[m][0] = *reinterpret_cast<const bf16x8*>(zt + zr * 64 + (kq ^ sw));
        av[m][1] = *reinterpret_cast<const bf16x8*>(zt + zr * 64 + ((32 + kq) ^ sw));
      }
      #pragma unroll
      for (int n = 0; n < 4; ++n) {
        const int o = n * 16 + r;
        bv[n] = *reinterpret_cast<const bf16x8*>(wl + (tt * 64 + o) * 32 + (kq ^ ((o & 3) << 3)));
      }
      #pragma unroll
      for (int m = 0; m < 2; ++m)
        #pragma unroll
        for (int n = 0; n < 4; ++n)
          acc[m][n] = __builtin_amdgcn_mfma_f32_16x16x32_bf16(av[m][n >> 1], bv[n], acc[m][n], 0, 0, 0);
    }

    #pragma unroll
    for (int n = 0; n < 4; ++n) {
      const int o = n * 16 + r;
      const float bias = cpb[o];
      float s2 = 0.f;
      #pragma unroll
      for (int m = 0; m < 2; ++m) {
        #pragma unroll
        for (int rg = 0; rg < 4; ++rg) {
          float v = acc[m][n][rg] + bias;
          acc[m][n][rg] = v;
          s2 += v * v;
        }
      }
      s2 += __shfl_xor(s2, 16); s2 += __shfl_xor(s2, 32);
      if (lane < 16) red[wv][n * 16 + lane] = s2;
    }
    __syncthreads();
    if (t < 64) {
      float S = red[0][t] + red[1][t] + red[2][t] + red[3][t];
      float nn = sqrtf(S);
      fl[t] = (1.f - 1.f / (expf(nn) + 1e-21f)) / (nn + 1e-21f);
    }
    __syncthreads();

    float s0[2][4], s1[2][4];
    #pragma unroll
    for (int m = 0; m < 2; ++m)
      #pragma unroll
      for (int rg = 0; rg < 4; ++rg) { s0[m][rg] = 0.f; s1[m][rg] = 0.f; }
    #pragma unroll
    for (int n = 0; n < 4; ++n) {
      const int o = n * 16 + r;
      const float fact = fl[o];
      #pragma unroll
      for (int m = 0; m < 2; ++m) {
        const int l0 = wv * 32 + m * 16 + q * 4;
        uint2 rw0 = *reinterpret_cast<const uint2*>(rwp + (size_t)o * 128 + l0);
        uint2 rw1 = *reinterpret_cast<const uint2*>(rwp + (size_t)(64 + o) * 128 + l0);
        #pragma unroll
        for (int rg = 0; rg < 4; ++rg) {
          float v = acc[m][n][rg] * fact;
          u32 w0w = (rg < 2) ? rw0.x : rw0.y;
          u32 w1w = (rg < 2) ? rw1.x : rw1.y;
          float w0 = __uint_as_float((rg & 1) ? (w0w & 0xffff0000u) : (w0w << 16));
          float w1 = __uint_as_float((rg & 1) ? (w1w & 0xffff0000u) : (w1w << 16));
          s0[m][rg] = fmaf(v, w0, s0[m][rg]);
          s1[m][rg] = fmaf(v, w1, s1[m][rg]);
        }
      }
    }
    #pragma unroll
    for (int m = 0; m < 2; ++m)
      #pragma unroll
      for (int rg = 0; rg < 4; ++rg) {
        #pragma unroll
        for (int off = 1; off <= 8; off <<= 1) {
          s0[m][rg] += __shfl_xor(s0[m][rg], off);
          s1[m][rg] += __shfl_xor(s1[m][rg], off);
        }
      }
    float n0 = 0.f, n1 = 0.f;
    #pragma unroll
    for (int m = 0; m < 2; ++m)
      #pragma unroll
      for (int rg = 0; rg < 4; ++rg) {
        n0 = fmaf(s0[m][rg], s0[m][rg], n0);
        n1 = fmaf(s1[m][rg], s1[m][rg], n1);
      }
    n0 += __shfl_xor(n0, 16); n0 += __shfl_xor(n0, 32);
    n1 += __shfl_xor(n1, 16); n1 += __shfl_xor(n1, 32);
    if (lane == 0) { red2[wv][0] = n0; red2[wv][1] = n1; }
    __syncthreads();
    {
      float t0 = red2[0][0] + red2[1][0] + red2[2][0] + red2[3][0];
      float t1 = red2[0][1] + red2[1][1] + red2[2][1] + red2[3][1];
      float nn0 = sqrtf(t0), nn1 = sqrtf(t1);
      float fa0 = (1.f - 1.f / (expf(nn0) + 1e-21f)) / (nn0 + 1e-21f);
      float fa1 = (1.f - 1.f / (expf(nn1) + 1e-21f)) / (nn1 + 1e-21f);
      if (r == 0) {
        #pragma unroll
        for (int m = 0; m < 2; ++m)
          #pragma unroll
          for (int rg = 0; rg < 4; ++rg) {
            float v0 = s0[m][rg] * fa0, v1 = s1[m][rg] * fa1;
            float mx = fmaxf(v0, v1);
            int l = wv * 32 + m * 16 + q * 4 + rg;
            yl[0][l] = v0 + mx;
            yl[1][l] = v1 + mx;
          }
      }
    }
    __syncthreads();

    {
      const int h = t >> 7, idx = t & 127;
      const int jj = idx >> 6, qq = idx & 63;
      float a = 0.f;
      const float* yrow = &yl[jj][h * 64];
      const float* frow = f1l + (h * 64) * 64 + qq;
      #pragma unroll 8
      for (int tt = 0; tt < 64; ++tt)
        a = fmaf(yrow[tt], frow[tt * 64], a);
      if (h == 1) pt[idx] = a;
      __syncthreads();
      if (h == 0)
        y1[((size_t)b * 2 + jj) * 64 + qq] = a + pt[idx];
    }

    #pragma unroll
    for (int p = 0; p < 4; ++p) raw[p] = rawn[p];
  }
}

// ---------------- K9: BN stats stage 1 — partial sums over [B][2][per] ------
__global__ __launch_bounds__(256) void k_bnstat_part(const float* __restrict__ y,
                                                     float2* __restrict__ pp,
                                                     int perShift) {
  const int jj = blockIdx.y;
  const int per = 1 << perShift;
  const int n4 = (B << perShift) >> 2;
  const int p4shift = perShift - 2;
  const int p4mask = (per >> 2) - 1;
  float s = 0.f, q = 0.f;
  for (int i = blockIdx.x * 256 + threadIdx.x; i < n4; i += 64 * 256) {
    int bI = i >> p4shift, c4 = (i & p4mask) * 4;
    float4 v = *reinterpret_cast<const float4*>(
        y + (size_t)bI * (per * 2) + jj * per + c4);
    s += v.x + v.y + v.z + v.w;
    q += v.x * v.x + v.y * v.y + v.z * v.z + v.w * v.w;
  }
  #pragma unroll
  for (int off = 32; off; off >>= 1) { s += __shfl_down(s, off); q += __shfl_down(q, off); }
  __shared__ float rs[4], rq[4];
  int wv = threadIdx.x >> 6, ln = threadIdx.x & 63;
  if (ln == 0) { rs[wv] = s; rq[wv] = q; }
  __syncthreads();
  if (threadIdx.x == 0)
    pp[jj * 64 + blockIdx.x] =
        make_float2(rs[0] + rs[1] + rs[2] + rs[3], rq[0] + rq[1] + rq[2] + rq[3]);
}

// ---------------- K9b: BN stats stage 2 — 64 partials -> scale/shift --------
__global__ void k_bnstat_fin(const float2* __restrict__ pp, const float* __restrict__ g,
                             const float* __restrict__ bb, float* __restrict__ scale,
                             float* __restrict__ shift, int perShift) {
  const int jj = blockIdx.x;
  float2 p = pp[jj * 64 + threadIdx.x];
  float s = p.x, q = p.y;
  #pragma unroll
  for (int off = 32; off; off >>= 1) { s += __shfl_down(s, off); q += __shfl_down(q, off); }
  if (threadIdx.x == 0) {
    float fn = (float)(B << perShift);
    float mu = s / fn, var = q / fn - mu * mu;
    float sc = g[jj] * rsqrtf(var + 1e-5f);
    scale[jj] = sc; shift[jj] = bb[jj] - mu * sc;
  }
}

// ---------------- K10: bn1+relu+fc2 -----------------------------------------
__global__ void k_fc2(const float* __restrict__ y1, const float* __restrict__ sc1,
                      const float* __restrict__ sh1, const float* __restrict__ f2,
                      float* __restrict__ y2) {
  int t = threadIdx.x;
  int b = blockIdx.x * 4 + (t >> 6);
  int jj = (t >> 5) & 1, r = t & 31;
  float sc = sc1[jj], sh = sh1[jj];
  const float* yb = y1 + (size_t)b * 128 + jj * 64;
  float acc = 0.f;
  for (int q = 0; q < 64; ++q) {
    float v = fmaxf(fmaf(yb[q], sc, sh), 0.f);
    acc = fmaf(v, f2[q * 32 + r], acc);
  }
  y2[(size_t)b * 64 + jj * 32 + r] = acc;
}

// ---------------- K12: bn2+relu+fc3+sigmoid+max -----------------------------
__global__ void k_head(const float* __restrict__ y2, const float* __restrict__ sc2,
                       const float* __restrict__ sh2, const float* __restrict__ f3,
                       float* __restrict__ out) {
  int b = blockIdx.x * 256 + threadIdx.x;
  if (b >= B) return;
  const float* yb = y2 + (size_t)b * 64;
  float c0 = sc2[0], d0 = sh2[0], c1v = sc2[1], d1 = sh2[1];
  float a0 = 0.f, a1 = 0.f;
  for (int r = 0; r < 32; ++r) {
    float w = f3[r];
    a0 = fmaf(fmaxf(fmaf(yb[r], c0, d0), 0.f), w, a0);
    a1 = fmaf(fmaxf(fmaf(yb[32 + r], c1v, d1), 0.f), w, a1);
  }
  float s0 = 1.f / (1.f + expf(-a0));
  float s1 = 1.f / (1.f + expf(-a1));
  out[b] = fmaxf(s0, s1);
}

// ---------------- workspace layout ------------------------------------------
constexpr size_t SZ_H2    = (size_t)B * SQ * 128 * 2;   // 42,991,616 (bf16)
constexpr size_t SZ_C1    = (size_t)B * 64 * 128 * 2;   // 67,108,864 (bf16)
constexpr size_t OFF_H2   = 0;
constexpr size_t OFF_H3   = SZ_H2;
constexpr size_t R1       = 2 * SZ_H2;         // 85,983,232
constexpr size_t OFF_G    = R1;                                 // 314,880
constexpr size_t OFF_T1   = OFF_G + 314880;                     // 2,624,000
constexpr size_t OFF_T2   = OFF_T1 + 2624000;                   // 6,560,000 (bf16)
constexpr size_t OFF_CMB  = OFF_T2 + 6560000;                   //   671,744
constexpr size_t OFF_W7T  = OFF_CMB + 671744;  // 9,404,416 bf16; dead by K5
constexpr size_t OFF_C1   = R1;                // overlaps tables+w7t (dead by K5)
constexpr size_t R2       = R1 + SZ_C1;        // 153,092,096
constexpr size_t OFF_PART = R2;                                 // 2,097,152
constexpr size_t OFF_Y1   = OFF_PART + 2097152;                 // 2,097,152
constexpr size_t OFF_Y2   = OFF_Y1 + 2097152;                   // 1,048,576
constexpr size_t OFF_SM   = OFF_Y2 + 1048576;                   //     1,024
constexpr size_t OFF_BNP  = OFF_SM + 1024;                      //     1,024
constexpr size_t OFF_WPK  = OFF_BNP + 1024;                     //    24,576
constexpr size_t OFF_CPK  = OFF_WPK + 24576;                    //    12,288
constexpr size_t OFF_RWP  = OFF_CPK + 12288;                    //    32,768

extern "C" void kernel_launch(void* const* d_in, const int* in_sizes, int n_in,
                              void* d_out, int out_size, void* d_ws, size_t ws_size,
                              hipStream_t stream) {
  const int*   x   = (const int*)d_in[0];
  const float* emb = (const float*)d_in[1];
  const float* W3  = (const float*)d_in[2];
  const float* b3  = (const float*)d_in[3];
  const float* W5  = (const float*)d_in[4];
  const float* b5  = (const float*)d_in[5];
  const float* W7  = (const float*)d_in[6];
  const float* b7  = (const float*)d_in[7];
  const float* c1w = (const float*)d_in[8];
  const float* c1b = (const float*)d_in[9];
  const float* bng = (const float*)d_in[10];
  const float* bnb = (const float*)d_in[11];
  const float* cpw = (const float*)d_in[12];
  const float* cpb = (const float*)d_in[13];
  const float* rW  = (const float*)d_in[14];
  const float* rb  = (const float*)d_in[15];
  const float* f1  = (const float*)d_in[16];
  const float* g1  = (const float*)d_in[17];
  const float* bb1 = (const float*)d_in[18];
  const float* f2  = (const float*)d_in[19];
  const float* g2  = (const float*)d_in[20];
  const float* bb2 = (const float*)d_in[21];
  const float* f3  = (const float*)d_in[22];

  char* wsb = (char*)d_ws;
  u16*    h2p   = (u16*)(wsb + OFF_H2);
  u16*    h3p   = (u16*)(wsb + OFF_H3);
  float*  Gp    = (float*)(wsb + OFF_G);
  float*  t1p   = (float*)(wsb + OFF_T1);
  u16*    t2p   = (u16*)(wsb + OFF_T2);
  int*    cmbp  = (int*)(wsb + OFF_CMB);
  u16*    w7tp  = (u16*)(wsb + OFF_W7T);
  u16*    c1p   = (u16*)(wsb + OFF_C1);
  float2* partp = (float2*)(wsb + OFF_PART);
  float*  y1p   = (float*)(wsb + OFF_Y1);
  float*  y2p   = (float*)(wsb + OFF_Y2);
  float*  scp   = (float*)(wsb + OFF_SM);
  float*  shp   = scp + 64;
  float*  sc1p  = shp + 64;
  float*  sh1p  = sc1p + 2;
  float*  sc2p  = sh1p + 2;
  float*  sh2p  = sc2p + 2;
  float2* bnpp  = (float2*)(wsb + OFF_BNP);
  u16*    wpkp  = (u16*)(wsb + OFF_WPK);
  u16*    cpkp  = (u16*)(wsb + OFF_CPK);
  u16*    rwpp  = (u16*)(wsb + OFF_RWP);

  k_pack<<<136, 256, 0, stream>>>(c1w, cpw, rW, rb, wpkp, cpkp, rwpp);
  k_combo<<<(B * SQ + 255) / 256, 256, 0, stream>>>(x, cmbp);
  k_w7t<<<dim3(14, 2, SQ), 256, 0, stream>>>(W7, w7tp);
  k_gmat<<<SQ * 3, 128, 0, stream>>>(emb, W3, Gp);
  k_t1<<<(SQ * 128 * 125 + 255) / 256, 256, 0, stream>>>(Gp, b3, t1p);
  k_t2<<<SQ * 25, 128, 0, stream>>>(t1p, W5, t2p);
  k_h2<<<(B * SQ * 16) / 256, 256, 0, stream>>>(t2p, cmbp, b5, h2p);
  k_gemm7_mfma<<<dim3(32, SQ), 256, 0, stream>>>(h2p, w7tp, b7, h3p);
  k_conv1<<<B, 256, 0, stream>>>(h3p, wpkp, c1b, c1p, partp);
  k_bnfin<<<64, 256, 0, stream>>>(partp, bng, bnb, scp, shp);
  k_caps<<<B / NB, 256, 0, stream>>>(c1p, scp, shp, cpkp, cpb, rwpp, f1, y1p);
  k_bnstat_part<<<dim3(64, 2), 256, 0, stream>>>(y1p, bnpp, 6);
  k_bnstat_fin<<<2, 64, 0, stream>>>(bnpp, g1, bb1, sc1p, sh1p, 6);
  k_fc2<<<B / 4, 256, 0, stream>>>(y1p, sc1p, sh1p, f2, y2p);
  k_bnstat_part<<<dim3(64, 2), 256, 0, stream>>>(y2p, bnpp, 5);
  k_bnstat_fin<<<2, 64, 0, stream>>>(bnpp, g2, bb2, sc2p, sh2p, 5);
  k_head<<<B / 256, 256, 0, stream>>>(y2p, sc2p, sh2p, f3, (float*)d_out);
}

// Round 12
// 235.995 us; speedup vs baseline: 1.1018x; 1.0347x over previous
//
#include <hip/hip_runtime.h>
#include <cstdint>

typedef unsigned short u16;
typedef unsigned int   u32;
typedef __attribute__((ext_vector_type(8))) short bf16x8;
typedef __attribute__((ext_vector_type(4))) float f32x4;

#define DEVFN static __device__ __forceinline__

constexpr int B  = 4096;
constexpr int SQ = 41;

DEVFN float bf2f(u16 v) { return __uint_as_float(((u32)v) << 16); }
DEVFN u16 f2bf(float f) {
  u32 u = __float_as_uint(f);
  u += 0x7fffu + ((u >> 16) & 1u);
  return (u16)(u >> 16);
}
DEVFN u32 pack2(float a, float b) { return (u32)f2bf(a) | ((u32)f2bf(b) << 16); }

DEVFN void gload16(const void* g, void* l) {
  __builtin_amdgcn_global_load_lds(
      (const __attribute__((address_space(1))) unsigned int*)g,
      (__attribute__((address_space(3))) unsigned int*)l, 16, 0, 0);
}

// ---------------- K-1: pack weights into swizzled bf16 global images --------
__global__ void k_pack(const float* __restrict__ cw, const float* __restrict__ cpw,
                       const float* __restrict__ rW, const float* __restrict__ rb,
                       u16* __restrict__ wpk, u16* __restrict__ cpk,
                       u16* __restrict__ rwp) {
  int i = blockIdx.x * 256 + threadIdx.x;
  if (i < 12288) {                    // conv1 weights [t][o][c^swz], c padded 64
    int tt = i >> 12, rem = i & 4095, o = rem >> 6, c = rem & 63;
    float v = (c < 41) ? cw[(o * 41 + c) * 3 + tt] : 0.f;
    wpk[(tt * 64 + o) * 64 + (c ^ ((o & 7) << 3))] = f2bf(v);
  } else if (i < 18432) {             // caps weights [t][o][cg^swz]
    int k = i - 12288;
    int tt = k >> 11, rem = k & 2047, o = rem >> 5, c = rem & 31;
    cpk[(tt * 64 + o) * 32 + (c ^ ((o & 3) << 3))] = f2bf(cpw[(o * 32 + c) * 3 + tt]);
  } else if (i < 34816) {             // routing weights [j*64+o][l] * (1+rb)
    int k = i - 18432;
    rwp[k] = f2bf(rW[k] * (1.f + rb[k >> 7]));
  }
}

// ---------------- K0: combo indices [B][41], symbols 0..3, pad=4 -------------
__global__ void k_combo(const int* __restrict__ x, int* __restrict__ combo) {
  int i = blockIdx.x * 256 + threadIdx.x;
  if (i >= B * SQ) return;
  int b = i / SQ, s = i - b * SQ;
  const int* xb = x + b * SQ;
  int d0 = (s > 0) ? xb[s - 1] : 4;
  int d1 = xb[s];
  int d2 = (s < SQ - 1) ? xb[s + 1] : 4;
  combo[i] = d0 * 25 + d1 * 5 + d2;
}

// ---------------- K1a: G[s][w][sym][o] = sum_f emb[sym][f]*W3[s][w*128+f][o] -
__global__ void k_gmat(const float* __restrict__ emb, const float* __restrict__ W3,
                       float* __restrict__ G) {
  int s = blockIdx.x / 3, ww = blockIdx.x % 3;
  int o = threadIdx.x;
  const float* Ws = W3 + ((size_t)s * 384 + ww * 128) * 128;
  float a0 = 0.f, a1 = 0.f, a2 = 0.f, a3 = 0.f;
  for (int f = 0; f < 128; ++f) {
    float wg = Ws[(size_t)f * 128 + o];
    a0 = fmaf(emb[f], wg, a0);
    a1 = fmaf(emb[128 + f], wg, a1);
    a2 = fmaf(emb[256 + f], wg, a2);
    a3 = fmaf(emb[384 + f], wg, a3);
  }
  float* Gp = G + ((size_t)(s * 3 + ww) * 5) * 128 + o;
  Gp[0] = a0; Gp[128] = a1; Gp[256] = a2; Gp[384] = a3; Gp[512] = 0.f;
}

// ---------------- K1b: t1T[s][o][v] = relu(b3 + G0+G1+G2)  (transposed) -----
__global__ void k_t1(const float* __restrict__ G, const float* __restrict__ b3,
                     float* __restrict__ t1T) {
  int i = blockIdx.x * 256 + threadIdx.x;
  if (i >= SQ * 128 * 125) return;
  int v = i % 125, so = i / 125;
  int s = so >> 7, o = so & 127;
  int d0 = v / 25, r = v % 25;
  int d1 = r / 5, d2 = r % 5;
  float acc = b3[so]
      + G[((size_t)(s * 3 + 0) * 5 + d0) * 128 + o]
      + G[((size_t)(s * 3 + 1) * 5 + d1) * 128 + o]
      + G[((size_t)(s * 3 + 2) * 5 + d2) * 128 + o];
  t1T[i] = fmaxf(acc, 0.f);
}

// ---------------- K2: t2[s][w][v][o] (bf16) = sum_f t1[s+w-2][v][f]*W5[..] --
__global__ __launch_bounds__(128) void k_t2(const float* __restrict__ t1T,
                                            const float* __restrict__ W5,
                                            u16* __restrict__ t2) {
  int bx = blockIdx.x;
  int s = bx / 25; int r = bx % 25;
  int ww = r / 5;  int vt = (r % 5) * 25;
  int o = threadIdx.x;
  int t = s + ww - 2;
  u16* dst = t2 + ((size_t)(s * 5 + ww) * 125 + vt) * 128 + o;
  if (t < 0 || t >= SQ) {
    #pragma unroll
    for (int v = 0; v < 25; ++v) dst[(size_t)v * 128] = 0;
    return;
  }
  float acc[25];
  #pragma unroll
  for (int v = 0; v < 25; ++v) acc[v] = 0.f;
  const float* Ws = W5 + ((size_t)s * 640 + ww * 128) * 128;
  const float* tp = t1T + (size_t)t * 128 * 125 + vt;
  for (int f = 0; f < 128; ++f) {
    float wg = Ws[(size_t)f * 128 + o];
    #pragma unroll
    for (int v = 0; v < 25; ++v) acc[v] = fmaf(tp[f * 125 + v], wg, acc[v]);
  }
  #pragma unroll
  for (int v = 0; v < 25; ++v) dst[(size_t)v * 128] = f2bf(acc[v]);
}

// ---------------- K3: h2[b][s][o] = relu(b5 + sum_w t2[s][w][combo]) --------
__global__ __launch_bounds__(256) void k_h2(const u16* __restrict__ t2,
                                            const int* __restrict__ combo,
                                            const float* __restrict__ b5,
                                            u16* __restrict__ h2) {
  const int i = blockIdx.x * 256 + threadIdx.x;   // B*41*16 total
  const int o8 = (i & 15) * 8;
  const int rid = i >> 4;                          // s-major: s = rid>>12
  const int s = rid >> 12, b = rid & 4095;
  float acc[8];
  {
    float4 b0 = *reinterpret_cast<const float4*>(b5 + s * 128 + o8);
    float4 b1 = *reinterpret_cast<const float4*>(b5 + s * 128 + o8 + 4);
    acc[0] = b0.x; acc[1] = b0.y; acc[2] = b0.z; acc[3] = b0.w;
    acc[4] = b1.x; acc[5] = b1.y; acc[6] = b1.z; acc[7] = b1.w;
  }
  const int* cb = combo + b * SQ;
  #pragma unroll
  for (int ww = 0; ww < 5; ++ww) {
    const int t = s + ww - 2;
    if (0 <= t && t < SQ) {
      const int c = cb[t];
      uint4 raw = *reinterpret_cast<const uint4*>(
          t2 + ((size_t)(s * 5 + ww) * 125 + c) * 128 + o8);
      acc[0] += __uint_as_float(raw.x << 16);
      acc[1] += __uint_as_float(raw.x & 0xffff0000u);
      acc[2] += __uint_as_float(raw.y << 16);
      acc[3] += __uint_as_float(raw.y & 0xffff0000u);
      acc[4] += __uint_as_float(raw.z << 16);
      acc[5] += __uint_as_float(raw.z & 0xffff0000u);
      acc[6] += __uint_as_float(raw.w << 16);
      acc[7] += __uint_as_float(raw.w & 0xffff0000u);
    }
  }
  uint4 pk;
  pk.x = pack2(fmaxf(acc[0], 0.f), fmaxf(acc[1], 0.f));
  pk.y = pack2(fmaxf(acc[2], 0.f), fmaxf(acc[3], 0.f));
  pk.z = pack2(fmaxf(acc[4], 0.f), fmaxf(acc[5], 0.f));
  pk.w = pack2(fmaxf(acc[6], 0.f), fmaxf(acc[7], 0.f));
  *reinterpret_cast<uint4*>(h2 + ((size_t)b * SQ + s) * 128 + o8) = pk;
}

// ---------------- K4a: W7 [41][896][128] f32 -> w7t [41][128][896] bf16 -----
__global__ __launch_bounds__(256) void k_w7t(const float* __restrict__ W7,
                                             u16* __restrict__ w7t) {
  __shared__ float tile[64][65];
  const int s = blockIdx.z;
  const int k0 = blockIdx.x * 64;   // 896/64 = 14
  const int o0 = blockIdx.y * 64;   // 128/64 = 2
  const int t = threadIdx.x;
  #pragma unroll
  for (int i = 0; i < 16; ++i) {
    int idx = t + i * 256;
    int kl = idx >> 6, ol = idx & 63;
    tile[kl][ol] = W7[((size_t)s * 896 + k0 + kl) * 128 + o0 + ol];
  }
  __syncthreads();
  #pragma unroll
  for (int i = 0; i < 16; ++i) {
    int idx = t + i * 256;
    int ol = idx >> 6, kl = idx & 63;
    w7t[((size_t)s * 128 + o0 + ol) * 896 + k0 + kl] = f2bf(tile[kl][ol]);
  }
}

// ---------------- K4b: layer-3 GEMM, BK=64 dbuf + counted vmcnt pipeline ----
__global__ __launch_bounds__(256) void k_gemm7_mfma(const u16* __restrict__ h2,
                                                    const u16* __restrict__ w7t,
                                                    const float* __restrict__ b7,
                                                    u16* __restrict__ h3) {
  __shared__ u16 As[2][8192];   // [buf][row][k-granule^swz] 2x16 KB
  __shared__ u16 Bs[2][8192];   // [buf][o][k-granule^swz]   2x16 KB
  const int s  = blockIdx.y;
  const int b0 = blockIdx.x * 128;
  const int t  = threadIdx.x;
  const int lane = t & 63, w = t >> 6;
  const int wr = w >> 1, wc = w & 1;            // wave -> 64x64 quadrant
  const int lcol = lane & 15, qk = lane >> 4;   // qk: k-granule quarter 0..3

  f32x4 acc[4][4];
  #pragma unroll
  for (int i = 0; i < 4; ++i)
    #pragma unroll
    for (int j = 0; j < 4; ++j) acc[i][j] = (f32x4){0.f, 0.f, 0.f, 0.f};

  const u16* wbase = w7t + (size_t)s * 128 * 896;

  auto stage = [&](int kt, int bi) -> int {
    const int k0 = kt * 64;
    const int ww = k0 >> 7, tr = s + ww - 3, kf0 = k0 & 127;
    int issued = 0;
    if (0 <= tr && tr < SQ) {
      #pragma unroll
      for (int it = 0; it < 4; ++it) {
        const int L = it * 4096 + t * 16;       // dest byte offset
        const int r = L >> 7;                   // tile row 0..127
        const int g = (L >> 4) & 7;             // dest 16B granule in row
        const int gs = g ^ (r & 7);             // pre-swizzled source granule
        gload16(h2 + ((size_t)(b0 + r) * SQ + tr) * 128 + kf0 + gs * 8,
                (char*)As[bi] + it * 4096 + w * 1024);
      }
      issued += 4;
    } else {
      #pragma unroll
      for (int it = 0; it < 4; ++it)
        *reinterpret_cast<uint4*>((char*)As[bi] + it * 4096 + t * 16) =
            make_uint4(0u, 0u, 0u, 0u);
    }
    #pragma unroll
    for (int it = 0; it < 4; ++it) {
      const int L = it * 4096 + t * 16;
      const int o = L >> 7;
      const int g = (L >> 4) & 7;
      const int gs = g ^ (o & 7);
      gload16(wbase + (size_t)o * 896 + k0 + gs * 8,
              (char*)Bs[bi] + it * 4096 + w * 1024);
    }
    return issued + 4;
  };

  stage(0, 0);   // prologue

  for (int kt = 0; kt < 14; ++kt) {
    const int cur = kt & 1;
    int ni = 0;
    if (kt < 13) ni = stage(kt + 1, cur ^ 1);
    if (ni == 8)      asm volatile("s_waitcnt vmcnt(8) lgkmcnt(0)" ::: "memory");
    else if (ni == 4) asm volatile("s_waitcnt vmcnt(4) lgkmcnt(0)" ::: "memory");
    else              asm volatile("s_waitcnt vmcnt(0) lgkmcnt(0)" ::: "memory");
    __builtin_amdgcn_sched_barrier(0);
    __builtin_amdgcn_s_barrier();          // buf[cur] ready for all waves
    __builtin_amdgcn_sched_barrier(0);

    const u16* Ac = As[cur];
    const u16* Bc = Bs[cur];
    #pragma unroll
    for (int kk = 0; kk < 2; ++kk) {
      const int gk = kk * 4 + qk;          // logical k-granule 0..7
      bf16x8 av[4], bv[4];
      #pragma unroll
      for (int m = 0; m < 4; ++m) {
        const int zr = wr * 64 + m * 16 + lcol;
        av[m] = *reinterpret_cast<const bf16x8*>(Ac + zr * 64 + ((gk ^ (zr & 7)) << 3));
      }
      #pragma unroll
      for (int n = 0; n < 4; ++n) {
        const int br = wc * 64 + n * 16 + lcol;
        bv[n] = *reinterpret_cast<const bf16x8*>(Bc + br * 64 + ((gk ^ (br & 7)) << 3));
      }
      #pragma unroll
      for (int m = 0; m < 4; ++m)
        #pragma unroll
        for (int n = 0; n < 4; ++n)
          acc[m][n] = __builtin_amdgcn_mfma_f32_16x16x32_bf16(av[m], bv[n], acc[m][n], 0, 0, 0);
    }
    __builtin_amdgcn_sched_barrier(0);
    __builtin_amdgcn_s_barrier();          // all reads of buf[cur] done
  }

  const int rq = (lane >> 4) * 4;
  #pragma unroll
  for (int n = 0; n < 4; ++n) {
    const int o = wc * 64 + n * 16 + lcol;
    const float bias = b7[s * 128 + o];
    #pragma unroll
    for (int m = 0; m < 4; ++m) {
      #pragma unroll
      for (int rg = 0; rg < 4; ++rg) {
        const int row = b0 + wr * 64 + m * 16 + rq + rg;
        h3[((size_t)row * SQ + s) * 128 + o] = f2bf(fmaxf(acc[m][n][rg] + bias, 0.f));
      }
    }
  }
}

// ---------------- K5: conv1 via MFMA, NB=8 batched + zs double buffer -------
// Weights staged ONCE per block (stream 98 -> 12 MB); next b's h3 staged via
// global_load_lds into zs[nxt] during current MFMA/epilogue (epilogue's
// __syncthreads drains vmcnt before the next transpose reads it).
constexpr int NBC = 8;
__global__ __launch_bounds__(256) void k_conv1(const u16* __restrict__ h3,
                                               const u16* __restrict__ wpk,
                                               const float* __restrict__ cb,
                                               u16* __restrict__ c1T,
                                               float2* __restrict__ part) {
  __shared__ u16 zs[2][6144];        // h3[b] staging dbuf (2x12 KB)
  __shared__ u16 zt[130 * 64];       // transposed [l+1][c^swz]
  __shared__ u16 wl[3 * 64 * 64];    // weights [t][o][c^swz]
  __shared__ float2 red[4][64];
  const int b0 = blockIdx.x * NBC;
  const int t = threadIdx.x;
  const int lane = t & 63, wv = t >> 6;
  const int r = lane & 15, kq = (lane >> 4) * 8, q = lane >> 4;

  // ---- prologue (once per block) ----
  #pragma unroll
  for (int it = 0; it < 6; ++it)
    gload16(wpk + ((size_t)it * 256 + t) * 8, (char*)wl + it * 4096 + wv * 1024);
  #pragma unroll
  for (int it = 0; it < 3; ++it)
    gload16(h3 + (size_t)b0 * (SQ * 128) + ((size_t)it * 256 + t) * 8,
            (char*)zs[0] + it * 4096 + wv * 1024);
  if (t < 64) zt[t] = 0;
  else if (t < 128) zt[129 * 64 + t - 64] = 0;
  __syncthreads();   // wl + zs[0] ready (drains vmcnt)

  for (int i = 0; i < NBC; ++i) {
    const int b = b0 + i;
    const int cur = i & 1;

    // ---- transpose zs[cur] -> zt (rotation spreads banks) ----
    {
      const int l = t & 127, jb = (t >> 7) * 32;
      const int sw = ((l + 1) & 7) << 3;
      u16* dst = zt + (l + 1) * 64;
      const u16* srcz = zs[cur];
      #pragma unroll
      for (int j = 0; j < 32; ++j) {
        int c = (jb + j + l) & 63;
        dst[c ^ sw] = (c < 41) ? srcz[c * 128 + l] : (u16)0;
      }
    }
    // ---- prefetch next b's h3 into zs[cur^1] (overlaps MFMA/epilogue) ----
    if (i + 1 < NBC) {
      #pragma unroll
      for (int it = 0; it < 3; ++it)
        gload16(h3 + (size_t)(b + 1) * (SQ * 128) + ((size_t)it * 256 + t) * 8,
                (char*)zs[cur ^ 1] + it * 4096 + wv * 1024);
    }
    // zt ready for all waves; do NOT drain vmcnt (prefetch stays in flight)
    asm volatile("s_waitcnt lgkmcnt(0)" ::: "memory");
    __builtin_amdgcn_sched_barrier(0);
    __builtin_amdgcn_s_barrier();
    __builtin_amdgcn_sched_barrier(0);

    // ---- MFMA ----
    f32x4 acc[2][4];
    #pragma unroll
    for (int m = 0; m < 2; ++m)
      #pragma unroll
      for (int n = 0; n < 4; ++n) acc[m][n] = (f32x4){0.f, 0.f, 0.f, 0.f};
    #pragma unroll
    for (int tt = 0; tt < 3; ++tt) {
      #pragma unroll
      for (int kk = 0; kk < 2; ++kk) {
        const int kof = kk * 32 + kq;
        bf16x8 av[2], bv[4];
        #pragma unroll
        for (int m = 0; m < 2; ++m) {
          const int zr = wv * 32 + m * 16 + r + tt;
          av[m] = *reinterpret_cast<const bf16x8*>(zt + zr * 64 + (kof ^ ((zr & 7) << 3)));
        }
        #pragma unroll
        for (int n = 0; n < 4; ++n) {
          const int o = n * 16 + r;
          bv[n] = *reinterpret_cast<const bf16x8*>(wl + (tt * 64 + o) * 64 + (kof ^ ((o & 7) << 3)));
        }
        #pragma unroll
        for (int m = 0; m < 2; ++m)
          #pragma unroll
          for (int n = 0; n < 4; ++n)
            acc[m][n] = __builtin_amdgcn_mfma_f32_16x16x32_bf16(av[m], bv[n], acc[m][n], 0, 0, 0);
      }
    }

    // ---- epilogue: bias, store c1T[b], per-o BN partials ----
    u16* outb = c1T + (size_t)b * 8192;
    #pragma unroll
    for (int n = 0; n < 4; ++n) {
      const int o = n * 16 + r;
      const float bias = cb[o];
      float s1 = 0.f, s2 = 0.f;
      #pragma unroll
      for (int m = 0; m < 2; ++m) {
        #pragma unroll
        for (int rg = 0; rg < 4; ++rg) {
          float v = acc[m][n][rg] + bias;
          s1 += v; s2 += v * v;
          outb[(wv * 32 + m * 16 + q * 4 + rg) * 64 + o] = f2bf(v);
        }
      }
      s1 += __shfl_xor(s1, 16); s1 += __shfl_xor(s1, 32);
      s2 += __shfl_xor(s2, 16); s2 += __shfl_xor(s2, 32);
      if (lane < 16) red[wv][n * 16 + lane] = make_float2(s1, s2);
    }
    __syncthreads();   // red ready; also drains prefetch vmcnt for next iter
    if (t < 64) {
      float S = red[0][t].x + red[1][t].x + red[2][t].x + red[3][t].x;
      float Q = red[0][t].y + red[1][t].y + red[2][t].y + red[3][t].y;
      part[(size_t)t * B + b] = make_float2(S, Q);
    }
    __syncthreads();   // red/zt reusable next iteration
  }
}

// ---------------- K6: finalize conv1 BN -> scale/shift per channel ----------
__global__ void k_bnfin(const float2* __restrict__ part, const float* __restrict__ g,
                        const float* __restrict__ bb, float* __restrict__ scale,
                        float* __restrict__ shift) {
  int o = blockIdx.x;
  float s = 0.f, q = 0.f;
  for (int i = threadIdx.x; i < B; i += 256) {
    float2 p = part[(size_t)o * B + i];
    s += p.x; q += p.y;
  }
  #pragma unroll
  for (int off = 32; off; off >>= 1) { s += __shfl_down(s, off); q += __shfl_down(q, off); }
  __shared__ float rs[4], rq[4];
  int wv = threadIdx.x >> 6, ln = threadIdx.x & 63;
  if (ln == 0) { rs[wv] = s; rq[wv] = q; }
  __syncthreads();
  if (threadIdx.x == 0) {
    float S = rs[0] + rs[1] + rs[2] + rs[3];
    float Q = rq[0] + rq[1] + rq[2] + rq[3];
    const float n = (float)B * 128.f;
    float mu = S / n, var = Q / n - mu * mu;
    float sc = g[o] * rsqrtf(var + 1e-5f);
    scale[o] = sc; shift[o] = bb[o] - mu * sc;
  }
}

// ---------------- K7: caps conv + squash + routing + pair/max + fc1 ---------
constexpr int NB = 8;
__global__ __launch_bounds__(256) void k_caps(const u16* __restrict__ c1T,
                                              const float* __restrict__ scale,
                                              const float* __restrict__ shift,
                                              const u16* __restrict__ cpk,
                                              const float* __restrict__ cpb,
                                              const u16* __restrict__ rwp,
                                              const float* __restrict__ f1,
                                              float* __restrict__ y1) {
  __shared__ u16 zt[130 * 64];
  __shared__ u16 wl[3 * 64 * 32];
  __shared__ float f1l[128 * 64];
  __shared__ float red[4][64];
  __shared__ float fl[64];
  __shared__ float sc_s[64], sh_s[64];
  __shared__ float red2[4][2];
  __shared__ float yl[2][128];
  __shared__ float pt[128];
  const int b0 = blockIdx.x * NB;
  const int t = threadIdx.x;
  const int lane = t & 63, wv = t >> 6;
  const int r = lane & 15, kq = (lane >> 4) * 8, q = lane >> 4;

  #pragma unroll
  for (int it = 0; it < 3; ++it)
    gload16(cpk + ((size_t)it * 256 + t) * 8, (char*)wl + it * 4096 + wv * 1024);
  #pragma unroll
  for (int it = 0; it < 8; ++it)
    gload16(f1 + ((size_t)it * 256 + t) * 4, (char*)f1l + it * 4096 + wv * 1024);
  if (t < 64) { sc_s[t] = scale[t]; sh_s[t] = shift[t]; }
  if (t < 64) zt[t] = 0;
  else if (t < 128) zt[129 * 64 + t - 64] = 0;

  uint4 raw[4], rawn[4];
  {
    const u16* src = c1T + (size_t)b0 * 8192;
    #pragma unroll
    for (int p = 0; p < 4; ++p)
      raw[p] = *reinterpret_cast<const uint4*>(src + ((size_t)t + p * 256) * 8);
  }

  for (int i = 0; i < NB; ++i) {
    const int b = b0 + i;
    __syncthreads();

    #pragma unroll
    for (int p = 0; p < 4; ++p) {
      int idx = t + p * 256;
      int l = idx >> 3, c0 = (idx & 7) * 8;
      float vv[8];
      vv[0] = __uint_as_float(raw[p].x << 16); vv[1] = __uint_as_float(raw[p].x & 0xffff0000u);
      vv[2] = __uint_as_float(raw[p].y << 16); vv[3] = __uint_as_float(raw[p].y & 0xffff0000u);
      vv[4] = __uint_as_float(raw[p].z << 16); vv[5] = __uint_as_float(raw[p].z & 0xffff0000u);
      vv[6] = __uint_as_float(raw[p].w << 16); vv[7] = __uint_as_float(raw[p].w & 0xffff0000u);
      float a0 = fmaxf(fmaf(vv[0], sc_s[c0 + 0], sh_s[c0 + 0]), 0.f);
      float a1 = fmaxf(fmaf(vv[1], sc_s[c0 + 1], sh_s[c0 + 1]), 0.f);
      float a2 = fmaxf(fmaf(vv[2], sc_s[c0 + 2], sh_s[c0 + 2]), 0.f);
      float a3 = fmaxf(fmaf(vv[3], sc_s[c0 + 3], sh_s[c0 + 3]), 0.f);
      float a4 = fmaxf(fmaf(vv[4], sc_s[c0 + 4], sh_s[c0 + 4]), 0.f);
      float a5 = fmaxf(fmaf(vv[5], sc_s[c0 + 5], sh_s[c0 + 5]), 0.f);
      float a6 = fmaxf(fmaf(vv[6], sc_s[c0 + 6], sh_s[c0 + 6]), 0.f);
      float a7 = fmaxf(fmaf(vv[7], sc_s[c0 + 7], sh_s[c0 + 7]), 0.f);
      uint4 pk;
      pk.x = pack2(a0, a1); pk.y = pack2(a2, a3);
      pk.z = pack2(a4, a5); pk.w = pack2(a6, a7);
      *reinterpret_cast<uint4*>(zt + (l + 1) * 64 + (c0 ^ (((l + 1) & 7) << 3))) = pk;
    }
    if (i + 1 < NB) {
      const u16* srcn = c1T + (size_t)(b + 1) * 8192;
      #pragma unroll
      for (int p = 0; p < 4; ++p)
        rawn[p] = *reinterpret_cast<const uint4*>(srcn + ((size_t)t + p * 256) * 8);
    }
    __syncthreads();

    f32x4 acc[2][4];
    #pragma unroll
    for (int m = 0; m < 2; ++m)
      #pragma unroll
      for (int n = 0; n < 4; ++n) acc[m][n] = (f32x4){0.f, 0.f, 0.f, 0.f};
    #pragma unroll
    for (int tt = 0; tt < 3; ++tt) {
      bf16x8 av[2][2], bv[4];
      #pragma unroll
      for (int m = 0; m < 2; ++m) {
        const int zr = wv * 32 + m * 16 + r + tt;
        const int sw = (zr & 7) << 3;
        av[m][0] = *reinterpret_cast<const bf16x8*>(zt + zr * 64 + (kq ^ sw));
        av[m][1] = *reinterpret_cast<const bf16x8*>(zt + zr * 64 + ((32 + kq) ^ sw));
      }
      #pragma unroll
      for (int n = 0; n < 4; ++n) {
        const int o = n * 16 + r;
        bv[n] = *reinterpret_cast<const bf16x8*>(wl + (tt * 64 + o) * 32 + (kq ^ ((o & 3) << 3)));
      }
      #pragma unroll
      for (int m = 0; m < 2; ++m)
        #pragma unroll
        for (int n = 0; n < 4; ++n)
          acc[m][n] = __builtin_amdgcn_mfma_f32_16x16x32_bf16(av[m][n >> 1], bv[n], acc[m][n], 0, 0, 0);
    }

    #pragma unroll
    for (int n = 0; n < 4; ++n) {
      const int o = n * 16 + r;
      const float bias = cpb[o];
      float s2 = 0.f;
      #pragma unroll
      for (int m = 0; m < 2; ++m) {
        #pragma unroll
        for (int rg = 0; rg < 4; ++rg) {
          float v = acc[m][n][rg] + bias;
          acc[m][n][rg] = v;
          s2 += v * v;
        }
      }
      s2 += __shfl_xor(s2, 16); s2 += __shfl_xor(s2, 32);
      if (lane < 16) red[wv][n * 16 + lane] = s2;
    }
    __syncthreads();
    if (t < 64) {
      float S = red[0][t] + red[1][t] + red[2][t] + red[3][t];
      float nn = sqrtf(S);
      fl[t] = (1.f - 1.f / (expf(nn) + 1e-21f)) / (nn + 1e-21f);
    }
    __syncthreads();

    float s0[2][4], s1[2][4];
    #pragma unroll
    for (int m = 0; m < 2; ++m)
      #pragma unroll
      for (int rg = 0; rg < 4; ++rg) { s0[m][rg] = 0.f; s1[m][rg] = 0.f; }
    #pragma unroll
    for (int n = 0; n < 4; ++n) {
      const int o = n * 16 + r;
      const float fact = fl[o];
      #pragma unroll
      for (int m = 0; m < 2; ++m) {
        const int l0 = wv * 32 + m * 16 + q * 4;
        uint2 rw0 = *reinterpret_cast<const uint2*>(rwp + (size_t)o * 128 + l0);
        uint2 rw1 = *reinterpret_cast<const uint2*>(rwp + (size_t)(64 + o) * 128 + l0);
        #pragma unroll
        for (int rg = 0; rg < 4; ++rg) {
          float v = acc[m][n][rg] * fact;
          u32 w0w = (rg < 2) ? rw0.x : rw0.y;
          u32 w1w = (rg < 2) ? rw1.x : rw1.y;
          float w0 = __uint_as_float((rg & 1) ? (w0w & 0xffff0000u) : (w0w << 16));
          float w1 = __uint_as_float((rg & 1) ? (w1w & 0xffff0000u) : (w1w << 16));
          s0[m][rg] = fmaf(v, w0, s0[m][rg]);
          s1[m][rg] = fmaf(v, w1, s1[m][rg]);
        }
      }
    }
    #pragma unroll
    for (int m = 0; m < 2; ++m)
      #pragma unroll
      for (int rg = 0; rg < 4; ++rg) {
        #pragma unroll
        for (int off = 1; off <= 8; off <<= 1) {
          s0[m][rg] += __shfl_xor(s0[m][rg], off);
          s1[m][rg] += __shfl_xor(s1[m][rg], off);
        }
      }
    float n0 = 0.f, n1 = 0.f;
    #pragma unroll
    for (int m = 0; m < 2; ++m)
      #pragma unroll
      for (int rg = 0; rg < 4; ++rg) {
        n0 = fmaf(s0[m][rg], s0[m][rg], n0);
        n1 = fmaf(s1[m][rg], s1[m][rg], n1);
      }
    n0 += __shfl_xor(n0, 16); n0 += __shfl_xor(n0, 32);
    n1 += __shfl_xor(n1, 16); n1 += __shfl_xor(n1, 32);
    if (lane == 0) { red2[wv][0] = n0; red2[wv][1] = n1; }
    __syncthreads();
    {
      float t0 = red2[0][0] + red2[1][0] + red2[2][0] + red2[3][0];
      float t1 = red2[0][1] + red2[1][1] + red2[2][1] + red2[3][1];
      float nn0 = sqrtf(t0), nn1 = sqrtf(t1);
      float fa0 = (1.f - 1.f / (expf(nn0) + 1e-21f)) / (nn0 + 1e-21f);
      float fa1 = (1.f - 1.f / (expf(nn1) + 1e-21f)) / (nn1 + 1e-21f);
      if (r == 0) {
        #pragma unroll
        for (int m = 0; m < 2; ++m)
          #pragma unroll
          for (int rg = 0; rg < 4; ++rg) {
            float v0 = s0[m][rg] * fa0, v1 = s1[m][rg] * fa1;
            float mx = fmaxf(v0, v1);
            int l = wv * 32 + m * 16 + q * 4 + rg;
            yl[0][l] = v0 + mx;
            yl[1][l] = v1 + mx;
          }
      }
    }
    __syncthreads();

    {
      const int h = t >> 7, idx = t & 127;
      const int jj = idx >> 6, qq = idx & 63;
      float a = 0.f;
      const float* yrow = &yl[jj][h * 64];
      const float* frow = f1l + (h * 64) * 64 + qq;
      #pragma unroll 8
      for (int tt = 0; tt < 64; ++tt)
        a = fmaf(yrow[tt], frow[tt * 64], a);
      if (h == 1) pt[idx] = a;
      __syncthreads();
      if (h == 0)
        y1[((size_t)b * 2 + jj) * 64 + qq] = a + pt[idx];
    }

    #pragma unroll
    for (int p = 0; p < 4; ++p) raw[p] = rawn[p];
  }
}

// ---------------- K9: BN stats stage 1 — partial sums over [B][2][per] ------
__global__ __launch_bounds__(256) void k_bnstat_part(const float* __restrict__ y,
                                                     float2* __restrict__ pp,
                                                     int perShift) {
  const int jj = blockIdx.y;
  const int per = 1 << perShift;
  const int n4 = (B << perShift) >> 2;
  const int p4shift = perShift - 2;
  const int p4mask = (per >> 2) - 1;
  float s = 0.f, q = 0.f;
  for (int i = blockIdx.x * 256 + threadIdx.x; i < n4; i += 64 * 256) {
    int bI = i >> p4shift, c4 = (i & p4mask) * 4;
    float4 v = *reinterpret_cast<const float4*>(
        y + (size_t)bI * (per * 2) + jj * per + c4);
    s += v.x + v.y + v.z + v.w;
    q += v.x * v.x + v.y * v.y + v.z * v.z + v.w * v.w;
  }
  #pragma unroll
  for (int off = 32; off; off >>= 1) { s += __shfl_down(s, off); q += __shfl_down(q, off); }
  __shared__ float rs[4], rq[4];
  int wv = threadIdx.x >> 6, ln = threadIdx.x & 63;
  if (ln == 0) { rs[wv] = s; rq[wv] = q; }
  __syncthreads();
  if (threadIdx.x == 0)
    pp[jj * 64 + blockIdx.x] =
        make_float2(rs[0] + rs[1] + rs[2] + rs[3], rq[0] + rq[1] + rq[2] + rq[3]);
}

// ---------------- K9b: BN stats stage 2 — 64 partials -> scale/shift --------
__global__ void k_bnstat_fin(const float2* __restrict__ pp, const float* __restrict__ g,
                             const float* __restrict__ bb, float* __restrict__ scale,
                             float* __restrict__ shift, int perShift) {
  const int jj = blockIdx.x;
  float2 p = pp[jj * 64 + threadIdx.x];
  float s = p.x, q = p.y;
  #pragma unroll
  for (int off = 32; off; off >>= 1) { s += __shfl_down(s, off); q += __shfl_down(q, off); }
  if (threadIdx.x == 0) {
    float fn = (float)(B << perShift);
    float mu = s / fn, var = q / fn - mu * mu;
    float sc = g[jj] * rsqrtf(var + 1e-5f);
    scale[jj] = sc; shift[jj] = bb[jj] - mu * sc;
  }
}

// ---------------- K10: bn1+relu+fc2 -----------------------------------------
__global__ void k_fc2(const float* __restrict__ y1, const float* __restrict__ sc1,
                      const float* __restrict__ sh1, const float* __restrict__ f2,
                      float* __restrict__ y2) {
  int t = threadIdx.x;
  int b = blockIdx.x * 4 + (t >> 6);
  int jj = (t >> 5) & 1, r = t & 31;
  float sc = sc1[jj], sh = sh1[jj];
  const float* yb = y1 + (size_t)b * 128 + jj * 64;
  float acc = 0.f;
  for (int q = 0; q < 64; ++q) {
    float v = fmaxf(fmaf(yb[q], sc, sh), 0.f);
    acc = fmaf(v, f2[q * 32 + r], acc);
  }
  y2[(size_t)b * 64 + jj * 32 + r] = acc;
}

// ---------------- K12: bn2+relu+fc3+sigmoid+max -----------------------------
__global__ void k_head(const float* __restrict__ y2, const float* __restrict__ sc2,
                       const float* __restrict__ sh2, const float* __restrict__ f3,
                       float* __restrict__ out) {
  int b = blockIdx.x * 256 + threadIdx.x;
  if (b >= B) return;
  const float* yb = y2 + (size_t)b * 64;
  float c0 = sc2[0], d0 = sh2[0], c1v = sc2[1], d1 = sh2[1];
  float a0 = 0.f, a1 = 0.f;
  for (int r = 0; r < 32; ++r) {
    float w = f3[r];
    a0 = fmaf(fmaxf(fmaf(yb[r], c0, d0), 0.f), w, a0);
    a1 = fmaf(fmaxf(fmaf(yb[32 + r], c1v, d1), 0.f), w, a1);
  }
  float s0 = 1.f / (1.f + expf(-a0));
  float s1 = 1.f / (1.f + expf(-a1));
  out[b] = fmaxf(s0, s1);
}

// ---------------- workspace layout ------------------------------------------
constexpr size_t SZ_H2    = (size_t)B * SQ * 128 * 2;   // 42,991,616 (bf16)
constexpr size_t SZ_C1    = (size_t)B * 64 * 128 * 2;   // 67,108,864 (bf16)
constexpr size_t OFF_H2   = 0;
constexpr size_t OFF_H3   = SZ_H2;
constexpr size_t R1       = 2 * SZ_H2;         // 85,983,232
constexpr size_t OFF_G    = R1;                                 // 314,880
constexpr size_t OFF_T1   = OFF_G + 314880;                     // 2,624,000
constexpr size_t OFF_T2   = OFF_T1 + 2624000;                   // 6,560,000 (bf16)
constexpr size_t OFF_CMB  = OFF_T2 + 6560000;                   //   671,744
constexpr size_t OFF_W7T  = OFF_CMB + 671744;  // 9,404,416 bf16; dead by K5
constexpr size_t OFF_C1   = R1;                // overlaps tables+w7t (dead by K5)
constexpr size_t R2       = R1 + SZ_C1;        // 153,092,096
constexpr size_t OFF_PART = R2;                                 // 2,097,152
constexpr size_t OFF_Y1   = OFF_PART + 2097152;                 // 2,097,152
constexpr size_t OFF_Y2   = OFF_Y1 + 2097152;                   // 1,048,576
constexpr size_t OFF_SM   = OFF_Y2 + 1048576;                   //     1,024
constexpr size_t OFF_BNP  = OFF_SM + 1024;                      //     1,024
constexpr size_t OFF_WPK  = OFF_BNP + 1024;                     //    24,576
constexpr size_t OFF_CPK  = OFF_WPK + 24576;                    //    12,288
constexpr size_t OFF_RWP  = OFF_CPK + 12288;                    //    32,768

extern "C" void kernel_launch(void* const* d_in, const int* in_sizes, int n_in,
                              void* d_out, int out_size, void* d_ws, size_t ws_size,
                              hipStream_t stream) {
  const int*   x   = (const int*)d_in[0];
  const float* emb = (const float*)d_in[1];
  const float* W3  = (const float*)d_in[2];
  const float* b3  = (const float*)d_in[3];
  const float* W5  = (const float*)d_in[4];
  const float* b5  = (const float*)d_in[5];
  const float* W7  = (const float*)d_in[6];
  const float* b7  = (const float*)d_in[7];
  const float* c1w = (const float*)d_in[8];
  const float* c1b = (const float*)d_in[9];
  const float* bng = (const float*)d_in[10];
  const float* bnb = (const float*)d_in[11];
  const float* cpw = (const float*)d_in[12];
  const float* cpb = (const float*)d_in[13];
  const float* rW  = (const float*)d_in[14];
  const float* rb  = (const float*)d_in[15];
  const float* f1  = (const float*)d_in[16];
  const float* g1  = (const float*)d_in[17];
  const float* bb1 = (const float*)d_in[18];
  const float* f2  = (const float*)d_in[19];
  const float* g2  = (const float*)d_in[20];
  const float* bb2 = (const float*)d_in[21];
  const float* f3  = (const float*)d_in[22];

  char* wsb = (char*)d_ws;
  u16*    h2p   = (u16*)(wsb + OFF_H2);
  u16*    h3p   = (u16*)(wsb + OFF_H3);
  float*  Gp    = (float*)(wsb + OFF_G);
  float*  t1p   = (float*)(wsb + OFF_T1);
  u16*    t2p   = (u16*)(wsb + OFF_T2);
  int*    cmbp  = (int*)(wsb + OFF_CMB);
  u16*    w7tp  = (u16*)(wsb + OFF_W7T);
  u16*    c1p   = (u16*)(wsb + OFF_C1);
  float2* partp = (float2*)(wsb + OFF_PART);
  float*  y1p   = (float*)(wsb + OFF_Y1);
  float*  y2p   = (float*)(wsb + OFF_Y2);
  float*  scp   = (float*)(wsb + OFF_SM);
  float*  shp   = scp + 64;
  float*  sc1p  = shp + 64;
  float*  sh1p  = sc1p + 2;
  float*  sc2p  = sh1p + 2;
  float*  sh2p  = sc2p + 2;
  float2* bnpp  = (float2*)(wsb + OFF_BNP);
  u16*    wpkp  = (u16*)(wsb + OFF_WPK);
  u16*    cpkp  = (u16*)(wsb + OFF_CPK);
  u16*    rwpp  = (u16*)(wsb + OFF_RWP);

  k_pack<<<136, 256, 0, stream>>>(c1w, cpw, rW, rb, wpkp, cpkp, rwpp);
  k_combo<<<(B * SQ + 255) / 256, 256, 0, stream>>>(x, cmbp);
  k_w7t<<<dim3(14, 2, SQ), 256, 0, stream>>>(W7, w7tp);
  k_gmat<<<SQ * 3, 128, 0, stream>>>(emb, W3, Gp);
  k_t1<<<(SQ * 128 * 125 + 255) / 256, 256, 0, stream>>>(Gp, b3, t1p);
  k_t2<<<SQ * 25, 128, 0, stream>>>(t1p, W5, t2p);
  k_h2<<<(B * SQ * 16) / 256, 256, 0, stream>>>(t2p, cmbp, b5, h2p);
  k_gemm7_mfma<<<dim3(32, SQ), 256, 0, stream>>>(h2p, w7tp, b7, h3p);
  k_conv1<<<B / NBC, 256, 0, stream>>>(h3p, wpkp, c1b, c1p, partp);
  k_bnfin<<<64, 256, 0, stream>>>(partp, bng, bnb, scp, shp);
  k_caps<<<B / NB, 256, 0, stream>>>(c1p, scp, shp, cpkp, cpb, rwpp, f1, y1p);
  k_bnstat_part<<<dim3(64, 2), 256, 0, stream>>>(y1p, bnpp, 6);
  k_bnstat_fin<<<2, 64, 0, stream>>>(bnpp, g1, bb1, sc1p, sh1p, 6);
  k_fc2<<<B / 4, 256, 0, stream>>>(y1p, sc1p, sh1p, f2, y2p);
  k_bnstat_part<<<dim3(64, 2), 256, 0, stream>>>(y2p, bnpp, 5);
  k_bnstat_fin<<<2, 64, 0, stream>>>(bnpp, g2, bb2, sc2p, sh2p, 5);
  k_head<<<B / 256, 256, 0, stream>>>(y2p, sc2p, sh2p, f3, (float*)d_out);
}

// Round 13
// 216.347 us; speedup vs baseline: 1.2018x; 1.0908x over previous
//
#include <hip/hip_runtime.h>
#include <cstdint>

typedef unsigned short u16;
typedef unsigned int   u32;
typedef __attribute__((ext_vector_type(8))) short bf16x8;
typedef __attribute__((ext_vector_type(4))) float f32x4;

#define DEVFN static __device__ __forceinline__

constexpr int B  = 4096;
constexpr int SQ = 41;

DEVFN float bf2f(u16 v) { return __uint_as_float(((u32)v) << 16); }
DEVFN u16 f2bf(float f) {
  u32 u = __float_as_uint(f);
  u += 0x7fffu + ((u >> 16) & 1u);
  return (u16)(u >> 16);
}
DEVFN u32 pack2(float a, float b) { return (u32)f2bf(a) | ((u32)f2bf(b) << 16); }

DEVFN void gload16(const void* g, void* l) {
  __builtin_amdgcn_global_load_lds(
      (const __attribute__((address_space(1))) unsigned int*)g,
      (__attribute__((address_space(3))) unsigned int*)l, 16, 0, 0);
}

// ---------------- K-1: pack weights into swizzled bf16 global images --------
__global__ void k_pack(const float* __restrict__ cw, const float* __restrict__ cpw,
                       const float* __restrict__ rW, const float* __restrict__ rb,
                       u16* __restrict__ wpk, u16* __restrict__ cpk,
                       u16* __restrict__ rwp) {
  int i = blockIdx.x * 256 + threadIdx.x;
  if (i < 12288) {                    // conv1 weights [t][o][c^swz], c padded 64
    int tt = i >> 12, rem = i & 4095, o = rem >> 6, c = rem & 63;
    float v = (c < 41) ? cw[(o * 41 + c) * 3 + tt] : 0.f;
    wpk[(tt * 64 + o) * 64 + (c ^ ((o & 7) << 3))] = f2bf(v);
  } else if (i < 18432) {             // caps weights [t][o][cg^swz]
    int k = i - 12288;
    int tt = k >> 11, rem = k & 2047, o = rem >> 5, c = rem & 31;
    cpk[(tt * 64 + o) * 32 + (c ^ ((o & 3) << 3))] = f2bf(cpw[(o * 32 + c) * 3 + tt]);
  } else if (i < 34816) {             // routing weights [j*64+o][l] * (1+rb)
    int k = i - 18432;
    rwp[k] = f2bf(rW[k] * (1.f + rb[k >> 7]));
  }
}

// ---------------- K0: combo indices [B][41], symbols 0..3, pad=4 -------------
__global__ void k_combo(const int* __restrict__ x, int* __restrict__ combo) {
  int i = blockIdx.x * 256 + threadIdx.x;
  if (i >= B * SQ) return;
  int b = i / SQ, s = i - b * SQ;
  const int* xb = x + b * SQ;
  int d0 = (s > 0) ? xb[s - 1] : 4;
  int d1 = xb[s];
  int d2 = (s < SQ - 1) ? xb[s + 1] : 4;
  combo[i] = d0 * 25 + d1 * 5 + d2;
}

// ---------------- K1a: G[s][w][sym][o] = sum_f emb[sym][f]*W3[s][w*128+f][o] -
__global__ void k_gmat(const float* __restrict__ emb, const float* __restrict__ W3,
                       float* __restrict__ G) {
  int s = blockIdx.x / 3, ww = blockIdx.x % 3;
  int o = threadIdx.x;
  const float* Ws = W3 + ((size_t)s * 384 + ww * 128) * 128;
  float a0 = 0.f, a1 = 0.f, a2 = 0.f, a3 = 0.f;
  for (int f = 0; f < 128; ++f) {
    float wg = Ws[(size_t)f * 128 + o];
    a0 = fmaf(emb[f], wg, a0);
    a1 = fmaf(emb[128 + f], wg, a1);
    a2 = fmaf(emb[256 + f], wg, a2);
    a3 = fmaf(emb[384 + f], wg, a3);
  }
  float* Gp = G + ((size_t)(s * 3 + ww) * 5) * 128 + o;
  Gp[0] = a0; Gp[128] = a1; Gp[256] = a2; Gp[384] = a3; Gp[512] = 0.f;
}

// ---------------- K1b: t1b[s][v(128)][f] bf16 = relu(b3 + G0+G1+G2) ---------
__global__ void k_t1(const float* __restrict__ G, const float* __restrict__ b3,
                     u16* __restrict__ t1b) {
  int i = blockIdx.x * 256 + threadIdx.x;   // SQ*128*128
  int f = i & 127, v = (i >> 7) & 127, s = i >> 14;
  u16 out = 0;
  if (v < 125) {
    int d0 = v / 25, r = v % 25;
    int d1 = r / 5, d2 = r % 5;
    float acc = b3[s * 128 + f]
        + G[((size_t)(s * 3 + 0) * 5 + d0) * 128 + f]
        + G[((size_t)(s * 3 + 1) * 5 + d1) * 128 + f]
        + G[((size_t)(s * 3 + 2) * 5 + d2) * 128 + f];
    out = f2bf(fmaxf(acc, 0.f));
  }
  t1b[i] = out;
}

// ---------------- K1c: W5 [41][640][128] f32 -> w5t [41*5][128o][128f] bf16 -
__global__ __launch_bounds__(256) void k_w5t(const float* __restrict__ W5,
                                             u16* __restrict__ w5t) {
  __shared__ float tile[64][65];
  const int sw = blockIdx.z;                 // s*5 + w
  const int s = sw / 5, w = sw % 5;
  const int f0 = blockIdx.x * 64;
  const int o0 = blockIdx.y * 64;
  const int t = threadIdx.x;
  const float* Ws = W5 + ((size_t)s * 640 + w * 128) * 128;
  #pragma unroll
  for (int i = 0; i < 16; ++i) {
    int idx = t + i * 256;
    int fl = idx >> 6, ol = idx & 63;
    tile[fl][ol] = Ws[(size_t)(f0 + fl) * 128 + o0 + ol];
  }
  __syncthreads();
  #pragma unroll
  for (int i = 0; i < 16; ++i) {
    int idx = t + i * 256;
    int ol = idx >> 6, fl = idx & 63;
    w5t[((size_t)sw * 128 + o0 + ol) * 128 + f0 + fl] = f2bf(tile[fl][ol]);
  }
}

// ---------------- K2: t2[s*5+w][v<125][o] via MFMA (single K=128 tile) ------
// A = t1b[t][v][f] (v rows), B = w5t[sw][o][f]; D[v][o]. Invalid t: skip
// (k_h2 never reads those windows). Same swizzle pattern as gemm7.
__global__ __launch_bounds__(256) void k_t2_mfma(const u16* __restrict__ t1b,
                                                 const u16* __restrict__ w5t,
                                                 u16* __restrict__ t2) {
  __shared__ u16 As[2][8192];   // [k-half][row v][64 k-granule^swz]
  __shared__ u16 Bs[2][8192];   // [k-half][row o][64 k-granule^swz]
  const int sw = blockIdx.x;                 // s*5 + w
  const int s = sw / 5, w5 = sw % 5;
  const int tw = s + w5 - 2;
  if (tw < 0 || tw >= SQ) return;            // window out of range: never read
  const int t = threadIdx.x;
  const int lane = t & 63, w = t >> 6;
  const int wr = w >> 1, wc = w & 1;
  const int lcol = lane & 15, qk = lane >> 4;

  const u16* abase = t1b + (size_t)tw * 128 * 128;
  const u16* bbase = w5t + (size_t)sw * 128 * 128;
  #pragma unroll
  for (int h = 0; h < 2; ++h) {
    #pragma unroll
    for (int it = 0; it < 4; ++it) {
      const int L = it * 4096 + t * 16;
      const int r = L >> 7, g = (L >> 4) & 7;
      const int gs = g ^ (r & 7);
      gload16(abase + (size_t)r * 128 + h * 64 + gs * 8,
              (char*)As[h] + it * 4096 + w * 1024);
      gload16(bbase + (size_t)r * 128 + h * 64 + gs * 8,
              (char*)Bs[h] + it * 4096 + w * 1024);
    }
  }
  __syncthreads();

  f32x4 acc[4][4];
  #pragma unroll
  for (int i = 0; i < 4; ++i)
    #pragma unroll
    for (int j = 0; j < 4; ++j) acc[i][j] = (f32x4){0.f, 0.f, 0.f, 0.f};

  #pragma unroll
  for (int h = 0; h < 2; ++h) {
    #pragma unroll
    for (int kk = 0; kk < 2; ++kk) {
      const int gk = kk * 4 + qk;
      bf16x8 av[4], bv[4];
      #pragma unroll
      for (int m = 0; m < 4; ++m) {
        const int zr = wr * 64 + m * 16 + lcol;
        av[m] = *reinterpret_cast<const bf16x8*>(&As[h][zr * 64 + ((gk ^ (zr & 7)) << 3)]);
      }
      #pragma unroll
      for (int n = 0; n < 4; ++n) {
        const int br = wc * 64 + n * 16 + lcol;
        bv[n] = *reinterpret_cast<const bf16x8*>(&Bs[h][br * 64 + ((gk ^ (br & 7)) << 3)]);
      }
      #pragma unroll
      for (int m = 0; m < 4; ++m)
        #pragma unroll
        for (int n = 0; n < 4; ++n)
          acc[m][n] = __builtin_amdgcn_mfma_f32_16x16x32_bf16(av[m], bv[n], acc[m][n], 0, 0, 0);
    }
  }

  u16* dst = t2 + (size_t)sw * 125 * 128;
  const int rq = (lane >> 4) * 4;
  #pragma unroll
  for (int n = 0; n < 4; ++n) {
    const int o = wc * 64 + n * 16 + lcol;
    #pragma unroll
    for (int m = 0; m < 4; ++m) {
      #pragma unroll
      for (int rg = 0; rg < 4; ++rg) {
        const int row = wr * 64 + m * 16 + rq + rg;
        if (row < 125) dst[(size_t)row * 128 + o] = f2bf(acc[m][n][rg]);
      }
    }
  }
}

// ---------------- K3: h2[b][s][o] = relu(b5 + sum_w t2[s][w][combo]) --------
__global__ __launch_bounds__(256) void k_h2(const u16* __restrict__ t2,
                                            const int* __restrict__ combo,
                                            const float* __restrict__ b5,
                                            u16* __restrict__ h2) {
  const int i = blockIdx.x * 256 + threadIdx.x;   // B*41*16 total
  const int o8 = (i & 15) * 8;
  const int rid = i >> 4;                          // s-major: s = rid>>12
  const int s = rid >> 12, b = rid & 4095;
  float acc[8];
  {
    float4 b0 = *reinterpret_cast<const float4*>(b5 + s * 128 + o8);
    float4 b1 = *reinterpret_cast<const float4*>(b5 + s * 128 + o8 + 4);
    acc[0] = b0.x; acc[1] = b0.y; acc[2] = b0.z; acc[3] = b0.w;
    acc[4] = b1.x; acc[5] = b1.y; acc[6] = b1.z; acc[7] = b1.w;
  }
  const int* cb = combo + b * SQ;
  #pragma unroll
  for (int ww = 0; ww < 5; ++ww) {
    const int t = s + ww - 2;
    if (0 <= t && t < SQ) {
      const int c = cb[t];
      uint4 raw = *reinterpret_cast<const uint4*>(
          t2 + ((size_t)(s * 5 + ww) * 125 + c) * 128 + o8);
      acc[0] += __uint_as_float(raw.x << 16);
      acc[1] += __uint_as_float(raw.x & 0xffff0000u);
      acc[2] += __uint_as_float(raw.y << 16);
      acc[3] += __uint_as_float(raw.y & 0xffff0000u);
      acc[4] += __uint_as_float(raw.z << 16);
      acc[5] += __uint_as_float(raw.z & 0xffff0000u);
      acc[6] += __uint_as_float(raw.w << 16);
      acc[7] += __uint_as_float(raw.w & 0xffff0000u);
    }
  }
  uint4 pk;
  pk.x = pack2(fmaxf(acc[0], 0.f), fmaxf(acc[1], 0.f));
  pk.y = pack2(fmaxf(acc[2], 0.f), fmaxf(acc[3], 0.f));
  pk.z = pack2(fmaxf(acc[4], 0.f), fmaxf(acc[5], 0.f));
  pk.w = pack2(fmaxf(acc[6], 0.f), fmaxf(acc[7], 0.f));
  *reinterpret_cast<uint4*>(h2 + ((size_t)b * SQ + s) * 128 + o8) = pk;
}

// ---------------- K4a: W7 [41][896][128] f32 -> w7t [41][128][896] bf16 -----
__global__ __launch_bounds__(256) void k_w7t(const float* __restrict__ W7,
                                             u16* __restrict__ w7t) {
  __shared__ float tile[64][65];
  const int s = blockIdx.z;
  const int k0 = blockIdx.x * 64;   // 896/64 = 14
  const int o0 = blockIdx.y * 64;   // 128/64 = 2
  const int t = threadIdx.x;
  #pragma unroll
  for (int i = 0; i < 16; ++i) {
    int idx = t + i * 256;
    int kl = idx >> 6, ol = idx & 63;
    tile[kl][ol] = W7[((size_t)s * 896 + k0 + kl) * 128 + o0 + ol];
  }
  __syncthreads();
  #pragma unroll
  for (int i = 0; i < 16; ++i) {
    int idx = t + i * 256;
    int ol = idx >> 6, kl = idx & 63;
    w7t[((size_t)s * 128 + o0 + ol) * 896 + k0 + kl] = f2bf(tile[kl][ol]);
  }
}

// ---------------- K4b: layer-3 GEMM, BK=64 dbuf + counted vmcnt pipeline ----
__global__ __launch_bounds__(256) void k_gemm7_mfma(const u16* __restrict__ h2,
                                                    const u16* __restrict__ w7t,
                                                    const float* __restrict__ b7,
                                                    u16* __restrict__ h3) {
  __shared__ u16 As[2][8192];   // [buf][row][k-granule^swz] 2x16 KB
  __shared__ u16 Bs[2][8192];   // [buf][o][k-granule^swz]   2x16 KB
  const int s  = blockIdx.y;
  const int b0 = blockIdx.x * 128;
  const int t  = threadIdx.x;
  const int lane = t & 63, w = t >> 6;
  const int wr = w >> 1, wc = w & 1;            // wave -> 64x64 quadrant
  const int lcol = lane & 15, qk = lane >> 4;   // qk: k-granule quarter 0..3

  f32x4 acc[4][4];
  #pragma unroll
  for (int i = 0; i < 4; ++i)
    #pragma unroll
    for (int j = 0; j < 4; ++j) acc[i][j] = (f32x4){0.f, 0.f, 0.f, 0.f};

  const u16* wbase = w7t + (size_t)s * 128 * 896;

  auto stage = [&](int kt, int bi) -> int {
    const int k0 = kt * 64;
    const int ww = k0 >> 7, tr = s + ww - 3, kf0 = k0 & 127;
    int issued = 0;
    if (0 <= tr && tr < SQ) {
      #pragma unroll
      for (int it = 0; it < 4; ++it) {
        const int L = it * 4096 + t * 16;       // dest byte offset
        const int r = L >> 7;                   // tile row 0..127
        const int g = (L >> 4) & 7;             // dest 16B granule in row
        const int gs = g ^ (r & 7);             // pre-swizzled source granule
        gload16(h2 + ((size_t)(b0 + r) * SQ + tr) * 128 + kf0 + gs * 8,
                (char*)As[bi] + it * 4096 + w * 1024);
      }
      issued += 4;
    } else {
      #pragma unroll
      for (int it = 0; it < 4; ++it)
        *reinterpret_cast<uint4*>((char*)As[bi] + it * 4096 + t * 16) =
            make_uint4(0u, 0u, 0u, 0u);
    }
    #pragma unroll
    for (int it = 0; it < 4; ++it) {
      const int L = it * 4096 + t * 16;
      const int o = L >> 7;
      const int g = (L >> 4) & 7;
      const int gs = g ^ (o & 7);
      gload16(wbase + (size_t)o * 896 + k0 + gs * 8,
              (char*)Bs[bi] + it * 4096 + w * 1024);
    }
    return issued + 4;
  };

  stage(0, 0);   // prologue

  for (int kt = 0; kt < 14; ++kt) {
    const int cur = kt & 1;
    int ni = 0;
    if (kt < 13) ni = stage(kt + 1, cur ^ 1);
    if (ni == 8)      asm volatile("s_waitcnt vmcnt(8) lgkmcnt(0)" ::: "memory");
    else if (ni == 4) asm volatile("s_waitcnt vmcnt(4) lgkmcnt(0)" ::: "memory");
    else              asm volatile("s_waitcnt vmcnt(0) lgkmcnt(0)" ::: "memory");
    __builtin_amdgcn_sched_barrier(0);
    __builtin_amdgcn_s_barrier();          // buf[cur] ready for all waves
    __builtin_amdgcn_sched_barrier(0);

    const u16* Ac = As[cur];
    const u16* Bc = Bs[cur];
    #pragma unroll
    for (int kk = 0; kk < 2; ++kk) {
      const int gk = kk * 4 + qk;          // logical k-granule 0..7
      bf16x8 av[4], bv[4];
      #pragma unroll
      for (int m = 0; m < 4; ++m) {
        const int zr = wr * 64 + m * 16 + lcol;
        av[m] = *reinterpret_cast<const bf16x8*>(Ac + zr * 64 + ((gk ^ (zr & 7)) << 3));
      }
      #pragma unroll
      for (int n = 0; n < 4; ++n) {
        const int br = wc * 64 + n * 16 + lcol;
        bv[n] = *reinterpret_cast<const bf16x8*>(Bc + br * 64 + ((gk ^ (br & 7)) << 3));
      }
      #pragma unroll
      for (int m = 0; m < 4; ++m)
        #pragma unroll
        for (int n = 0; n < 4; ++n)
          acc[m][n] = __builtin_amdgcn_mfma_f32_16x16x32_bf16(av[m], bv[n], acc[m][n], 0, 0, 0);
    }
    __builtin_amdgcn_sched_barrier(0);
    __builtin_amdgcn_s_barrier();          // all reads of buf[cur] done
  }

  const int rq = (lane >> 4) * 4;
  #pragma unroll
  for (int n = 0; n < 4; ++n) {
    const int o = wc * 64 + n * 16 + lcol;
    const float bias = b7[s * 128 + o];
    #pragma unroll
    for (int m = 0; m < 4; ++m) {
      #pragma unroll
      for (int rg = 0; rg < 4; ++rg) {
        const int row = b0 + wr * 64 + m * 16 + rq + rg;
        h3[((size_t)row * SQ + s) * 128 + o] = f2bf(fmaxf(acc[m][n][rg] + bias, 0.f));
      }
    }
  }
}

// ---------------- K5: conv1 via MFMA, NB=8 batched + zs double buffer -------
constexpr int NBC = 8;
__global__ __launch_bounds__(256) void k_conv1(const u16* __restrict__ h3,
                                               const u16* __restrict__ wpk,
                                               const float* __restrict__ cb,
                                               u16* __restrict__ c1T,
                                               float2* __restrict__ part) {
  __shared__ u16 zs[2][6144];        // h3[b] staging dbuf (2x12 KB)
  __shared__ u16 zt[130 * 64];       // transposed [l+1][c^swz]
  __shared__ u16 wl[3 * 64 * 64];    // weights [t][o][c^swz]
  __shared__ float2 red[4][64];
  const int b0 = blockIdx.x * NBC;
  const int t = threadIdx.x;
  const int lane = t & 63, wv = t >> 6;
  const int r = lane & 15, kq = (lane >> 4) * 8, q = lane >> 4;

  #pragma unroll
  for (int it = 0; it < 6; ++it)
    gload16(wpk + ((size_t)it * 256 + t) * 8, (char*)wl + it * 4096 + wv * 1024);
  #pragma unroll
  for (int it = 0; it < 3; ++it)
    gload16(h3 + (size_t)b0 * (SQ * 128) + ((size_t)it * 256 + t) * 8,
            (char*)zs[0] + it * 4096 + wv * 1024);
  if (t < 64) zt[t] = 0;
  else if (t < 128) zt[129 * 64 + t - 64] = 0;
  __syncthreads();   // wl + zs[0] ready (drains vmcnt)

  for (int i = 0; i < NBC; ++i) {
    const int b = b0 + i;
    const int cur = i & 1;

    {
      const int l = t & 127, jb = (t >> 7) * 32;
      const int sw = ((l + 1) & 7) << 3;
      u16* dst = zt + (l + 1) * 64;
      const u16* srcz = zs[cur];
      #pragma unroll
      for (int j = 0; j < 32; ++j) {
        int c = (jb + j + l) & 63;
        dst[c ^ sw] = (c < 41) ? srcz[c * 128 + l] : (u16)0;
      }
    }
    if (i + 1 < NBC) {
      #pragma unroll
      for (int it = 0; it < 3; ++it)
        gload16(h3 + (size_t)(b + 1) * (SQ * 128) + ((size_t)it * 256 + t) * 8,
                (char*)zs[cur ^ 1] + it * 4096 + wv * 1024);
    }
    asm volatile("s_waitcnt lgkmcnt(0)" ::: "memory");
    __builtin_amdgcn_sched_barrier(0);
    __builtin_amdgcn_s_barrier();
    __builtin_amdgcn_sched_barrier(0);

    f32x4 acc[2][4];
    #pragma unroll
    for (int m = 0; m < 2; ++m)
      #pragma unroll
      for (int n = 0; n < 4; ++n) acc[m][n] = (f32x4){0.f, 0.f, 0.f, 0.f};
    #pragma unroll
    for (int tt = 0; tt < 3; ++tt) {
      #pragma unroll
      for (int kk = 0; kk < 2; ++kk) {
        const int kof = kk * 32 + kq;
        bf16x8 av[2], bv[4];
        #pragma unroll
        for (int m = 0; m < 2; ++m) {
          const int zr = wv * 32 + m * 16 + r + tt;
          av[m] = *reinterpret_cast<const bf16x8*>(zt + zr * 64 + (kof ^ ((zr & 7) << 3)));
        }
        #pragma unroll
        for (int n = 0; n < 4; ++n) {
          const int o = n * 16 + r;
          bv[n] = *reinterpret_cast<const bf16x8*>(wl + (tt * 64 + o) * 64 + (kof ^ ((o & 7) << 3)));
        }
        #pragma unroll
        for (int m = 0; m < 2; ++m)
          #pragma unroll
          for (int n = 0; n < 4; ++n)
            acc[m][n] = __builtin_amdgcn_mfma_f32_16x16x32_bf16(av[m], bv[n], acc[m][n], 0, 0, 0);
      }
    }

    u16* outb = c1T + (size_t)b * 8192;
    #pragma unroll
    for (int n = 0; n < 4; ++n) {
      const int o = n * 16 + r;
      const float bias = cb[o];
      float s1 = 0.f, s2 = 0.f;
      #pragma unroll
      for (int m = 0; m < 2; ++m) {
        #pragma unroll
        for (int rg = 0; rg < 4; ++rg) {
          float v = acc[m][n][rg] + bias;
          s1 += v; s2 += v * v;
          outb[(wv * 32 + m * 16 + q * 4 + rg) * 64 + o] = f2bf(v);
        }
      }
      s1 += __shfl_xor(s1, 16); s1 += __shfl_xor(s1, 32);
      s2 += __shfl_xor(s2, 16); s2 += __shfl_xor(s2, 32);
      if (lane < 16) red[wv][n * 16 + lane] = make_float2(s1, s2);
    }
    __syncthreads();   // red ready; also drains prefetch vmcnt for next iter
    if (t < 64) {
      float S = red[0][t].x + red[1][t].x + red[2][t].x + red[3][t].x;
      float Q = red[0][t].y + red[1][t].y + red[2][t].y + red[3][t].y;
      part[(size_t)t * B + b] = make_float2(S, Q);
    }
    __syncthreads();   // red/zt reusable next iteration
  }
}

// ---------------- K6: finalize conv1 BN -> scale/shift per channel ----------
__global__ void k_bnfin(const float2* __restrict__ part, const float* __restrict__ g,
                        const float* __restrict__ bb, float* __restrict__ scale,
                        float* __restrict__ shift) {
  int o = blockIdx.x;
  float s = 0.f, q = 0.f;
  for (int i = threadIdx.x; i < B; i += 256) {
    float2 p = part[(size_t)o * B + i];
    s += p.x; q += p.y;
  }
  #pragma unroll
  for (int off = 32; off; off >>= 1) { s += __shfl_down(s, off); q += __shfl_down(q, off); }
  __shared__ float rs[4], rq[4];
  int wv = threadIdx.x >> 6, ln = threadIdx.x & 63;
  if (ln == 0) { rs[wv] = s; rq[wv] = q; }
  __syncthreads();
  if (threadIdx.x == 0) {
    float S = rs[0] + rs[1] + rs[2] + rs[3];
    float Q = rq[0] + rq[1] + rq[2] + rq[3];
    const float n = (float)B * 128.f;
    float mu = S / n, var = Q / n - mu * mu;
    float sc = g[o] * rsqrtf(var + 1e-5f);
    scale[o] = sc; shift[o] = bb[o] - mu * sc;
  }
}

// ---------------- K7: caps conv + squash + routing + fc1 + y1 BN partials ---
constexpr int NB = 8;
__global__ __launch_bounds__(256) void k_caps(const u16* __restrict__ c1T,
                                              const float* __restrict__ scale,
                                              const float* __restrict__ shift,
                                              const u16* __restrict__ cpk,
                                              const float* __restrict__ cpb,
                                              const u16* __restrict__ rwp,
                                              const float* __restrict__ f1,
                                              float* __restrict__ y1,
                                              float2* __restrict__ ppy1) {
  __shared__ u16 zt[130 * 64];
  __shared__ u16 wl[3 * 64 * 32];
  __shared__ float f1l[128 * 64];
  __shared__ float red[4][64];
  __shared__ float fl[64];
  __shared__ float sc_s[64], sh_s[64];
  __shared__ float red2[4][2];
  __shared__ float yl[2][128];
  __shared__ float pt[128];
  const int b0 = blockIdx.x * NB;
  const int t = threadIdx.x;
  const int lane = t & 63, wv = t >> 6;
  const int r = lane & 15, kq = (lane >> 4) * 8, q = lane >> 4;
  float ysum = 0.f, ysq = 0.f;     // y1-stat accumulators (h==1 threads add 0)

  #pragma unroll
  for (int it = 0; it < 3; ++it)
    gload16(cpk + ((size_t)it * 256 + t) * 8, (char*)wl + it * 4096 + wv * 1024);
  #pragma unroll
  for (int it = 0; it < 8; ++it)
    gload16(f1 + ((size_t)it * 256 + t) * 4, (char*)f1l + it * 4096 + wv * 1024);
  if (t < 64) { sc_s[t] = scale[t]; sh_s[t] = shift[t]; }
  if (t < 64) zt[t] = 0;
  else if (t < 128) zt[129 * 64 + t - 64] = 0;

  uint4 raw[4], rawn[4];
  {
    const u16* src = c1T + (size_t)b0 * 8192;
    #pragma unroll
    for (int p = 0; p < 4; ++p)
      raw[p] = *reinterpret_cast<const uint4*>(src + ((size_t)t + p * 256) * 8);
  }

  for (int i = 0; i < NB; ++i) {
    const int b = b0 + i;
    __syncthreads();

    #pragma unroll
    for (int p = 0; p < 4; ++p) {
      int idx = t + p * 256;
      int l = idx >> 3, c0 = (idx & 7) * 8;
      float vv[8];
      vv[0] = __uint_as_float(raw[p].x << 16); vv[1] = __uint_as_float(raw[p].x & 0xffff0000u);
      vv[2] = __uint_as_float(raw[p].y << 16); vv[3] = __uint_as_float(raw[p].y & 0xffff0000u);
      vv[4] = __uint_as_float(raw[p].z << 16); vv[5] = __uint_as_float(raw[p].z & 0xffff0000u);
      vv[6] = __uint_as_float(raw[p].w << 16); vv[7] = __uint_as_float(raw[p].w & 0xffff0000u);
      float a0 = fmaxf(fmaf(vv[0], sc_s[c0 + 0], sh_s[c0 + 0]), 0.f);
      float a1 = fmaxf(fmaf(vv[1], sc_s[c0 + 1], sh_s[c0 + 1]), 0.f);
      float a2 = fmaxf(fmaf(vv[2], sc_s[c0 + 2], sh_s[c0 + 2]), 0.f);
      float a3 = fmaxf(fmaf(vv[3], sc_s[c0 + 3], sh_s[c0 + 3]), 0.f);
      float a4 = fmaxf(fmaf(vv[4], sc_s[c0 + 4], sh_s[c0 + 4]), 0.f);
      float a5 = fmaxf(fmaf(vv[5], sc_s[c0 + 5], sh_s[c0 + 5]), 0.f);
      float a6 = fmaxf(fmaf(vv[6], sc_s[c0 + 6], sh_s[c0 + 6]), 0.f);
      float a7 = fmaxf(fmaf(vv[7], sc_s[c0 + 7], sh_s[c0 + 7]), 0.f);
      uint4 pk;
      pk.x = pack2(a0, a1); pk.y = pack2(a2, a3);
      pk.z = pack2(a4, a5); pk.w = pack2(a6, a7);
      *reinterpret_cast<uint4*>(zt + (l + 1) * 64 + (c0 ^ (((l + 1) & 7) << 3))) = pk;
    }
    if (i + 1 < NB) {
      const u16* srcn = c1T + (size_t)(b + 1) * 8192;
      #pragma unroll
      for (int p = 0; p < 4; ++p)
        rawn[p] = *reinterpret_cast<const uint4*>(srcn + ((size_t)t + p * 256) * 8);
    }
    __syncthreads();

    f32x4 acc[2][4];
    #pragma unroll
    for (int m = 0; m < 2; ++m)
      #pragma unroll
      for (int n = 0; n < 4; ++n) acc[m][n] = (f32x4){0.f, 0.f, 0.f, 0.f};
    #pragma unroll
    for (int tt = 0; tt < 3; ++tt) {
      bf16x8 av[2][2], bv[4];
      #pragma unroll
      for (int m = 0; m < 2; ++m) {
        const int zr = wv * 32 + m * 16 + r + tt;
        const int sw = (zr & 7) << 3;
        av[m][0] = *reinterpret_cast<const bf16x8*>(zt + zr * 64 + (kq ^ sw));
        av[m][1] = *reinterpret_cast<const bf16x8*>(zt + zr * 64 + ((32 + kq) ^ sw));
      }
      #pragma unroll
      for (int n = 0; n < 4; ++n) {
        const int o = n * 16 + r;
        bv[n] = *reinterpret_cast<const bf16x8*>(wl + (tt * 64 + o) * 32 + (kq ^ ((o & 3) << 3)));
      }
      #pragma unroll
      for (int m = 0; m < 2; ++m)
        #pragma unroll
        for (int n = 0; n < 4; ++n)
          acc[m][n] = __builtin_amdgcn_mfma_f32_16x16x32_bf16(av[m][n >> 1], bv[n], acc[m][n], 0, 0, 0);
    }

    #pragma unroll
    for (int n = 0; n < 4; ++n) {
      const int o = n * 16 + r;
      const float bias = cpb[o];
      float s2 = 0.f;
      #pragma unroll
      for (int m = 0; m < 2; ++m) {
        #pragma unroll
        for (int rg = 0; rg < 4; ++rg) {
          float v = acc[m][n][rg] + bias;
          acc[m][n][rg] = v;
          s2 += v * v;
        }
      }
      s2 += __shfl_xor(s2, 16); s2 += __shfl_xor(s2, 32);
      if (lane < 16) red[wv][n * 16 + lane] = s2;
    }
    __syncthreads();
    if (t < 64) {
      float S = red[0][t] + red[1][t] + red[2][t] + red[3][t];
      float nn = sqrtf(S);
      fl[t] = (1.f - 1.f / (expf(nn) + 1e-21f)) / (nn + 1e-21f);
    }
    __syncthreads();

    float s0[2][4], s1[2][4];
    #pragma unroll
    for (int m = 0; m < 2; ++m)
      #pragma unroll
      for (int rg = 0; rg < 4; ++rg) { s0[m][rg] = 0.f; s1[m][rg] = 0.f; }
    #pragma unroll
    for (int n = 0; n < 4; ++n) {
      const int o = n * 16 + r;
      const float fact = fl[o];
      #pragma unroll
      for (int m = 0; m < 2; ++m) {
        const int l0 = wv * 32 + m * 16 + q * 4;
        uint2 rw0 = *reinterpret_cast<const uint2*>(rwp + (size_t)o * 128 + l0);
        uint2 rw1 = *reinterpret_cast<const uint2*>(rwp + (size_t)(64 + o) * 128 + l0);
        #pragma unroll
        for (int rg = 0; rg < 4; ++rg) {
          float v = acc[m][n][rg] * fact;
          u32 w0w = (rg < 2) ? rw0.x : rw0.y;
          u32 w1w = (rg < 2) ? rw1.x : rw1.y;
          float w0 = __uint_as_float((rg & 1) ? (w0w & 0xffff0000u) : (w0w << 16));
          float w1 = __uint_as_float((rg & 1) ? (w1w & 0xffff0000u) : (w1w << 16));
          s0[m][rg] = fmaf(v, w0, s0[m][rg]);
          s1[m][rg] = fmaf(v, w1, s1[m][rg]);
        }
      }
    }
    #pragma unroll
    for (int m = 0; m < 2; ++m)
      #pragma unroll
      for (int rg = 0; rg < 4; ++rg) {
        #pragma unroll
        for (int off = 1; off <= 8; off <<= 1) {
          s0[m][rg] += __shfl_xor(s0[m][rg], off);
          s1[m][rg] += __shfl_xor(s1[m][rg], off);
        }
      }
    float n0 = 0.f, n1 = 0.f;
    #pragma unroll
    for (int m = 0; m < 2; ++m)
      #pragma unroll
      for (int rg = 0; rg < 4; ++rg) {
        n0 = fmaf(s0[m][rg], s0[m][rg], n0);
        n1 = fmaf(s1[m][rg], s1[m][rg], n1);
      }
    n0 += __shfl_xor(n0, 16); n0 += __shfl_xor(n0, 32);
    n1 += __shfl_xor(n1, 16); n1 += __shfl_xor(n1, 32);
    if (lane == 0) { red2[wv][0] = n0; red2[wv][1] = n1; }
    __syncthreads();
    {
      float t0 = red2[0][0] + red2[1][0] + red2[2][0] + red2[3][0];
      float t1 = red2[0][1] + red2[1][1] + red2[2][1] + red2[3][1];
      float nn0 = sqrtf(t0), nn1 = sqrtf(t1);
      float fa0 = (1.f - 1.f / (expf(nn0) + 1e-21f)) / (nn0 + 1e-21f);
      float fa1 = (1.f - 1.f / (expf(nn1) + 1e-21f)) / (nn1 + 1e-21f);
      if (r == 0) {
        #pragma unroll
        for (int m = 0; m < 2; ++m)
          #pragma unroll
          for (int rg = 0; rg < 4; ++rg) {
            float v0 = s0[m][rg] * fa0, v1 = s1[m][rg] * fa1;
            float mx = fmaxf(v0, v1);
            int l = wv * 32 + m * 16 + q * 4 + rg;
            yl[0][l] = v0 + mx;
            yl[1][l] = v1 + mx;
          }
      }
    }
    __syncthreads();

    {
      const int h = t >> 7, idx = t & 127;
      const int jj = idx >> 6, qq = idx & 63;
      float a = 0.f;
      const float* yrow = &yl[jj][h * 64];
      const float* frow = f1l + (h * 64) * 64 + qq;
      #pragma unroll 8
      for (int tt = 0; tt < 64; ++tt)
        a = fmaf(yrow[tt], frow[tt * 64], a);
      if (h == 1) pt[idx] = a;
      __syncthreads();
      float val = 0.f;
      if (h == 0) {
        val = a + pt[idx];
        y1[((size_t)b * 2 + jj) * 64 + qq] = val;
      }
      ysum += val; ysq += val * val;
    }

    #pragma unroll
    for (int p = 0; p < 4; ++p) raw[p] = rawn[p];
  }

  // ---- y1 BN partials: wave w has uniform jj = w&1 (h==1 waves contribute 0)
  #pragma unroll
  for (int off = 32; off; off >>= 1) {
    ysum += __shfl_down(ysum, off);
    ysq  += __shfl_down(ysq, off);
  }
  __syncthreads();
  if (lane == 0) { red2[wv][0] = ysum; red2[wv][1] = ysq; }
  __syncthreads();
  if (t == 0) ppy1[blockIdx.x] = make_float2(red2[0][0] + red2[2][0],
                                             red2[0][1] + red2[2][1]);
  if (t == 1) ppy1[512 + blockIdx.x] = make_float2(red2[1][0] + red2[3][0],
                                                   red2[1][1] + red2[3][1]);
}

// ---------------- K9b: BN stats finalize — nparts partials -> scale/shift ---
__global__ void k_bnstat_fin(const float2* __restrict__ pp, const float* __restrict__ g,
                             const float* __restrict__ bb, float* __restrict__ scale,
                             float* __restrict__ shift, int perShift, int nparts) {
  const int jj = blockIdx.x;
  float s = 0.f, q = 0.f;
  for (int i = threadIdx.x; i < nparts; i += 256) {
    float2 p = pp[jj * nparts + i];
    s += p.x; q += p.y;
  }
  #pragma unroll
  for (int off = 32; off; off >>= 1) { s += __shfl_down(s, off); q += __shfl_down(q, off); }
  __shared__ float rs[4], rq[4];
  int wv = threadIdx.x >> 6, ln = threadIdx.x & 63;
  if (ln == 0) { rs[wv] = s; rq[wv] = q; }
  __syncthreads();
  if (threadIdx.x == 0) {
    float S = rs[0] + rs[1] + rs[2] + rs[3];
    float Q = rq[0] + rq[1] + rq[2] + rq[3];
    float fn = (float)(B << perShift);
    float mu = S / fn, var = Q / fn - mu * mu;
    float sc = g[jj] * rsqrtf(var + 1e-5f);
    scale[jj] = sc; shift[jj] = bb[jj] - mu * sc;
  }
}

// ---------------- K10: bn1+relu+fc2 + y2 BN partials ------------------------
__global__ void k_fc2(const float* __restrict__ y1, const float* __restrict__ sc1,
                      const float* __restrict__ sh1, const float* __restrict__ f2,
                      float* __restrict__ y2, float2* __restrict__ ppy2) {
  __shared__ float2 r2[8];
  int t = threadIdx.x;
  int b = blockIdx.x * 4 + (t >> 6);
  int jj = (t >> 5) & 1, r = t & 31;
  float sc = sc1[jj], sh = sh1[jj];
  const float* yb = y1 + (size_t)b * 128 + jj * 64;
  float acc = 0.f;
  for (int q = 0; q < 64; ++q) {
    float v = fmaxf(fmaf(yb[q], sc, sh), 0.f);
    acc = fmaf(v, f2[q * 32 + r], acc);
  }
  y2[(size_t)b * 64 + jj * 32 + r] = acc;
  // y2 BN partials: 32-lane subgroups have uniform jj
  float s = acc, q2 = acc * acc;
  #pragma unroll
  for (int off = 16; off; off >>= 1) { s += __shfl_down(s, off); q2 += __shfl_down(q2, off); }
  if ((t & 31) == 0) r2[t >> 5] = make_float2(s, q2);
  __syncthreads();
  if (t == 0) ppy2[blockIdx.x] =
      make_float2(r2[0].x + r2[2].x + r2[4].x + r2[6].x,
                  r2[0].y + r2[2].y + r2[4].y + r2[6].y);
  if (t == 1) ppy2[1024 + blockIdx.x] =
      make_float2(r2[1].x + r2[3].x + r2[5].x + r2[7].x,
                  r2[1].y + r2[3].y + r2[5].y + r2[7].y);
}

// ---------------- K12: bn2+relu+fc3+sigmoid+max -----------------------------
__global__ void k_head(const float* __restrict__ y2, const float* __restrict__ sc2,
                       const float* __restrict__ sh2, const float* __restrict__ f3,
                       float* __restrict__ out) {
  int b = blockIdx.x * 256 + threadIdx.x;
  if (b >= B) return;
  const float* yb = y2 + (size_t)b * 64;
  float c0 = sc2[0], d0 = sh2[0], c1v = sc2[1], d1 = sh2[1];
  float a0 = 0.f, a1 = 0.f;
  for (int r = 0; r < 32; ++r) {
    float w = f3[r];
    a0 = fmaf(fmaxf(fmaf(yb[r], c0, d0), 0.f), w, a0);
    a1 = fmaf(fmaxf(fmaf(yb[32 + r], c1v, d1), 0.f), w, a1);
  }
  float s0 = 1.f / (1.f + expf(-a0));
  float s1 = 1.f / (1.f + expf(-a1));
  out[b] = fmaxf(s0, s1);
}

// ---------------- workspace layout ------------------------------------------
constexpr size_t SZ_H2    = (size_t)B * SQ * 128 * 2;   // 42,991,616 (bf16)
constexpr size_t SZ_C1    = (size_t)B * 64 * 128 * 2;   // 67,108,864 (bf16)
constexpr size_t OFF_H2   = 0;
constexpr size_t OFF_W5T  = 0;                 // w5t 6.7 MB; dead before k_h2 writes h2
constexpr size_t OFF_H3   = SZ_H2;
constexpr size_t R1       = 2 * SZ_H2;         // 85,983,232
constexpr size_t OFF_G    = R1;                                 // 314,880
constexpr size_t OFF_T1   = OFF_G + 314880;                     // t1b bf16 1,343,488
constexpr size_t OFF_T2   = OFF_T1 + 2624000;                   // 6,560,000 (bf16)
constexpr size_t OFF_CMB  = OFF_T2 + 6560000;                   //   671,744
constexpr size_t OFF_W7T  = OFF_CMB + 671744;  // 9,404,416 bf16; dead by K5
constexpr size_t OFF_C1   = R1;                // overlaps tables+w7t (dead by K5)
constexpr size_t R2       = R1 + SZ_C1;        // 153,092,096
constexpr size_t OFF_PART = R2;                // 2 MB (conv1 BN; later ppy1/ppy2)
constexpr size_t OFF_Y1   = OFF_PART + 2097152;                 // 2,097,152
constexpr size_t OFF_Y2   = OFF_Y1 + 2097152;                   // 1,048,576
constexpr size_t OFF_SM   = OFF_Y2 + 1048576;                   //     1,024
constexpr size_t OFF_WPK  = OFF_SM + 1024;                      //    24,576
constexpr size_t OFF_CPK  = OFF_WPK + 24576;                    //    12,288
constexpr size_t OFF_RWP  = OFF_CPK + 12288;                    //    32,768

extern "C" void kernel_launch(void* const* d_in, const int* in_sizes, int n_in,
                              void* d_out, int out_size, void* d_ws, size_t ws_size,
                              hipStream_t stream) {
  const int*   x   = (const int*)d_in[0];
  const float* emb = (const float*)d_in[1];
  const float* W3  = (const float*)d_in[2];
  const float* b3  = (const float*)d_in[3];
  const float* W5  = (const float*)d_in[4];
  const float* b5  = (const float*)d_in[5];
  const float* W7  = (const float*)d_in[6];
  const float* b7  = (const float*)d_in[7];
  const float* c1w = (const float*)d_in[8];
  const float* c1b = (const float*)d_in[9];
  const float* bng = (const float*)d_in[10];
  const float* bnb = (const float*)d_in[11];
  const float* cpw = (const float*)d_in[12];
  const float* cpb = (const float*)d_in[13];
  const float* rW  = (const float*)d_in[14];
  const float* rb  = (const float*)d_in[15];
  const float* f1  = (const float*)d_in[16];
  const float* g1  = (const float*)d_in[17];
  const float* bb1 = (const float*)d_in[18];
  const float* f2  = (const float*)d_in[19];
  const float* g2  = (const float*)d_in[20];
  const float* bb2 = (const float*)d_in[21];
  const float* f3  = (const float*)d_in[22];

  char* wsb = (char*)d_ws;
  u16*    h2p   = (u16*)(wsb + OFF_H2);
  u16*    w5tp  = (u16*)(wsb + OFF_W5T);
  u16*    h3p   = (u16*)(wsb + OFF_H3);
  float*  Gp    = (float*)(wsb + OFF_G);
  u16*    t1p   = (u16*)(wsb + OFF_T1);
  u16*    t2p   = (u16*)(wsb + OFF_T2);
  int*    cmbp  = (int*)(wsb + OFF_CMB);
  u16*    w7tp  = (u16*)(wsb + OFF_W7T);
  u16*    c1p   = (u16*)(wsb + OFF_C1);
  float2* partp = (float2*)(wsb + OFF_PART);
  float2* ppy1  = partp;               // 2*512 float2 (PART free after bnfin)
  float2* ppy2  = partp + 2048;        // 2*1024 float2
  float*  y1p   = (float*)(wsb + OFF_Y1);
  float*  y2p   = (float*)(wsb + OFF_Y2);
  float*  scp   = (float*)(wsb + OFF_SM);
  float*  shp   = scp + 64;
  float*  sc1p  = shp + 64;
  float*  sh1p  = sc1p + 2;
  float*  sc2p  = sh1p + 2;
  float*  sh2p  = sc2p + 2;
  u16*    wpkp  = (u16*)(wsb + OFF_WPK);
  u16*    cpkp  = (u16*)(wsb + OFF_CPK);
  u16*    rwpp  = (u16*)(wsb + OFF_RWP);

  k_pack<<<136, 256, 0, stream>>>(c1w, cpw, rW, rb, wpkp, cpkp, rwpp);
  k_combo<<<(B * SQ + 255) / 256, 256, 0, stream>>>(x, cmbp);
  k_w5t<<<dim3(2, 2, SQ * 5), 256, 0, stream>>>(W5, w5tp);
  k_w7t<<<dim3(14, 2, SQ), 256, 0, stream>>>(W7, w7tp);
  k_gmat<<<SQ * 3, 128, 0, stream>>>(emb, W3, Gp);
  k_t1<<<SQ * 128 * 128 / 256, 256, 0, stream>>>(Gp, b3, t1p);
  k_t2_mfma<<<SQ * 5, 256, 0, stream>>>(t1p, w5tp, t2p);
  k_h2<<<(B * SQ * 16) / 256, 256, 0, stream>>>(t2p, cmbp, b5, h2p);
  k_gemm7_mfma<<<dim3(32, SQ), 256, 0, stream>>>(h2p, w7tp, b7, h3p);
  k_conv1<<<B / NBC, 256, 0, stream>>>(h3p, wpkp, c1b, c1p, partp);
  k_bnfin<<<64, 256, 0, stream>>>(partp, bng, bnb, scp, shp);
  k_caps<<<B / NB, 256, 0, stream>>>(c1p, scp, shp, cpkp, cpb, rwpp, f1, y1p, ppy1);
  k_bnstat_fin<<<2, 256, 0, stream>>>(ppy1, g1, bb1, sc1p, sh1p, 6, 512);
  k_fc2<<<B / 4, 256, 0, stream>>>(y1p, sc1p, sh1p, f2, y2p, ppy2);
  k_bnstat_fin<<<2, 256, 0, stream>>>(ppy2, g2, bb2, sc2p, sh2p, 5, 1024);
  k_head<<<B / 256, 256, 0, stream>>>(y2p, sc2p, sh2p, f3, (float*)d_out);
}

// Round 14
// 201.369 us; speedup vs baseline: 1.2912x; 1.0744x over previous
//
#include <hip/hip_runtime.h>
#include <cstdint>

typedef unsigned short u16;
typedef unsigned int   u32;
typedef __attribute__((ext_vector_type(8))) short bf16x8;
typedef __attribute__((ext_vector_type(4))) float f32x4;

#define DEVFN static __device__ __forceinline__

constexpr int B  = 4096;
constexpr int SQ = 41;

DEVFN float bf2f(u16 v) { return __uint_as_float(((u32)v) << 16); }
DEVFN u16 f2bf(float f) {
  u32 u = __float_as_uint(f);
  u += 0x7fffu + ((u >> 16) & 1u);
  return (u16)(u >> 16);
}
DEVFN u32 pack2(float a, float b) { return (u32)f2bf(a) | ((u32)f2bf(b) << 16); }

DEVFN void gload16(const void* g, void* l) {
  __builtin_amdgcn_global_load_lds(
      (const __attribute__((address_space(1))) unsigned int*)g,
      (__attribute__((address_space(3))) unsigned int*)l, 16, 0, 0);
}

// ---------------- K-PREP: pack + combo + w5t + w7t + gmat (block ranges) ----
// [0,136) pack | [136,793) combo | [793,1613) w5t | [1613,2761) w7t | [2761,2884) gmat
__global__ __launch_bounds__(256) void k_prep(
    const float* __restrict__ cw, const float* __restrict__ cpw,
    const float* __restrict__ rW, const float* __restrict__ rb,
    u16* __restrict__ wpk, u16* __restrict__ cpk, u16* __restrict__ rwp,
    const int* __restrict__ x, int* __restrict__ combo,
    const float* __restrict__ W5, u16* __restrict__ w5t,
    const float* __restrict__ W7, u16* __restrict__ w7t,
    const float* __restrict__ emb, const float* __restrict__ W3,
    float* __restrict__ G) {
  __shared__ float tile[64][65];
  const int blk = blockIdx.x;
  const int t = threadIdx.x;

  if (blk < 136) {                     // ---- pack ----
    int i = blk * 256 + t;
    if (i < 12288) {
      int tt = i >> 12, rem = i & 4095, o = rem >> 6, c = rem & 63;
      float v = (c < 41) ? cw[(o * 41 + c) * 3 + tt] : 0.f;
      wpk[(tt * 64 + o) * 64 + (c ^ ((o & 7) << 3))] = f2bf(v);
    } else if (i < 18432) {
      int k = i - 12288;
      int tt = k >> 11, rem = k & 2047, o = rem >> 5, c = rem & 31;
      cpk[(tt * 64 + o) * 32 + (c ^ ((o & 3) << 3))] = f2bf(cpw[(o * 32 + c) * 3 + tt]);
    } else if (i < 34816) {
      int k = i - 18432;
      rwp[k] = f2bf(rW[k] * (1.f + rb[k >> 7]));
    }
  } else if (blk < 793) {              // ---- combo ----
    int i = (blk - 136) * 256 + t;
    if (i < B * SQ) {
      int b = i / SQ, s = i - b * SQ;
      const int* xb = x + b * SQ;
      int d0 = (s > 0) ? xb[s - 1] : 4;
      int d1 = xb[s];
      int d2 = (s < SQ - 1) ? xb[s + 1] : 4;
      combo[i] = d0 * 25 + d1 * 5 + d2;
    }
  } else if (blk < 1613) {             // ---- w5t: W5 -> [sw][o][f] bf16 ----
    int flat = blk - 793;
    int sw = flat >> 2, r4 = flat & 3;
    int f0 = (r4 & 1) * 64, o0 = (r4 >> 1) * 64;
    int s = sw / 5, w = sw % 5;
    const float* Ws = W5 + ((size_t)s * 640 + w * 128) * 128;
    #pragma unroll
    for (int i = 0; i < 16; ++i) {
      int idx = t + i * 256;
      int fl = idx >> 6, ol = idx & 63;
      tile[fl][ol] = Ws[(size_t)(f0 + fl) * 128 + o0 + ol];
    }
    __syncthreads();
    #pragma unroll
    for (int i = 0; i < 16; ++i) {
      int idx = t + i * 256;
      int ol = idx >> 6, fl = idx & 63;
      w5t[((size_t)sw * 128 + o0 + ol) * 128 + f0 + fl] = f2bf(tile[fl][ol]);
    }
  } else if (blk < 2761) {             // ---- w7t: W7 -> [s][o][k] bf16 ----
    int flat = blk - 1613;
    int s = flat / 28, r28 = flat % 28;
    int k0 = (r28 >> 1) * 64, o0 = (r28 & 1) * 64;
    #pragma unroll
    for (int i = 0; i < 16; ++i) {
      int idx = t + i * 256;
      int kl = idx >> 6, ol = idx & 63;
      tile[kl][ol] = W7[((size_t)s * 896 + k0 + kl) * 128 + o0 + ol];
    }
    __syncthreads();
    #pragma unroll
    for (int i = 0; i < 16; ++i) {
      int idx = t + i * 256;
      int ol = idx >> 6, kl = idx & 63;
      w7t[((size_t)s * 128 + o0 + ol) * 896 + k0 + kl] = f2bf(tile[kl][ol]);
    }
  } else {                             // ---- gmat (128 active threads) ----
    int blk2 = blk - 2761;
    int s = blk2 / 3, ww = blk2 % 3;
    if (t < 128) {
      const int o = t;
      const float* Ws = W3 + ((size_t)s * 384 + ww * 128) * 128;
      float a0 = 0.f, a1 = 0.f, a2 = 0.f, a3 = 0.f;
      for (int f = 0; f < 128; ++f) {
        float wg = Ws[(size_t)f * 128 + o];
        a0 = fmaf(emb[f], wg, a0);
        a1 = fmaf(emb[128 + f], wg, a1);
        a2 = fmaf(emb[256 + f], wg, a2);
        a3 = fmaf(emb[384 + f], wg, a3);
      }
      float* Gp = G + ((size_t)(s * 3 + ww) * 5) * 128 + o;
      Gp[0] = a0; Gp[128] = a1; Gp[256] = a2; Gp[384] = a3; Gp[512] = 0.f;
    }
  }
}

// ---------------- K2: t2[sw][v<125][o] via MFMA; A (=t1[tw]) built in LDS ---
// t1[tw][v][f] = relu(b3+G0+G1+G2) computed in-kernel (G is L2-resident),
// written swizzled to LDS (both-sides rule: we control write AND read).
__global__ __launch_bounds__(256) void k_t2_mfma(const float* __restrict__ G,
                                                 const float* __restrict__ b3,
                                                 const u16* __restrict__ w5t,
                                                 u16* __restrict__ t2) {
  __shared__ u16 As[2][8192];   // [k-half][row v][64 u16, granule^swz]
  __shared__ u16 Bs[2][8192];
  const int sw = blockIdx.x;                 // s*5 + w
  const int s = sw / 5, w5 = sw % 5;
  const int tw = s + w5 - 2;
  if (tw < 0 || tw >= SQ) return;            // window out of range: never read
  const int t = threadIdx.x;
  const int lane = t & 63, w = t >> 6;
  const int wr = w >> 1, wc = w & 1;
  const int lcol = lane & 15, qk = lane >> 4;

  // ---- stage B (w5t) via gload16 ----
  const u16* bbase = w5t + (size_t)sw * 128 * 128;
  #pragma unroll
  for (int h = 0; h < 2; ++h) {
    #pragma unroll
    for (int it = 0; it < 4; ++it) {
      const int L = it * 4096 + t * 16;
      const int r = L >> 7, g = (L >> 4) & 7;
      const int gs = g ^ (r & 7);
      gload16(bbase + (size_t)r * 128 + h * 64 + gs * 8,
              (char*)Bs[h] + it * 4096 + w * 1024);
    }
  }
  // ---- build A = t1[tw] in LDS (swizzled ds_write_b128) ----
  #pragma unroll
  for (int p = 0; p < 8; ++p) {
    int idx = t + p * 256;                   // 2048 total: v(128) x hg(16)
    int v = idx >> 4, hg = idx & 15;
    int h = hg >> 3, gl = hg & 7;
    int f0 = h * 64 + gl * 8;
    uint4 pk = make_uint4(0u, 0u, 0u, 0u);
    if (v < 125) {
      int d0 = v / 25, rr = v % 25, d1 = rr / 5, d2 = rr % 5;
      const float* g0 = G + ((size_t)(tw * 3 + 0) * 5 + d0) * 128 + f0;
      const float* g1 = G + ((size_t)(tw * 3 + 1) * 5 + d1) * 128 + f0;
      const float* g2 = G + ((size_t)(tw * 3 + 2) * 5 + d2) * 128 + f0;
      const float* bb = b3 + tw * 128 + f0;
      float vals[8];
      #pragma unroll
      for (int e = 0; e < 8; ++e)
        vals[e] = fmaxf(bb[e] + g0[e] + g1[e] + g2[e], 0.f);
      pk.x = pack2(vals[0], vals[1]); pk.y = pack2(vals[2], vals[3]);
      pk.z = pack2(vals[4], vals[5]); pk.w = pack2(vals[6], vals[7]);
    }
    *reinterpret_cast<uint4*>(&As[h][v * 64 + ((gl ^ (v & 7)) << 3)]) = pk;
  }
  __syncthreads();   // drains vmcnt (B) + lgkmcnt (A writes)

  f32x4 acc[4][4];
  #pragma unroll
  for (int i = 0; i < 4; ++i)
    #pragma unroll
    for (int j = 0; j < 4; ++j) acc[i][j] = (f32x4){0.f, 0.f, 0.f, 0.f};

  #pragma unroll
  for (int h = 0; h < 2; ++h) {
    #pragma unroll
    for (int kk = 0; kk < 2; ++kk) {
      const int gk = kk * 4 + qk;
      bf16x8 av[4], bv[4];
      #pragma unroll
      for (int m = 0; m < 4; ++m) {
        const int zr = wr * 64 + m * 16 + lcol;
        av[m] = *reinterpret_cast<const bf16x8*>(&As[h][zr * 64 + ((gk ^ (zr & 7)) << 3)]);
      }
      #pragma unroll
      for (int n = 0; n < 4; ++n) {
        const int br = wc * 64 + n * 16 + lcol;
        bv[n] = *reinterpret_cast<const bf16x8*>(&Bs[h][br * 64 + ((gk ^ (br & 7)) << 3)]);
      }
      #pragma unroll
      for (int m = 0; m < 4; ++m)
        #pragma unroll
        for (int n = 0; n < 4; ++n)
          acc[m][n] = __builtin_amdgcn_mfma_f32_16x16x32_bf16(av[m], bv[n], acc[m][n], 0, 0, 0);
    }
  }

  u16* dst = t2 + (size_t)sw * 125 * 128;
  const int rq = (lane >> 4) * 4;
  #pragma unroll
  for (int n = 0; n < 4; ++n) {
    const int o = wc * 64 + n * 16 + lcol;
    #pragma unroll
    for (int m = 0; m < 4; ++m) {
      #pragma unroll
      for (int rg = 0; rg < 4; ++rg) {
        const int row = wr * 64 + m * 16 + rq + rg;
        if (row < 125) dst[(size_t)row * 128 + o] = f2bf(acc[m][n][rg]);
      }
    }
  }
}

// ---------------- K3: h2[b][s][o] = relu(b5 + sum_w t2[s][w][combo]) --------
__global__ __launch_bounds__(256) void k_h2(const u16* __restrict__ t2,
                                            const int* __restrict__ combo,
                                            const float* __restrict__ b5,
                                            u16* __restrict__ h2) {
  const int i = blockIdx.x * 256 + threadIdx.x;   // B*41*16 total
  const int o8 = (i & 15) * 8;
  const int rid = i >> 4;                          // s-major: s = rid>>12
  const int s = rid >> 12, b = rid & 4095;
  float acc[8];
  {
    float4 b0 = *reinterpret_cast<const float4*>(b5 + s * 128 + o8);
    float4 b1 = *reinterpret_cast<const float4*>(b5 + s * 128 + o8 + 4);
    acc[0] = b0.x; acc[1] = b0.y; acc[2] = b0.z; acc[3] = b0.w;
    acc[4] = b1.x; acc[5] = b1.y; acc[6] = b1.z; acc[7] = b1.w;
  }
  const int* cb = combo + b * SQ;
  #pragma unroll
  for (int ww = 0; ww < 5; ++ww) {
    const int t = s + ww - 2;
    if (0 <= t && t < SQ) {
      const int c = cb[t];
      uint4 raw = *reinterpret_cast<const uint4*>(
          t2 + ((size_t)(s * 5 + ww) * 125 + c) * 128 + o8);
      acc[0] += __uint_as_float(raw.x << 16);
      acc[1] += __uint_as_float(raw.x & 0xffff0000u);
      acc[2] += __uint_as_float(raw.y << 16);
      acc[3] += __uint_as_float(raw.y & 0xffff0000u);
      acc[4] += __uint_as_float(raw.z << 16);
      acc[5] += __uint_as_float(raw.z & 0xffff0000u);
      acc[6] += __uint_as_float(raw.w << 16);
      acc[7] += __uint_as_float(raw.w & 0xffff0000u);
    }
  }
  uint4 pk;
  pk.x = pack2(fmaxf(acc[0], 0.f), fmaxf(acc[1], 0.f));
  pk.y = pack2(fmaxf(acc[2], 0.f), fmaxf(acc[3], 0.f));
  pk.z = pack2(fmaxf(acc[4], 0.f), fmaxf(acc[5], 0.f));
  pk.w = pack2(fmaxf(acc[6], 0.f), fmaxf(acc[7], 0.f));
  *reinterpret_cast<uint4*>(h2 + ((size_t)b * SQ + s) * 128 + o8) = pk;
}

// ---------------- K4b: layer-3 GEMM, BK=64 dbuf + counted vmcnt pipeline ----
__global__ __launch_bounds__(256) void k_gemm7_mfma(const u16* __restrict__ h2,
                                                    const u16* __restrict__ w7t,
                                                    const float* __restrict__ b7,
                                                    u16* __restrict__ h3) {
  __shared__ u16 As[2][8192];   // [buf][row][k-granule^swz] 2x16 KB
  __shared__ u16 Bs[2][8192];   // [buf][o][k-granule^swz]   2x16 KB
  const int s  = blockIdx.y;
  const int b0 = blockIdx.x * 128;
  const int t  = threadIdx.x;
  const int lane = t & 63, w = t >> 6;
  const int wr = w >> 1, wc = w & 1;            // wave -> 64x64 quadrant
  const int lcol = lane & 15, qk = lane >> 4;   // qk: k-granule quarter 0..3

  f32x4 acc[4][4];
  #pragma unroll
  for (int i = 0; i < 4; ++i)
    #pragma unroll
    for (int j = 0; j < 4; ++j) acc[i][j] = (f32x4){0.f, 0.f, 0.f, 0.f};

  const u16* wbase = w7t + (size_t)s * 128 * 896;

  auto stage = [&](int kt, int bi) -> int {
    const int k0 = kt * 64;
    const int ww = k0 >> 7, tr = s + ww - 3, kf0 = k0 & 127;
    int issued = 0;
    if (0 <= tr && tr < SQ) {
      #pragma unroll
      for (int it = 0; it < 4; ++it) {
        const int L = it * 4096 + t * 16;       // dest byte offset
        const int r = L >> 7;                   // tile row 0..127
        const int g = (L >> 4) & 7;             // dest 16B granule in row
        const int gs = g ^ (r & 7);             // pre-swizzled source granule
        gload16(h2 + ((size_t)(b0 + r) * SQ + tr) * 128 + kf0 + gs * 8,
                (char*)As[bi] + it * 4096 + w * 1024);
      }
      issued += 4;
    } else {
      #pragma unroll
      for (int it = 0; it < 4; ++it)
        *reinterpret_cast<uint4*>((char*)As[bi] + it * 4096 + t * 16) =
            make_uint4(0u, 0u, 0u, 0u);
    }
    #pragma unroll
    for (int it = 0; it < 4; ++it) {
      const int L = it * 4096 + t * 16;
      const int o = L >> 7;
      const int g = (L >> 4) & 7;
      const int gs = g ^ (o & 7);
      gload16(wbase + (size_t)o * 896 + k0 + gs * 8,
              (char*)Bs[bi] + it * 4096 + w * 1024);
    }
    return issued + 4;
  };

  stage(0, 0);   // prologue

  for (int kt = 0; kt < 14; ++kt) {
    const int cur = kt & 1;
    int ni = 0;
    if (kt < 13) ni = stage(kt + 1, cur ^ 1);
    if (ni == 8)      asm volatile("s_waitcnt vmcnt(8) lgkmcnt(0)" ::: "memory");
    else if (ni == 4) asm volatile("s_waitcnt vmcnt(4) lgkmcnt(0)" ::: "memory");
    else              asm volatile("s_waitcnt vmcnt(0) lgkmcnt(0)" ::: "memory");
    __builtin_amdgcn_sched_barrier(0);
    __builtin_amdgcn_s_barrier();          // buf[cur] ready for all waves
    __builtin_amdgcn_sched_barrier(0);

    const u16* Ac = As[cur];
    const u16* Bc = Bs[cur];
    #pragma unroll
    for (int kk = 0; kk < 2; ++kk) {
      const int gk = kk * 4 + qk;          // logical k-granule 0..7
      bf16x8 av[4], bv[4];
      #pragma unroll
      for (int m = 0; m < 4; ++m) {
        const int zr = wr * 64 + m * 16 + lcol;
        av[m] = *reinterpret_cast<const bf16x8*>(Ac + zr * 64 + ((gk ^ (zr & 7)) << 3));
      }
      #pragma unroll
      for (int n = 0; n < 4; ++n) {
        const int br = wc * 64 + n * 16 + lcol;
        bv[n] = *reinterpret_cast<const bf16x8*>(Bc + br * 64 + ((gk ^ (br & 7)) << 3));
      }
      #pragma unroll
      for (int m = 0; m < 4; ++m)
        #pragma unroll
        for (int n = 0; n < 4; ++n)
          acc[m][n] = __builtin_amdgcn_mfma_f32_16x16x32_bf16(av[m], bv[n], acc[m][n], 0, 0, 0);
    }
    __builtin_amdgcn_sched_barrier(0);
    __builtin_amdgcn_s_barrier();          // all reads of buf[cur] done
  }

  const int rq = (lane >> 4) * 4;
  #pragma unroll
  for (int n = 0; n < 4; ++n) {
    const int o = wc * 64 + n * 16 + lcol;
    const float bias = b7[s * 128 + o];
    #pragma unroll
    for (int m = 0; m < 4; ++m) {
      #pragma unroll
      for (int rg = 0; rg < 4; ++rg) {
        const int row = b0 + wr * 64 + m * 16 + rq + rg;
        h3[((size_t)row * SQ + s) * 128 + o] = f2bf(fmaxf(acc[m][n][rg] + bias, 0.f));
      }
    }
  }
}

// ---------------- K5: conv1 via MFMA, NB=8 batched + zs double buffer -------
constexpr int NBC = 8;
__global__ __launch_bounds__(256) void k_conv1(const u16* __restrict__ h3,
                                               const u16* __restrict__ wpk,
                                               const float* __restrict__ cb,
                                               u16* __restrict__ c1T,
                                               float2* __restrict__ part) {
  __shared__ u16 zs[2][6144];        // h3[b] staging dbuf (2x12 KB)
  __shared__ u16 zt[130 * 64];       // transposed [l+1][c^swz]
  __shared__ u16 wl[3 * 64 * 64];    // weights [t][o][c^swz]
  __shared__ float2 red[4][64];
  const int b0 = blockIdx.x * NBC;
  const int t = threadIdx.x;
  const int lane = t & 63, wv = t >> 6;
  const int r = lane & 15, kq = (lane >> 4) * 8, q = lane >> 4;

  #pragma unroll
  for (int it = 0; it < 6; ++it)
    gload16(wpk + ((size_t)it * 256 + t) * 8, (char*)wl + it * 4096 + wv * 1024);
  #pragma unroll
  for (int it = 0; it < 3; ++it)
    gload16(h3 + (size_t)b0 * (SQ * 128) + ((size_t)it * 256 + t) * 8,
            (char*)zs[0] + it * 4096 + wv * 1024);
  if (t < 64) zt[t] = 0;
  else if (t < 128) zt[129 * 64 + t - 64] = 0;
  __syncthreads();   // wl + zs[0] ready (drains vmcnt)

  for (int i = 0; i < NBC; ++i) {
    const int b = b0 + i;
    const int cur = i & 1;

    {
      const int l = t & 127, jb = (t >> 7) * 32;
      const int sw = ((l + 1) & 7) << 3;
      u16* dst = zt + (l + 1) * 64;
      const u16* srcz = zs[cur];
      #pragma unroll
      for (int j = 0; j < 32; ++j) {
        int c = (jb + j + l) & 63;
        dst[c ^ sw] = (c < 41) ? srcz[c * 128 + l] : (u16)0;
      }
    }
    if (i + 1 < NBC) {
      #pragma unroll
      for (int it = 0; it < 3; ++it)
        gload16(h3 + (size_t)(b + 1) * (SQ * 128) + ((size_t)it * 256 + t) * 8,
                (char*)zs[cur ^ 1] + it * 4096 + wv * 1024);
    }
    asm volatile("s_waitcnt lgkmcnt(0)" ::: "memory");
    __builtin_amdgcn_sched_barrier(0);
    __builtin_amdgcn_s_barrier();
    __builtin_amdgcn_sched_barrier(0);

    f32x4 acc[2][4];
    #pragma unroll
    for (int m = 0; m < 2; ++m)
      #pragma unroll
      for (int n = 0; n < 4; ++n) acc[m][n] = (f32x4){0.f, 0.f, 0.f, 0.f};
    #pragma unroll
    for (int tt = 0; tt < 3; ++tt) {
      #pragma unroll
      for (int kk = 0; kk < 2; ++kk) {
        const int kof = kk * 32 + kq;
        bf16x8 av[2], bv[4];
        #pragma unroll
        for (int m = 0; m < 2; ++m) {
          const int zr = wv * 32 + m * 16 + r + tt;
          av[m] = *reinterpret_cast<const bf16x8*>(zt + zr * 64 + (kof ^ ((zr & 7) << 3)));
        }
        #pragma unroll
        for (int n = 0; n < 4; ++n) {
          const int o = n * 16 + r;
          bv[n] = *reinterpret_cast<const bf16x8*>(wl + (tt * 64 + o) * 64 + (kof ^ ((o & 7) << 3)));
        }
        #pragma unroll
        for (int m = 0; m < 2; ++m)
          #pragma unroll
          for (int n = 0; n < 4; ++n)
            acc[m][n] = __builtin_amdgcn_mfma_f32_16x16x32_bf16(av[m], bv[n], acc[m][n], 0, 0, 0);
      }
    }

    u16* outb = c1T + (size_t)b * 8192;
    #pragma unroll
    for (int n = 0; n < 4; ++n) {
      const int o = n * 16 + r;
      const float bias = cb[o];
      float s1 = 0.f, s2 = 0.f;
      #pragma unroll
      for (int m = 0; m < 2; ++m) {
        #pragma unroll
        for (int rg = 0; rg < 4; ++rg) {
          float v = acc[m][n][rg] + bias;
          s1 += v; s2 += v * v;
          outb[(wv * 32 + m * 16 + q * 4 + rg) * 64 + o] = f2bf(v);
        }
      }
      s1 += __shfl_xor(s1, 16); s1 += __shfl_xor(s1, 32);
      s2 += __shfl_xor(s2, 16); s2 += __shfl_xor(s2, 32);
      if (lane < 16) red[wv][n * 16 + lane] = make_float2(s1, s2);
    }
    __syncthreads();   // red ready; also drains prefetch vmcnt for next iter
    if (t < 64) {
      float S = red[0][t].x + red[1][t].x + red[2][t].x + red[3][t].x;
      float Q = red[0][t].y + red[1][t].y + red[2][t].y + red[3][t].y;
      part[(size_t)t * B + b] = make_float2(S, Q);
    }
    __syncthreads();   // red/zt reusable next iteration
  }
}

// ---------------- K6: finalize conv1 BN -> scale/shift per channel ----------
__global__ void k_bnfin(const float2* __restrict__ part, const float* __restrict__ g,
                        const float* __restrict__ bb, float* __restrict__ scale,
                        float* __restrict__ shift) {
  int o = blockIdx.x;
  float s = 0.f, q = 0.f;
  for (int i = threadIdx.x; i < B; i += 256) {
    float2 p = part[(size_t)o * B + i];
    s += p.x; q += p.y;
  }
  #pragma unroll
  for (int off = 32; off; off >>= 1) { s += __shfl_down(s, off); q += __shfl_down(q, off); }
  __shared__ float rs[4], rq[4];
  int wv = threadIdx.x >> 6, ln = threadIdx.x & 63;
  if (ln == 0) { rs[wv] = s; rq[wv] = q; }
  __syncthreads();
  if (threadIdx.x == 0) {
    float S = rs[0] + rs[1] + rs[2] + rs[3];
    float Q = rq[0] + rq[1] + rq[2] + rq[3];
    const float n = (float)B * 128.f;
    float mu = S / n, var = Q / n - mu * mu;
    float sc = g[o] * rsqrtf(var + 1e-5f);
    scale[o] = sc; shift[o] = bb[o] - mu * sc;
  }
}

// ---------------- K7: caps conv + squash + routing + fc1 + y1 BN partials ---
constexpr int NB = 8;
__global__ __launch_bounds__(256) void k_caps(const u16* __restrict__ c1T,
                                              const float* __restrict__ scale,
                                              const float* __restrict__ shift,
                                              const u16* __restrict__ cpk,
                                              const float* __restrict__ cpb,
                                              const u16* __restrict__ rwp,
                                              const float* __restrict__ f1,
                                              float* __restrict__ y1,
                                              float2* __restrict__ ppy1) {
  __shared__ u16 zt[130 * 64];
  __shared__ u16 wl[3 * 64 * 32];
  __shared__ float f1l[128 * 64];
  __shared__ float red[4][64];
  __shared__ float fl[64];
  __shared__ float sc_s[64], sh_s[64];
  __shared__ float red2[4][2];
  __shared__ float yl[2][128];
  __shared__ float pt[128];
  const int b0 = blockIdx.x * NB;
  const int t = threadIdx.x;
  const int lane = t & 63, wv = t >> 6;
  const int r = lane & 15, kq = (lane >> 4) * 8, q = lane >> 4;
  float ysum = 0.f, ysq = 0.f;     // y1-stat accumulators (h==1 threads add 0)

  #pragma unroll
  for (int it = 0; it < 3; ++it)
    gload16(cpk + ((size_t)it * 256 + t) * 8, (char*)wl + it * 4096 + wv * 1024);
  #pragma unroll
  for (int it = 0; it < 8; ++it)
    gload16(f1 + ((size_t)it * 256 + t) * 4, (char*)f1l + it * 4096 + wv * 1024);
  if (t < 64) { sc_s[t] = scale[t]; sh_s[t] = shift[t]; }
  if (t < 64) zt[t] = 0;
  else if (t < 128) zt[129 * 64 + t - 64] = 0;

  uint4 raw[4], rawn[4];
  {
    const u16* src = c1T + (size_t)b0 * 8192;
    #pragma unroll
    for (int p = 0; p < 4; ++p)
      raw[p] = *reinterpret_cast<const uint4*>(src + ((size_t)t + p * 256) * 8);
  }

  for (int i = 0; i < NB; ++i) {
    const int b = b0 + i;
    __syncthreads();

    #pragma unroll
    for (int p = 0; p < 4; ++p) {
      int idx = t + p * 256;
      int l = idx >> 3, c0 = (idx & 7) * 8;
      float vv[8];
      vv[0] = __uint_as_float(raw[p].x << 16); vv[1] = __uint_as_float(raw[p].x & 0xffff0000u);
      vv[2] = __uint_as_float(raw[p].y << 16); vv[3] = __uint_as_float(raw[p].y & 0xffff0000u);
      vv[4] = __uint_as_float(raw[p].z << 16); vv[5] = __uint_as_float(raw[p].z & 0xffff0000u);
      vv[6] = __uint_as_float(raw[p].w << 16); vv[7] = __uint_as_float(raw[p].w & 0xffff0000u);
      float a0 = fmaxf(fmaf(vv[0], sc_s[c0 + 0], sh_s[c0 + 0]), 0.f);
      float a1 = fmaxf(fmaf(vv[1], sc_s[c0 + 1], sh_s[c0 + 1]), 0.f);
      float a2 = fmaxf(fmaf(vv[2], sc_s[c0 + 2], sh_s[c0 + 2]), 0.f);
      float a3 = fmaxf(fmaf(vv[3], sc_s[c0 + 3], sh_s[c0 + 3]), 0.f);
      float a4 = fmaxf(fmaf(vv[4], sc_s[c0 + 4], sh_s[c0 + 4]), 0.f);
      float a5 = fmaxf(fmaf(vv[5], sc_s[c0 + 5], sh_s[c0 + 5]), 0.f);
      float a6 = fmaxf(fmaf(vv[6], sc_s[c0 + 6], sh_s[c0 + 6]), 0.f);
      float a7 = fmaxf(fmaf(vv[7], sc_s[c0 + 7], sh_s[c0 + 7]), 0.f);
      uint4 pk;
      pk.x = pack2(a0, a1); pk.y = pack2(a2, a3);
      pk.z = pack2(a4, a5); pk.w = pack2(a6, a7);
      *reinterpret_cast<uint4*>(zt + (l + 1) * 64 + (c0 ^ (((l + 1) & 7) << 3))) = pk;
    }
    if (i + 1 < NB) {
      const u16* srcn = c1T + (size_t)(b + 1) * 8192;
      #pragma unroll
      for (int p = 0; p < 4; ++p)
        rawn[p] = *reinterpret_cast<const uint4*>(srcn + ((size_t)t + p * 256) * 8);
    }
    __syncthreads();

    f32x4 acc[2][4];
    #pragma unroll
    for (int m = 0; m < 2; ++m)
      #pragma unroll
      for (int n = 0; n < 4; ++n) acc[m][n] = (f32x4){0.f, 0.f, 0.f, 0.f};
    #pragma unroll
    for (int tt = 0; tt < 3; ++tt) {
      bf16x8 av[2][2], bv[4];
      #pragma unroll
      for (int m = 0; m < 2; ++m) {
        const int zr = wv * 32 + m * 16 + r + tt;
        const int sw = (zr & 7) << 3;
        av[m][0] = *reinterpret_cast<const bf16x8*>(zt + zr * 64 + (kq ^ sw));
        av[m][1] = *reinterpret_cast<const bf16x8*>(zt + zr * 64 + ((32 + kq) ^ sw));
      }
      #pragma unroll
      for (int n = 0; n < 4; ++n) {
        const int o = n * 16 + r;
        bv[n] = *reinterpret_cast<const bf16x8*>(wl + (tt * 64 + o) * 32 + (kq ^ ((o & 3) << 3)));
      }
      #pragma unroll
      for (int m = 0; m < 2; ++m)
        #pragma unroll
        for (int n = 0; n < 4; ++n)
          acc[m][n] = __builtin_amdgcn_mfma_f32_16x16x32_bf16(av[m][n >> 1], bv[n], acc[m][n], 0, 0, 0);
    }

    #pragma unroll
    for (int n = 0; n < 4; ++n) {
      const int o = n * 16 + r;
      const float bias = cpb[o];
      float s2 = 0.f;
      #pragma unroll
      for (int m = 0; m < 2; ++m) {
        #pragma unroll
        for (int rg = 0; rg < 4; ++rg) {
          float v = acc[m][n][rg] + bias;
          acc[m][n][rg] = v;
          s2 += v * v;
        }
      }
      s2 += __shfl_xor(s2, 16); s2 += __shfl_xor(s2, 32);
      if (lane < 16) red[wv][n * 16 + lane] = s2;
    }
    __syncthreads();
    if (t < 64) {
      float S = red[0][t] + red[1][t] + red[2][t] + red[3][t];
      float nn = sqrtf(S);
      fl[t] = (1.f - 1.f / (expf(nn) + 1e-21f)) / (nn + 1e-21f);
    }
    __syncthreads();

    float s0[2][4], s1[2][4];
    #pragma unroll
    for (int m = 0; m < 2; ++m)
      #pragma unroll
      for (int rg = 0; rg < 4; ++rg) { s0[m][rg] = 0.f; s1[m][rg] = 0.f; }
    #pragma unroll
    for (int n = 0; n < 4; ++n) {
      const int o = n * 16 + r;
      const float fact = fl[o];
      #pragma unroll
      for (int m = 0; m < 2; ++m) {
        const int l0 = wv * 32 + m * 16 + q * 4;
        uint2 rw0 = *reinterpret_cast<const uint2*>(rwp + (size_t)o * 128 + l0);
        uint2 rw1 = *reinterpret_cast<const uint2*>(rwp + (size_t)(64 + o) * 128 + l0);
        #pragma unroll
        for (int rg = 0; rg < 4; ++rg) {
          float v = acc[m][n][rg] * fact;
          u32 w0w = (rg < 2) ? rw0.x : rw0.y;
          u32 w1w = (rg < 2) ? rw1.x : rw1.y;
          float w0 = __uint_as_float((rg & 1) ? (w0w & 0xffff0000u) : (w0w << 16));
          float w1 = __uint_as_float((rg & 1) ? (w1w & 0xffff0000u) : (w1w << 16));
          s0[m][rg] = fmaf(v, w0, s0[m][rg]);
          s1[m][rg] = fmaf(v, w1, s1[m][rg]);
        }
      }
    }
    #pragma unroll
    for (int m = 0; m < 2; ++m)
      #pragma unroll
      for (int rg = 0; rg < 4; ++rg) {
        #pragma unroll
        for (int off = 1; off <= 8; off <<= 1) {
          s0[m][rg] += __shfl_xor(s0[m][rg], off);
          s1[m][rg] += __shfl_xor(s1[m][rg], off);
        }
      }
    float n0 = 0.f, n1 = 0.f;
    #pragma unroll
    for (int m = 0; m < 2; ++m)
      #pragma unroll
      for (int rg = 0; rg < 4; ++rg) {
        n0 = fmaf(s0[m][rg], s0[m][rg], n0);
        n1 = fmaf(s1[m][rg], s1[m][rg], n1);
      }
    n0 += __shfl_xor(n0, 16); n0 += __shfl_xor(n0, 32);
    n1 += __shfl_xor(n1, 16); n1 += __shfl_xor(n1, 32);
    if (lane == 0) { red2[wv][0] = n0; red2[wv][1] = n1; }
    __syncthreads();
    {
      float t0 = red2[0][0] + red2[1][0] + red2[2][0] + red2[3][0];
      float t1 = red2[0][1] + red2[1][1] + red2[2][1] + red2[3][1];
      float nn0 = sqrtf(t0), nn1 = sqrtf(t1);
      float fa0 = (1.f - 1.f / (expf(nn0) + 1e-21f)) / (nn0 + 1e-21f);
      float fa1 = (1.f - 1.f / (expf(nn1) + 1e-21f)) / (nn1 + 1e-21f);
      if (r == 0) {
        #pragma unroll
        for (int m = 0; m < 2; ++m)
          #pragma unroll
          for (int rg = 0; rg < 4; ++rg) {
            float v0 = s0[m][rg] * fa0, v1 = s1[m][rg] * fa1;
            float mx = fmaxf(v0, v1);
            int l = wv * 32 + m * 16 + q * 4 + rg;
            yl[0][l] = v0 + mx;
            yl[1][l] = v1 + mx;
          }
      }
    }
    __syncthreads();

    {
      const int h = t >> 7, idx = t & 127;
      const int jj = idx >> 6, qq = idx & 63;
      float a = 0.f;
      const float* yrow = &yl[jj][h * 64];
      const float* frow = f1l + (h * 64) * 64 + qq;
      #pragma unroll 8
      for (int tt = 0; tt < 64; ++tt)
        a = fmaf(yrow[tt], frow[tt * 64], a);
      if (h == 1) pt[idx] = a;
      __syncthreads();
      float val = 0.f;
      if (h == 0) {
        val = a + pt[idx];
        y1[((size_t)b * 2 + jj) * 64 + qq] = val;
      }
      ysum += val; ysq += val * val;
    }

    #pragma unroll
    for (int p = 0; p < 4; ++p) raw[p] = rawn[p];
  }

  // ---- y1 BN partials: wave w has uniform jj = w&1 (h==1 waves contribute 0)
  #pragma unroll
  for (int off = 32; off; off >>= 1) {
    ysum += __shfl_down(ysum, off);
    ysq  += __shfl_down(ysq, off);
  }
  __syncthreads();
  if (lane == 0) { red2[wv][0] = ysum; red2[wv][1] = ysq; }
  __syncthreads();
  if (t == 0) ppy1[blockIdx.x] = make_float2(red2[0][0] + red2[2][0],
                                             red2[0][1] + red2[2][1]);
  if (t == 1) ppy1[512 + blockIdx.x] = make_float2(red2[1][0] + red2[3][0],
                                                   red2[1][1] + red2[3][1]);
}

// ---------------- K10: bn1(from ppy1)+relu+fc2 + y2 BN partials -------------
__global__ __launch_bounds__(256) void k_fc2(const float* __restrict__ y1,
                                             const float2* __restrict__ ppy1,
                                             const float* __restrict__ g1,
                                             const float* __restrict__ bb1,
                                             const float* __restrict__ f2,
                                             float* __restrict__ y2,
                                             float2* __restrict__ ppy2) {
  __shared__ float2 r2[8];
  __shared__ float scs[2], shs[2];
  __shared__ float r4[4][4];
  int t = threadIdx.x;
  // ---- reduce ppy1 (512 partials per jj) -> sc1/sh1 ----
  {
    float s0 = 0.f, q0 = 0.f, s1 = 0.f, q1 = 0.f;
    for (int i = t; i < 512; i += 256) {
      float2 p0 = ppy1[i];       s0 += p0.x; q0 += p0.y;
      float2 p1 = ppy1[512 + i]; s1 += p1.x; q1 += p1.y;
    }
    #pragma unroll
    for (int off = 32; off; off >>= 1) {
      s0 += __shfl_down(s0, off); q0 += __shfl_down(q0, off);
      s1 += __shfl_down(s1, off); q1 += __shfl_down(q1, off);
    }
    int wv = t >> 6;
    if ((t & 63) == 0) { r4[wv][0] = s0; r4[wv][1] = q0; r4[wv][2] = s1; r4[wv][3] = q1; }
    __syncthreads();
    if (t == 0) {
      float fn = (float)B * 64.f;
      float S0 = r4[0][0] + r4[1][0] + r4[2][0] + r4[3][0];
      float Q0 = r4[0][1] + r4[1][1] + r4[2][1] + r4[3][1];
      float S1 = r4[0][2] + r4[1][2] + r4[2][2] + r4[3][2];
      float Q1 = r4[0][3] + r4[1][3] + r4[2][3] + r4[3][3];
      float mu0 = S0 / fn, var0 = Q0 / fn - mu0 * mu0;
      float mu1 = S1 / fn, var1 = Q1 / fn - mu1 * mu1;
      scs[0] = g1[0] * rsqrtf(var0 + 1e-5f); shs[0] = bb1[0] - mu0 * scs[0];
      scs[1] = g1[1] * rsqrtf(var1 + 1e-5f); shs[1] = bb1[1] - mu1 * scs[1];
    }
    __syncthreads();
  }
  int b = blockIdx.x * 4 + (t >> 6);
  int jj = (t >> 5) & 1, r = t & 31;
  float sc = scs[jj], sh = shs[jj];
  const float* yb = y1 + (size_t)b * 128 + jj * 64;
  float acc = 0.f;
  for (int q = 0; q < 64; ++q) {
    float v = fmaxf(fmaf(yb[q], sc, sh), 0.f);
    acc = fmaf(v, f2[q * 32 + r], acc);
  }
  y2[(size_t)b * 64 + jj * 32 + r] = acc;
  float s = acc, q2 = acc * acc;
  #pragma unroll
  for (int off = 16; off; off >>= 1) { s += __shfl_down(s, off); q2 += __shfl_down(q2, off); }
  if ((t & 31) == 0) r2[t >> 5] = make_float2(s, q2);
  __syncthreads();
  if (t == 0) ppy2[blockIdx.x] =
      make_float2(r2[0].x + r2[2].x + r2[4].x + r2[6].x,
                  r2[0].y + r2[2].y + r2[4].y + r2[6].y);
  if (t == 1) ppy2[1024 + blockIdx.x] =
      make_float2(r2[1].x + r2[3].x + r2[5].x + r2[7].x,
                  r2[1].y + r2[3].y + r2[5].y + r2[7].y);
}

// ---------------- K12: bn2(from ppy2)+relu+fc3+sigmoid+max ------------------
__global__ __launch_bounds__(256) void k_head(const float* __restrict__ y2,
                                              const float2* __restrict__ ppy2,
                                              const float* __restrict__ g2,
                                              const float* __restrict__ bb2,
                                              const float* __restrict__ f3,
                                              float* __restrict__ out) {
  __shared__ float scs[2], shs[2];
  __shared__ float r4[4][4];
  int t = threadIdx.x;
  {
    float s0 = 0.f, q0 = 0.f, s1 = 0.f, q1 = 0.f;
    for (int i = t; i < 1024; i += 256) {
      float2 p0 = ppy2[i];        s0 += p0.x; q0 += p0.y;
      float2 p1 = ppy2[1024 + i]; s1 += p1.x; q1 += p1.y;
    }
    #pragma unroll
    for (int off = 32; off; off >>= 1) {
      s0 += __shfl_down(s0, off); q0 += __shfl_down(q0, off);
      s1 += __shfl_down(s1, off); q1 += __shfl_down(q1, off);
    }
    int wv = t >> 6;
    if ((t & 63) == 0) { r4[wv][0] = s0; r4[wv][1] = q0; r4[wv][2] = s1; r4[wv][3] = q1; }
    __syncthreads();
    if (t == 0) {
      float fn = (float)B * 32.f;
      float S0 = r4[0][0] + r4[1][0] + r4[2][0] + r4[3][0];
      float Q0 = r4[0][1] + r4[1][1] + r4[2][1] + r4[3][1];
      float S1 = r4[0][2] + r4[1][2] + r4[2][2] + r4[3][2];
      float Q1 = r4[0][3] + r4[1][3] + r4[2][3] + r4[3][3];
      float mu0 = S0 / fn, var0 = Q0 / fn - mu0 * mu0;
      float mu1 = S1 / fn, var1 = Q1 / fn - mu1 * mu1;
      scs[0] = g2[0] * rsqrtf(var0 + 1e-5f); shs[0] = bb2[0] - mu0 * scs[0];
      scs[1] = g2[1] * rsqrtf(var1 + 1e-5f); shs[1] = bb2[1] - mu1 * scs[1];
    }
    __syncthreads();
  }
  int b = blockIdx.x * 256 + t;
  if (b >= B) return;
  const float* yb = y2 + (size_t)b * 64;
  float c0 = scs[0], d0 = shs[0], c1v = scs[1], d1 = shs[1];
  float a0 = 0.f, a1 = 0.f;
  for (int r = 0; r < 32; ++r) {
    float w = f3[r];
    a0 = fmaf(fmaxf(fmaf(yb[r], c0, d0), 0.f), w, a0);
    a1 = fmaf(fmaxf(fmaf(yb[32 + r], c1v, d1), 0.f), w, a1);
  }
  float s0 = 1.f / (1.f + expf(-a0));
  float s1 = 1.f / (1.f + expf(-a1));
  out[b] = fmaxf(s0, s1);
}

// ---------------- workspace layout ------------------------------------------
constexpr size_t SZ_H2    = (size_t)B * SQ * 128 * 2;   // 42,991,616 (bf16)
constexpr size_t SZ_C1    = (size_t)B * 64 * 128 * 2;   // 67,108,864 (bf16)
constexpr size_t OFF_H2   = 0;
constexpr size_t OFF_W5T  = 0;                 // w5t 6.7 MB; dead before k_h2 writes h2
constexpr size_t OFF_H3   = SZ_H2;
constexpr size_t R1       = 2 * SZ_H2;         // 85,983,232
constexpr size_t OFF_G    = R1;                                 // 314,880
constexpr size_t OFF_T2   = OFF_G + 314880 + 2624000;           // 6,560,000 (bf16)
constexpr size_t OFF_CMB  = OFF_T2 + 6560000;                   //   671,744
constexpr size_t OFF_W7T  = OFF_CMB + 671744;  // 9,404,416 bf16; dead by K5
constexpr size_t OFF_C1   = R1;                // overlaps tables+w7t (dead by K5)
constexpr size_t R2       = R1 + SZ_C1;        // 153,092,096
constexpr size_t OFF_PART = R2;                // 2 MB (conv1 BN; later ppy1/ppy2)
constexpr size_t OFF_Y1   = OFF_PART + 2097152;                 // 2,097,152
constexpr size_t OFF_Y2   = OFF_Y1 + 2097152;                   // 1,048,576
constexpr size_t OFF_SM   = OFF_Y2 + 1048576;                   //     1,024
constexpr size_t OFF_WPK  = OFF_SM + 1024;                      //    24,576
constexpr size_t OFF_CPK  = OFF_WPK + 24576;                    //    12,288
constexpr size_t OFF_RWP  = OFF_CPK + 12288;                    //    32,768

extern "C" void kernel_launch(void* const* d_in, const int* in_sizes, int n_in,
                              void* d_out, int out_size, void* d_ws, size_t ws_size,
                              hipStream_t stream) {
  const int*   x   = (const int*)d_in[0];
  const float* emb = (const float*)d_in[1];
  const float* W3  = (const float*)d_in[2];
  const float* b3  = (const float*)d_in[3];
  const float* W5  = (const float*)d_in[4];
  const float* b5  = (const float*)d_in[5];
  const float* W7  = (const float*)d_in[6];
  const float* b7  = (const float*)d_in[7];
  const float* c1w = (const float*)d_in[8];
  const float* c1b = (const float*)d_in[9];
  const float* bng = (const float*)d_in[10];
  const float* bnb = (const float*)d_in[11];
  const float* cpw = (const float*)d_in[12];
  const float* cpb = (const float*)d_in[13];
  const float* rW  = (const float*)d_in[14];
  const float* rb  = (const float*)d_in[15];
  const float* f1  = (const float*)d_in[16];
  const float* g1  = (const float*)d_in[17];
  const float* bb1 = (const float*)d_in[18];
  const float* f2  = (const float*)d_in[19];
  const float* g2  = (const float*)d_in[20];
  const float* bb2 = (const float*)d_in[21];
  const float* f3  = (const float*)d_in[22];

  char* wsb = (char*)d_ws;
  u16*    h2p   = (u16*)(wsb + OFF_H2);
  u16*    w5tp  = (u16*)(wsb + OFF_W5T);
  u16*    h3p   = (u16*)(wsb + OFF_H3);
  float*  Gp    = (float*)(wsb + OFF_G);
  u16*    t2p   = (u16*)(wsb + OFF_T2);
  int*    cmbp  = (int*)(wsb + OFF_CMB);
  u16*    w7tp  = (u16*)(wsb + OFF_W7T);
  u16*    c1p   = (u16*)(wsb + OFF_C1);
  float2* partp = (float2*)(wsb + OFF_PART);
  float2* ppy1  = partp;               // 2*512 float2 (PART free after bnfin)
  float2* ppy2  = partp + 2048;        // 2*1024 float2
  float*  y1p   = (float*)(wsb + OFF_Y1);
  float*  y2p   = (float*)(wsb + OFF_Y2);
  float*  scp   = (float*)(wsb + OFF_SM);
  float*  shp   = scp + 64;
  u16*    wpkp  = (u16*)(wsb + OFF_WPK);
  u16*    cpkp  = (u16*)(wsb + OFF_CPK);
  u16*    rwpp  = (u16*)(wsb + OFF_RWP);

  k_prep<<<2884, 256, 0, stream>>>(c1w, cpw, rW, rb, wpkp, cpkp, rwpp,
                                   x, cmbp, W5, w5tp, W7, w7tp, emb, W3, Gp);
  k_t2_mfma<<<SQ * 5, 256, 0, stream>>>(Gp, b3, w5tp, t2p);
  k_h2<<<(B * SQ * 16) / 256, 256, 0, stream>>>(t2p, cmbp, b5, h2p);
  k_gemm7_mfma<<<dim3(32, SQ), 256, 0, stream>>>(h2p, w7tp, b7, h3p);
  k_conv1<<<B / NBC, 256, 0, stream>>>(h3p, wpkp, c1b, c1p, partp);
  k_bnfin<<<64, 256, 0, stream>>>(partp, bng, bnb, scp, shp);
  k_caps<<<B / NB, 256, 0, stream>>>(c1p, scp, shp, cpkp, cpb, rwpp, f1, y1p, ppy1);
  k_fc2<<<B / 4, 256, 0, stream>>>(y1p, ppy1, g1, bb1, f2, y2p, ppy2);
  k_head<<<B / 256, 256, 0, stream>>>(y2p, ppy2, g2, bb2, f3, (float*)d_out);
}